// Round 2
// baseline (339.337 us; speedup 1.0000x reference)
//
#include <hip/hip_runtime.h>
#include <hip/hip_bf16.h>

#define N_SAMP    32768
#define NBINS     16384
#define NSIG      16
#define NBANDS    7
#define K_TOP     128
// padded per-signal band buffer: 64 zero-floats of guard before each band
#define BAND_STRIDE 65472   // 448 pad + 65024 payload

// staged bf16 layout (small): [filters 4096 | PT 8192 | PF 8192]
#define SST_F   0
#define SST_PT  4096
#define SST_PF  12288
#define SST_TOT 20480

#define TWO_PI 6.283185307179586f

typedef __attribute__((ext_vector_type(8))) short bf16x8;
typedef __attribute__((ext_vector_type(4))) float f32x4;

__device__ __forceinline__ float bf2f(__hip_bfloat16 v) { return __bfloat162float(v); }

__device__ __forceinline__ unsigned encf(float f) {
    unsigned u = __float_as_uint(f);
    return (u & 0x80000000u) ? ~u : (u | 0x80000000u);
}
__device__ __forceinline__ float decf(unsigned u) {
    return __uint_as_float((u & 0x80000000u) ? (u ^ 0x80000000u) : ~u);
}

__device__ __forceinline__ int band_M1sh(int b) { return b < 3 ? 4 : (b < 4 ? 5 : 6); }
__device__ __forceinline__ int band_Lsh(int b) {
    return b == 0 ? 5 : (b == 1 ? 6 : (b < 5 ? 7 : (b == 5 ? 8 : 9)));
}
__device__ __forceinline__ int band_M2sh(int b) {
    return b < 2 ? 4 : (b < 5 ? 5 : (b == 5 ? 6 : 7));
}

// ---------------------------------------------------------------------------
// K_fwd1 — MFMA step 1 (128x256 decomposition) with staging FOLDED IN (r14):
// blockIdx.x==4 blocks stage filters/PT/PF to bf16, zero band guards, and
// init all pipeline counters. Removes the separate k_stage launch.
__global__ __launch_bounds__(256) void k_fwd1(
    const void* __restrict__ tgt, const void* __restrict__ rec,
    const void* __restrict__ f, const void* __restrict__ pt,
    const void* __restrict__ pf,
    __hip_bfloat16* __restrict__ staged,
    float* __restrict__ bands, float* __restrict__ accum,
    int* __restrict__ counter, int* __restrict__ bandCnt,
    int* __restrict__ lossCnt,
    float* __restrict__ T)
{
    const int tid   = threadIdx.x;
    const int sig   = blockIdx.y;

    if (blockIdx.x == 4) {                     // staging slice for this sig
        float pv0 = bf2f(((const __hip_bfloat16*)tgt)[tid & 63]);
        int bad0 = (fabsf(pv0) > 1e8f) || (pv0 != pv0);
        const int isf = (__ballot(bad0) != 0ull);
        #pragma unroll
        for (int k = 0; k < 5; ++k) {          // 1280 elements per sig
            int id = sig * 1280 + k * 256 + tid;
            const void* src; int idx;
            if (id < SST_PT)      { src = f;  idx = id; }
            else if (id < SST_PF) { src = pt; idx = id - SST_PT; }
            else                  { src = pf; idx = id - SST_PF; }
            float v = isf ? ((const float*)src)[idx]
                          : bf2f(((const __hip_bfloat16*)src)[idx]);
            staged[id] = __float2bfloat16(v);
        }
        for (int i = tid; i < 448; i += 256) { // band guards for this sig
            int g = i >> 6, j = i & 63;
            int off = 64 * g + 512 * ((1 << g) - 1);
            bands[(size_t)sig * BAND_STRIDE + off + j] = 0.f;
        }
        if (sig == 0) {
            if (tid == 0) { accum[0] = 0.f; counter[0] = 0; }
            if (tid < NSIG * NBANDS) bandCnt[tid] = 0;          // 112
            if (tid >= 128 && tid < 128 + 8 * NBANDS) lossCnt[tid - 128] = 0; // 56
        }
        return;
    }

    const int nbase = (blockIdx.x & 1) * 128;  // n2 half
    const int kgrp  = (blockIdx.x >> 1) * 64;  // k1 group base
    __shared__ __align__(16) __hip_bfloat16 xT[128][136];  // [n2-local][n1]
    __shared__ float ct[128], st[128];
    __shared__ float2 t256[256];               // W_32768^(128a) = W_256^a, e^{-i}
    __shared__ float2 tF[128];                 // W_32768^a, a<128, e^{-i}

    {
        float sv, cv;
        sincosf(TWO_PI * (float)tid * (1.f / 256.f), &sv, &cv);
        t256[tid] = make_float2(cv, -sv);
        if (tid < 128) {
            sincosf(TWO_PI * (float)tid * (1.f / 128.f), &sv, &cv);
            ct[tid] = cv; st[tid] = sv;
            sincosf(TWO_PI * (float)tid * (1.f / 32768.f), &sv, &cv);
            tF[tid] = make_float2(cv, -sv);
        }
    }

    float pv = bf2f(((const __hip_bfloat16*)tgt)[tid & 63]);
    int bad = (fabsf(pv) > 1e8f) || (pv != pv);
    const int isf32 = (__ballot(bad) != 0ull);
    const void* xsrc = (sig < 8) ? tgt : rec;
    const int soff = (sig & 7) * N_SAMP;

    // stage transpose: row rloc = n2-local, thread covers one n1 half
    const int rloc = tid & 127;
    const int chb  = (tid >> 7) * 64;
    for (int c8 = 0; c8 < 64; c8 += 8) {
        union { bf16x8 v; __hip_bfloat16 h[8]; } u;
        #pragma unroll
        for (int uu = 0; uu < 8; ++uu) {
            int n1 = chb + c8 + uu;
            int gi = soff + n1 * 256 + nbase + rloc;
            float xv = isf32 ? ((const float*)xsrc)[gi]
                             : bf2f(((const __hip_bfloat16*)xsrc)[gi]);
            u.h[uu] = __float2bfloat16(xv);
        }
        *(bf16x8*)(&xT[rloc][chb + c8]) = u.v;
    }
    __syncthreads();

    const int tl = tid & 15, quad = (tid >> 4) & 3, w = tid >> 6;
    const int k1 = kgrp + w * 16 + tl;         // A row m = lane&15
    bf16x8 Arh[4], Arl[4], Aih[4], Ail[4];
    #pragma unroll
    for (int ki = 0; ki < 4; ++ki) {
        union { bf16x8 v; __hip_bfloat16 h[8]; } rh, rl, ih, il;
        #pragma unroll
        for (int j = 0; j < 8; ++j) {
            int n1 = ki * 32 + quad * 8 + j;
            int tt = (k1 * n1) & 127;
            float wre = ct[tt], wim = -st[tt]; // e^{-ia}
            __hip_bfloat16 h1 = __float2bfloat16(wre);
            rh.h[j] = h1;
            rl.h[j] = __float2bfloat16(wre - bf2f(h1));
            __hip_bfloat16 h2 = __float2bfloat16(wim);
            ih.h[j] = h2;
            il.h[j] = __float2bfloat16(wim - bf2f(h2));
        }
        Arh[ki] = rh.v; Arl[ki] = rl.v; Aih[ki] = ih.v; Ail[ki] = il.v;
    }

    float2* To = (float2*)T + (size_t)sig * 128 * 256;
    const int mk = kgrp + w * 16 + quad * 4;   // D row = quad*4+reg
    for (int ni = 0; ni < 8; ++ni) {
        bf16x8 B[4];
        #pragma unroll
        for (int ki = 0; ki < 4; ++ki)         // B[k=n1][n=n2]: b128, aligned
            B[ki] = *(const bf16x8*)(&xT[ni * 16 + tl][ki * 32 + quad * 8]);
        f32x4 aR = {0.f,0.f,0.f,0.f}, aI = {0.f,0.f,0.f,0.f};
        #pragma unroll
        for (int ki = 0; ki < 4; ++ki) {
            aR = __builtin_amdgcn_mfma_f32_16x16x32_bf16(Arh[ki], B[ki], aR, 0, 0, 0);
            aR = __builtin_amdgcn_mfma_f32_16x16x32_bf16(Arl[ki], B[ki], aR, 0, 0, 0);
            aI = __builtin_amdgcn_mfma_f32_16x16x32_bf16(Aih[ki], B[ki], aI, 0, 0, 0);
            aI = __builtin_amdgcn_mfma_f32_16x16x32_bf16(Ail[ki], B[ki], aI, 0, 0, 0);
        }
        const int n2 = nbase + ni * 16 + tl;
        #pragma unroll
        for (int rg = 0; rg < 4; ++rg) {
            int k1e = mk + rg;
            int m = k1e * n2;                  // < 32768, no mod needed
            float2 e1 = t256[m >> 7];
            float2 e2 = tF[m & 127];
            float er = e1.x * e2.x - e1.y * e2.y;   // e^{-i 2pi m/32768}
            float ei = e1.x * e2.y + e1.y * e2.x;
            float Tr = aR[rg] * er - aI[rg] * ei;
            float Ti = aI[rg] * er + aR[rg] * ei;
            To[(size_t)k1e * 256 + n2] = make_float2(Tr, Ti);
        }
    }
}

// Step2 with 4 independent rotation chains (proven r10) + W_256 LDS table (r13)
__global__ __launch_bounds__(128) void k_fwd2(
    const float* __restrict__ T, float* __restrict__ C)
{
    const int k2  = threadIdx.x;              // < 128
    const int k1  = blockIdx.x;
    const int sig = blockIdx.y;
    __shared__ float2 Ts[256];
    __shared__ float2 tw[256];                // e^{-i 2pi a/256}
    const float2* Tin = (const float2*)T + ((size_t)sig * 128 + k1) * 256;
    for (int i = k2; i < 256; i += 128) Ts[i] = Tin[i];
    {
        float sv, cv;
        sincosf(TWO_PI * (float)k2 * (1.f / 256.f), &sv, &cv);
        tw[k2]       = make_float2(cv, -sv);
        tw[k2 + 128] = make_float2(-cv, sv);   // angle + pi
    }
    __syncthreads();
    float er[4], ei[4];
    #pragma unroll
    for (int c = 0; c < 4; ++c) {
        float2 e = tw[(c * k2) & 255];
        er[c] = e.x; ei[c] = e.y;
    }
    float2 e4 = tw[(4 * k2) & 255];
    const float c4 = e4.x, s4 = e4.y;
    float Xr[4] = {0.f,0.f,0.f,0.f}, Xi[4] = {0.f,0.f,0.f,0.f};
    for (int n2 = 0; n2 < 256; n2 += 4) {
        #pragma unroll
        for (int c = 0; c < 4; ++c) {
            float2 t = Ts[n2 + c];
            Xr[c] += t.x * er[c] - t.y * ei[c];
            Xi[c] += t.x * ei[c] + t.y * er[c];
            float nr = er[c] * c4 - ei[c] * s4;
            ei[c]    = er[c] * s4 + ei[c] * c4;
            er[c] = nr;
        }
    }
    const float inv = 5.5242717280199030e-3f;   // 1/sqrt(32768)
    float xr = (Xr[0] + Xr[1]) + (Xr[2] + Xr[3]);
    float xi = (Xi[0] + Xi[1]) + (Xi[2] + Xi[3]);
    float2* Co = (float2*)C + (size_t)sig * NBINS;
    Co[k1 + 128 * k2] = make_float2(xr * inv, xi * inv);
}

// ---------------------------------------------------------------------------
// Band synthesis — quarter-band decimation (proven r11)
__global__ __launch_bounds__(256) void k_synthA(
    const float* __restrict__ C, float* __restrict__ G)
{
    const int tid = threadIdx.x;
    const int sig = blockIdx.y;
    const int bix = 63 - blockIdx.x;
    const int band = (bix == 0) ? 0 : (32 - __clz(bix));
    const int lbx  = (band == 0) ? 0 : (bix - (1 << (band - 1)));
    const int s    = 512 << band;
    const int m1sh = band_M1sh(band);
    const int lsh  = band_Lsh(band);
    const int m2sh = band_M2sh(band);
    const int M2   = 1 << m2sh;
    const int L    = 1 << lsh;
    const int L4   = L >> 2;
    const int a    = (band == 0) ? 0 : (128 << band);
    const int tix  = lbx * 256 + tid;
    const int j1lo = (lbx * 256) >> (lsh - 2);
    int j1cnt = 256 >> (lsh - 2);
    if (j1cnt > (1 << m1sh)) j1cnt = 1 << m1sh;
    __shared__ float2 Ds[256];
    const float2* D = (const float2*)C + (size_t)sig * NBINS + a;
    for (int i = tid; i < (j1cnt << m2sh); i += 256) {
        int j1o = i >> m2sh, j2 = i & (M2 - 1);
        Ds[i] = D[(j1lo + j1o) + (j2 << m1sh)];
    }
    __syncthreads();
    if (tix >= (128 << band)) return;
    const int j1o = (tix >> (lsh - 2)) - j1lo;
    const int m   = tix & (L4 - 1);
    const float2* Dj = Ds + (j1o << m2sh);
    float e0r = 1.f, e0i = 0.f, e1r, e1i, sr, si;
    sincosf(TWO_PI * (float)m / (float)L, &e1i, &e1r);
    sincosf(TWO_PI * (float)(2 * m) / (float)L, &si, &sr);
    float ar[4] = {0.f,0.f,0.f,0.f}, ai[4] = {0.f,0.f,0.f,0.f};
    for (int j2 = 0; j2 < M2; j2 += 4) {
        {   float2 d = Dj[j2];
            float tr = d.x * e0r - d.y * e0i, ti = d.x * e0i + d.y * e0r;
            ar[0] += tr; ai[0] += ti; ar[1] += tr; ai[1] += ti;
            ar[2] += tr; ai[2] += ti; ar[3] += tr; ai[3] += ti;
            float nr = e0r * sr - e0i * si; e0i = e0r * si + e0i * sr; e0r = nr;
        }
        {   float2 d = Dj[j2 + 1];
            float tr = d.x * e1r - d.y * e1i, ti = d.x * e1i + d.y * e1r;
            ar[0] += tr; ai[0] += ti;
            ar[1] -= ti; ai[1] += tr;
            ar[2] -= tr; ai[2] -= ti;
            ar[3] += ti; ai[3] -= tr;
            float nr = e1r * sr - e1i * si; e1i = e1r * si + e1i * sr; e1r = nr;
        }
        {   float2 d = Dj[j2 + 2];
            float tr = d.x * e0r - d.y * e0i, ti = d.x * e0i + d.y * e0r;
            ar[0] += tr; ai[0] += ti;
            ar[1] -= tr; ai[1] -= ti;
            ar[2] += tr; ai[2] += ti;
            ar[3] -= tr; ai[3] -= ti;
            float nr = e0r * sr - e0i * si; e0i = e0r * si + e0i * sr; e0r = nr;
        }
        {   float2 d = Dj[j2 + 3];
            float tr = d.x * e1r - d.y * e1i, ti = d.x * e1i + d.y * e1r;
            ar[0] += tr; ai[0] += ti;
            ar[1] += ti; ai[1] -= tr;
            ar[2] -= tr; ai[2] -= ti;
            ar[3] -= ti; ai[3] += tr;
            float nr = e1r * sr - e1i * si; e1i = e1r * si + e1i * sr; e1r = nr;
        }
    }
    const float sc = 2.f * rsqrtf((float)s);
    float2* Go = (float2*)G + (size_t)sig * 65024 + 512 * ((1 << band) - 1);
    const int base = ((tix >> (lsh - 2)) << lsh) + m;
    #pragma unroll
    for (int q = 0; q < 4; ++q)
        Go[base + q * L4] = make_float2(ar[q] * sc, ai[q] * sc);
}

__global__ __launch_bounds__(256) void k_synthB(
    const float* __restrict__ C, const float* __restrict__ G,
    float* __restrict__ bands)
{
    const int tid = threadIdx.x;
    const int sig = blockIdx.y;
    const int bix = 63 - blockIdx.x;
    const int band = (bix == 0) ? 0 : (32 - __clz(bix));
    const int lbx  = (band == 0) ? 0 : (bix - (1 << (band - 1)));
    const int s    = 512 << band;
    const int M1   = 1 << band_M1sh(band);
    const int lsh  = band_Lsh(band);
    const int n    = lbx * 256 + tid;
    const int s4   = s >> 2;
    if (n >= s4) return;
    const int m    = n & ((1 << lsh) - 1);
    const float2* Gi = (const float2*)G + (size_t)sig * 65024 + 512 * ((1 << band) - 1);
    float e0r = 1.f, e0i = 0.f, e1r, e1i, sr, si;
    sincosf(TWO_PI * (float)n / (float)s, &e1i, &e1r);
    sincosf(TWO_PI * (float)(2 * n) / (float)s, &si, &sr);
    float zr[4] = {0.f,0.f,0.f,0.f}, zi[4] = {0.f,0.f,0.f,0.f};
    for (int j1 = 0; j1 < M1; j1 += 4) {
        {   float2 g = Gi[((j1 + 0) << lsh) + m];
            float tr = g.x * e0r - g.y * e0i, ti = g.x * e0i + g.y * e0r;
            zr[0] += tr; zi[0] += ti; zr[1] += tr; zi[1] += ti;
            zr[2] += tr; zi[2] += ti; zr[3] += tr; zi[3] += ti;
            float nr = e0r * sr - e0i * si; e0i = e0r * si + e0i * sr; e0r = nr;
        }
        {   float2 g = Gi[((j1 + 1) << lsh) + m];
            float tr = g.x * e1r - g.y * e1i, ti = g.x * e1i + g.y * e1r;
            zr[0] += tr; zi[0] += ti;
            zr[1] -= ti; zi[1] += tr;
            zr[2] -= tr; zi[2] -= ti;
            zr[3] += ti; zi[3] -= tr;
            float nr = e1r * sr - e1i * si; e1i = e1r * si + e1i * sr; e1r = nr;
        }
        {   float2 g = Gi[((j1 + 2) << lsh) + m];
            float tr = g.x * e0r - g.y * e0i, ti = g.x * e0i + g.y * e0r;
            zr[0] += tr; zi[0] += ti;
            zr[1] -= tr; zi[1] -= ti;
            zr[2] += tr; zi[2] += ti;
            zr[3] -= tr; zi[3] -= ti;
            float nr = e0r * sr - e0i * si; e0i = e0r * si + e0i * sr; e0r = nr;
        }
        {   float2 g = Gi[((j1 + 3) << lsh) + m];
            float tr = g.x * e1r - g.y * e1i, ti = g.x * e1i + g.y * e1r;
            zr[0] += tr; zi[0] += ti;
            zr[1] += ti; zi[1] -= tr;
            zr[2] -= tr; zi[2] -= ti;
            zr[3] -= ti; zi[3] += tr;
            float nr = e1r * sr - e1i * si; e1i = e1r * si + e1i * sr; e1r = nr;
        }
    }
    const int poff = 64 * (band + 1) + 512 * ((1 << band) - 1);
    float* bo = bands + (size_t)sig * BAND_STRIDE + poff;
    if (band == 0) {
        const float dc = C[(size_t)sig * NBINS * 2] * 0.04419417382415922f;
        #pragma unroll
        for (int q = 0; q < 4; ++q) bo[n + q * s4] = zr[q] - dc;
    } else {
        #pragma unroll
        for (int q = 0; q < 4; ++q) {
            float val;
            switch (n & 3) {
                case 0:  val =  zr[q]; break;
                case 1:  val = -zi[q]; break;
                case 2:  val = -zr[q]; break;
                default: val =  zi[q]; break;
            }
            bo[n + q * s4] = val;
        }
    }
}

// ---------------------------------------------------------------------------
// K3 (r14): MFMA conv + fused segment-max pooling (proven r8), with TOPK and
// LOSS fused in via counter election: the last conv block of a (sig,band)
// runs the (proven r12) radix-select topk inline; the second topk winner of
// each (band,b) pair runs the loss inline. Device-scope fence+atomic handoff
// (same pattern as the proven k_loss finalize).
__global__ __launch_bounds__(256) void k_conv(
    const float* __restrict__ bands,
    const __hip_bfloat16* __restrict__ filters,
    float* __restrict__ segG,
    float* __restrict__ topv, int* __restrict__ topi,
    const __hip_bfloat16* __restrict__ PT, const __hip_bfloat16* __restrict__ PF,
    int* __restrict__ bandCnt, int* __restrict__ lossCnt,
    float* __restrict__ accum, int* __restrict__ counter,
    unsigned* __restrict__ out)
{
    const int tid  = threadIdx.x;
    const int sig  = blockIdx.y;
    const int c    = blockIdx.x;               // 0..126
    const int band = 31 - __clz(c + 1);
    const int cidx = c + 1 - (1 << band);
    const int poff = 64 * (band + 1) + 512 * ((1 << band) - 1);
    const float* bp = bands + (size_t)sig * BAND_STRIDE + poff + cidx * 512;

    __shared__ __align__(16) __hip_bfloat16 xr[8][584];
    __shared__ float segP[64 * 4];
    // topk phase
    __shared__ unsigned hist[256];
    __shared__ unsigned scan[256];
    __shared__ unsigned long long list[512];
    __shared__ int sh_B, sh_nA, sh_cnt, sh_num;
    // loss phase
    __shared__ float vT[128], vR[128];
    __shared__ int   iT[128], iR[128];
    __shared__ float red[256];
    __shared__ int amLast, sh_win, sh_w2;

    for (int i = tid; i < 576; i += 256) {
        __hip_bfloat16 b = __float2bfloat16(bp[511 - i]);
        #pragma unroll
        for (int p = 0; p < 8; ++p) {
            int idx = i - p;
            if (idx >= 0) xr[p][idx] = b;
        }
    }
    __syncthreads();

    const int tl   = tid & 15;
    const int quad = (tid >> 4) & 3;
    const int wave = tid >> 6;

    bf16x8 bf0[4], bf1[4];
    #pragma unroll
    for (int ft = 0; ft < 4; ++ft) {
        const __hip_bfloat16* fp = filters + ((ft * 16 + tl) * 64 + quad * 8);
        bf0[ft] = *(const bf16x8*)(fp);
        bf1[ft] = *(const bf16x8*)(fp + 32);
    }

    int s0 = 511 - wave * 128 - tl + 8 * quad;
    const __hip_bfloat16* xp = &xr[0][0] + (s0 & 7) * 584 + (s0 & ~7);

    const int spc = 512 >> (2 + band);
    float* segO = segG + (size_t)(sig * NBANDS + band) * 64 * 128 + cidx * spc;

    const float NEG = -3.4e38f;
    float run0 = NEG, run1 = NEG, run2 = NEG, run3 = NEG;
    const int per = (band >= 2) ? (1 << (band - 2)) : 1;

    for (int it = 0; it < 8; ++it) {
        const int t0 = wave * 128 + it * 16;
        bf16x8 a0 = *(const bf16x8*)(xp);
        bf16x8 a1 = *(const bf16x8*)(xp + 32);
        xp -= 16;
        f32x4 ac0 = {0.f,0.f,0.f,0.f}, ac1 = ac0, ac2 = ac0, ac3 = ac0;
        ac0 = __builtin_amdgcn_mfma_f32_16x16x32_bf16(a0, bf0[0], ac0, 0, 0, 0);
        ac0 = __builtin_amdgcn_mfma_f32_16x16x32_bf16(a1, bf1[0], ac0, 0, 0, 0);
        ac1 = __builtin_amdgcn_mfma_f32_16x16x32_bf16(a0, bf0[1], ac1, 0, 0, 0);
        ac1 = __builtin_amdgcn_mfma_f32_16x16x32_bf16(a1, bf1[1], ac1, 0, 0, 0);
        ac2 = __builtin_amdgcn_mfma_f32_16x16x32_bf16(a0, bf0[2], ac2, 0, 0, 0);
        ac2 = __builtin_amdgcn_mfma_f32_16x16x32_bf16(a1, bf1[2], ac2, 0, 0, 0);
        ac3 = __builtin_amdgcn_mfma_f32_16x16x32_bf16(a0, bf0[3], ac3, 0, 0, 0);
        ac3 = __builtin_amdgcn_mfma_f32_16x16x32_bf16(a1, bf1[3], ac3, 0, 0, 0);
        float m0 = fmaxf(fmaxf(ac0[0], ac0[1]), fmaxf(ac0[2], ac0[3]));
        float m1 = fmaxf(fmaxf(ac1[0], ac1[1]), fmaxf(ac1[2], ac1[3]));
        float m2 = fmaxf(fmaxf(ac2[0], ac2[1]), fmaxf(ac2[2], ac2[3]));
        float m3 = fmaxf(fmaxf(ac3[0], ac3[1]), fmaxf(ac3[2], ac3[3]));
        if (band == 0) {
            int sb = (t0 >> 2) + quad;
            segO[(tl     ) * 128 + sb] = m0;
            segO[(tl + 16) * 128 + sb] = m1;
            segO[(tl + 32) * 128 + sb] = m2;
            segO[(tl + 48) * 128 + sb] = m3;
        } else if (band == 1) {
            m0 = fmaxf(m0, __shfl_xor(m0, 16));
            m1 = fmaxf(m1, __shfl_xor(m1, 16));
            m2 = fmaxf(m2, __shfl_xor(m2, 16));
            m3 = fmaxf(m3, __shfl_xor(m3, 16));
            if ((quad & 1) == 0) {
                int sb = (t0 >> 3) + (quad >> 1);
                segO[(tl     ) * 128 + sb] = m0;
                segO[(tl + 16) * 128 + sb] = m1;
                segO[(tl + 32) * 128 + sb] = m2;
                segO[(tl + 48) * 128 + sb] = m3;
            }
        } else {
            m0 = fmaxf(m0, __shfl_xor(m0, 16)); m0 = fmaxf(m0, __shfl_xor(m0, 32));
            m1 = fmaxf(m1, __shfl_xor(m1, 16)); m1 = fmaxf(m1, __shfl_xor(m1, 32));
            m2 = fmaxf(m2, __shfl_xor(m2, 16)); m2 = fmaxf(m2, __shfl_xor(m2, 32));
            m3 = fmaxf(m3, __shfl_xor(m3, 16)); m3 = fmaxf(m3, __shfl_xor(m3, 32));
            run0 = fmaxf(run0, m0); run1 = fmaxf(run1, m1);
            run2 = fmaxf(run2, m2); run3 = fmaxf(run3, m3);
            if (((it + 1) & (per - 1)) == 0) {
                int sb = t0 >> (2 + band);
                float rv = quad == 0 ? run0 : quad == 1 ? run1
                         : quad == 2 ? run2 : run3;
                segO[(tl + 16 * quad) * 128 + sb] = rv;
                run0 = NEG; run1 = NEG; run2 = NEG; run3 = NEG;
            }
        }
    }
    if (band == 6) {
        float rv = quad == 0 ? run0 : quad == 1 ? run1
                 : quad == 2 ? run2 : run3;
        segP[(tl + 16 * quad) * 4 + wave] = rv;
        __syncthreads();
        if (tid < 128) {
            int f = tid & 63, sg = tid >> 6;
            segO[f * 128 + sg] =
                fmaxf(segP[f * 4 + 2 * sg], segP[f * 4 + 2 * sg + 1]);
        }
    }

    // ---- election: last conv block of this (sig,band) runs topk ----
    __syncthreads();
    if (tid == 0) {
        __threadfence();
        sh_win = (atomicAdd(&bandCnt[sig * NBANDS + band], 1) == (1 << band) - 1);
    }
    __syncthreads();
    if (!sh_win) return;
    __threadfence();   // acquire: see all blocks' segG writes

    // ---- topk (r12 proven) ----
    const float* segB = segG + (size_t)(sig * NBANDS + band) * 64 * 128;
    unsigned long long kk[16];
    #pragma unroll
    for (int q = 0; q < 16; ++q) {
        int i = q * 256 + tid;
        int f = i >> 6, t = i & 63;
        const float* sg = segB + f * 128;
        float m = fmaxf(sg[2 * t], sg[2 * t + 1]);
        if (t > 0)  m = fmaxf(m, sg[2 * t - 1]);
        if (t < 63) m = fmaxf(m, sg[2 * t + 2]);
        kk[q] = ((unsigned long long)encf(m) << 32) | (unsigned)(4095 - i);
    }

    int shift = 56;
    unsigned long long prefix = 0;
    int nA = 0;
    for (int lev = 0; lev < 8; ++lev) {
        hist[tid] = 0;
        __syncthreads();
        #pragma unroll
        for (int q = 0; q < 16; ++q) {
            bool inpre = (lev == 0) || ((kk[q] >> (shift + 8)) == prefix);
            if (inpre) atomicAdd(&hist[(unsigned)((kk[q] >> shift) & 255u)], 1u);
        }
        __syncthreads();
        scan[tid] = hist[tid];
        __syncthreads();
        for (int off = 1; off < 256; off <<= 1) {
            unsigned v = scan[tid] + ((tid + off < 256) ? scan[tid + off] : 0u);
            __syncthreads();
            scan[tid] = v;
            __syncthreads();
        }
        {
            unsigned ge = (unsigned)nA + scan[tid];
            unsigned gt = (unsigned)nA + ((tid < 255) ? scan[tid + 1] : 0u);
            if (ge >= 128u && gt < 128u) {
                sh_B = tid; sh_nA = (int)gt; sh_cnt = (int)hist[tid];
            }
        }
        __syncthreads();
        prefix = (prefix << 8) | (unsigned)sh_B;
        nA = sh_nA;
        if (nA + sh_cnt <= 511 || shift == 0) break;
        shift -= 8;
        __syncthreads();
    }

    list[tid] = 0ull; list[tid + 256] = 0ull;
    if (tid == 0) sh_num = 0;
    __syncthreads();
    #pragma unroll
    for (int q = 0; q < 16; ++q) {
        if ((kk[q] >> shift) >= prefix) {
            int p = atomicAdd(&sh_num, 1);
            if (p < 512) list[p] = kk[q];
        }
    }
    __syncthreads();

    for (int k = 2; k <= 512; k <<= 1) {
        for (int j = k >> 1; j > 0; j >>= 1) {
            for (int w = tid; w < 512; w += 256) {
                int l = w ^ j;
                if (l > w) {
                    unsigned long long av = list[w], bv = list[l];
                    bool up = ((w & k) == 0);
                    if ((av > bv) == up) { list[w] = bv; list[l] = av; }
                }
            }
            __syncthreads();
        }
    }
    if (tid < K_TOP) {
        unsigned long long key = list[511 - tid];
        const size_t ob = ((size_t)sig * NBANDS + band) * K_TOP + tid;
        topv[ob] = decf((unsigned)(key >> 32));
        topi[ob] = 4095 - (int)(key & 0xFFFFFFFFu);
    }

    // ---- election: second topk winner of this (band, b) pair runs loss ----
    __syncthreads();
    if (tid == 0) {
        __threadfence();
        sh_w2 = (atomicAdd(&lossCnt[(sig & 7) * NBANDS + band], 1) == 1);
    }
    __syncthreads();
    if (!sh_w2) return;
    __threadfence();   // acquire: see partner block's topv/topi

    // ---- loss (proven k_loss body) ----
    const int b = sig & 7;
    const size_t bt = ((size_t)b * NBANDS + band) * K_TOP;
    const size_t br = ((size_t)(8 + b) * NBANDS + band) * K_TOP;
    if (tid < 128) { vT[tid] = topv[bt + tid]; iT[tid] = topi[bt + tid]; }
    else { int j = tid - 128; vR[j] = topv[br + j]; iR[j] = topi[br + j]; }
    __syncthreads();
    float sum = 0.f;
    if (tid < 128) {
        #pragma unroll 4
        for (int k = 0; k < K_TOP; ++k) {
            float a = vT[k] * bf2f(PT[(iT[k] & 63) * 128 + tid]);
            float cc = vR[k] * bf2f(PT[(iR[k] & 63) * 128 + tid]);
            sum += fabsf(a - cc);
        }
    } else {
        const int j = tid - 128;
        #pragma unroll 4
        for (int k = 0; k < K_TOP; ++k) {
            float a = bf2f(PF[(iT[k] >> 6) * 128 + j]);
            float cc = bf2f(PF[(iR[k] >> 6) * 128 + j]);
            sum += fabsf(a - cc);
        }
    }
    red[tid] = sum;
    __syncthreads();
    for (int ofs = 128; ofs > 0; ofs >>= 1) {
        if (tid < ofs) red[tid] += red[tid + ofs];
        __syncthreads();
    }
    if (tid == 0) {
        atomicAdd(accum, red[0]);
        __threadfence();
        amLast = (atomicAdd(counter, 1) == NBANDS * 8 - 1);
    }
    __syncthreads();
    if (!amLast) return;
    if (tid == 0) {
        __threadfence();
        float L = atomicAdd(accum, 0.f) * (1.0f / 1835008.0f);
        unsigned lu = __float_as_uint(L);
        bool isnanL = ((lu & 0x7F800000u) == 0x7F800000u) && (lu & 0x007FFFFFu);
        float code;
        if      (isnanL)           code = 500.f;
        else if (L == 0.f)         code = 400.f;
        else if (fabsf(L) < 1e-6f) code = 600.f;
        else                       code = L;
        unsigned fb = __float_as_uint(code);
        unsigned hb = (fb + 0x7FFFu + ((fb >> 16) & 1u)) >> 16;
        out[0] = (hb << 16) | hb;    // dual-format store (proven r4)
    }
}

// ---------------------------------------------------------------------------
extern "C" void kernel_launch(void* const* d_in, const int* in_sizes, int n_in,
                              void* d_out, int out_size, void* d_ws, size_t ws_size,
                              hipStream_t stream)
{
    float* C      = (float*)d_ws;                          // 524288 f
    float* bands  = C + (size_t)NSIG * NBINS * 2;          // 1047552 f
    float* segG   = bands + (size_t)NSIG * BAND_STRIDE;    // 917504 f
    float* topv   = segG + (size_t)NSIG * NBANDS * 64 * 128; // 14336 f
    int*   topi   = (int*)(topv + (size_t)NSIG * NBANDS * K_TOP);
    float* accum  = (float*)(topi + (size_t)NSIG * NBANDS * K_TOP);
    int*   counter= (int*)(accum + 1);
    int*   bandCnt= (int*)(accum + 4);                     // 112 ints
    int*   lossCnt= bandCnt + NSIG * NBANDS;               // 56 ints
    __hip_bfloat16* staged = (__hip_bfloat16*)(accum + 172); // 16B-aligned
    float* TG = (float*)(staged + SST_TOT);   // T and G alias (T dead before G)
    float* T  = TG;
    float* G  = TG;

    const __hip_bfloat16* fst = staged + SST_F;
    const __hip_bfloat16* pts = staged + SST_PT;
    const __hip_bfloat16* pfs = staged + SST_PF;

    k_fwd1   <<<dim3(5, NSIG),   256, 0, stream>>>(d_in[0], d_in[1],
                 d_in[2], d_in[3], d_in[4], staged, bands, accum, counter,
                 bandCnt, lossCnt, T);
    k_fwd2   <<<dim3(128, NSIG), 128, 0, stream>>>(T, C);
    k_synthA <<<dim3(64, NSIG),  256, 0, stream>>>(C, G);
    k_synthB <<<dim3(64, NSIG),  256, 0, stream>>>(C, G, bands);
    k_conv   <<<dim3(127, NSIG), 256, 0, stream>>>(bands, fst, segG,
                 topv, topi, pts, pfs, bandCnt, lossCnt, accum, counter,
                 (unsigned*)d_out);
}

// Round 3
// 207.088 us; speedup vs baseline: 1.6386x; 1.6386x over previous
//
#include <hip/hip_runtime.h>
#include <hip/hip_bf16.h>

#define N_SAMP    32768
#define NBINS     16384
#define NSIG      16
#define NBANDS    7
#define K_TOP     128
// padded per-signal band buffer: 64 zero-floats of guard before each band
#define BAND_STRIDE 65472   // 448 pad + 65024 payload

// staged bf16 layout (small): [filters 4096 | PT 8192 | PF 8192]
#define SST_F   0
#define SST_PT  4096
#define SST_PF  12288
#define SST_TOT 20480

#define TWO_PI 6.283185307179586f

typedef __attribute__((ext_vector_type(8))) short bf16x8;
typedef __attribute__((ext_vector_type(4))) float f32x4;

__device__ __forceinline__ float bf2f(__hip_bfloat16 v) { return __bfloat162float(v); }

__device__ __forceinline__ unsigned encf(float f) {
    unsigned u = __float_as_uint(f);
    return (u & 0x80000000u) ? ~u : (u | 0x80000000u);
}
__device__ __forceinline__ float decf(unsigned u) {
    return __uint_as_float((u & 0x80000000u) ? (u ^ 0x80000000u) : ~u);
}

__device__ __forceinline__ int band_M1sh(int b) { return b < 3 ? 4 : (b < 4 ? 5 : 6); }
__device__ __forceinline__ int band_Lsh(int b) {
    return b == 0 ? 5 : (b == 1 ? 6 : (b < 5 ? 7 : (b == 5 ? 8 : 9)));
}
__device__ __forceinline__ int band_M2sh(int b) {
    return b < 2 ? 4 : (b < 5 ? 5 : (b == 5 ? 6 : 7));
}

// ---------------------------------------------------------------------------
// K_fwd1 — MFMA step 1 (128x256 decomposition), staging folded in (r15):
// blockIdx.x==4 blocks stage filters/PT/PF to bf16, zero this sig's band
// guards, and (sig 0) init accum/counter. Fence-free: staged data is
// consumed 4 kernel-boundaries later; boundaries provide visibility.
// Inter-step twiddles via two-level LDS table (r13):
// W_32768^m = W_256^(m>>7) * W_32768^(m&127).
__global__ __launch_bounds__(256) void k_fwd1(
    const void* __restrict__ tgt, const void* __restrict__ rec,
    const void* __restrict__ f, const void* __restrict__ pt,
    const void* __restrict__ pf,
    __hip_bfloat16* __restrict__ staged,
    float* __restrict__ bands, float* __restrict__ accum,
    int* __restrict__ counter,
    float* __restrict__ T)
{
    const int tid   = threadIdx.x;
    const int sig   = blockIdx.y;

    if (blockIdx.x == 4) {                     // staging slice for this sig
        float pv0 = bf2f(((const __hip_bfloat16*)tgt)[tid & 63]);
        int bad0 = (fabsf(pv0) > 1e8f) || (pv0 != pv0);
        const int isf = (__ballot(bad0) != 0ull);
        #pragma unroll
        for (int k = 0; k < 5; ++k) {          // 1280 elements per sig
            int id = sig * 1280 + k * 256 + tid;
            const void* src; int idx;
            if (id < SST_PT)      { src = f;  idx = id; }
            else if (id < SST_PF) { src = pt; idx = id - SST_PT; }
            else                  { src = pf; idx = id - SST_PF; }
            float v = isf ? ((const float*)src)[idx]
                          : bf2f(((const __hip_bfloat16*)src)[idx]);
            staged[id] = __float2bfloat16(v);
        }
        for (int i = tid; i < 448; i += 256) { // band guards for this sig
            int g = i >> 6, j = i & 63;
            int off = 64 * g + 512 * ((1 << g) - 1);
            bands[(size_t)sig * BAND_STRIDE + off + j] = 0.f;
        }
        if (sig == 0 && tid == 0) { accum[0] = 0.f; counter[0] = 0; }
        return;
    }

    const int nbase = (blockIdx.x & 1) * 128;  // n2 half
    const int kgrp  = (blockIdx.x >> 1) * 64;  // k1 group base
    __shared__ __align__(16) __hip_bfloat16 xT[128][136];  // [n2-local][n1]
    __shared__ float ct[128], st[128];
    __shared__ float2 t256[256];               // W_32768^(128a) = W_256^a, e^{-i}
    __shared__ float2 tF[128];                 // W_32768^a, a<128, e^{-i}

    {
        float sv, cv;
        sincosf(TWO_PI * (float)tid * (1.f / 256.f), &sv, &cv);
        t256[tid] = make_float2(cv, -sv);
        if (tid < 128) {
            sincosf(TWO_PI * (float)tid * (1.f / 128.f), &sv, &cv);
            ct[tid] = cv; st[tid] = sv;
            sincosf(TWO_PI * (float)tid * (1.f / 32768.f), &sv, &cv);
            tF[tid] = make_float2(cv, -sv);
        }
    }

    float pv = bf2f(((const __hip_bfloat16*)tgt)[tid & 63]);
    int bad = (fabsf(pv) > 1e8f) || (pv != pv);
    const int isf32 = (__ballot(bad) != 0ull);
    const void* xsrc = (sig < 8) ? tgt : rec;
    const int soff = (sig & 7) * N_SAMP;

    // stage transpose: row rloc = n2-local, thread covers one n1 half
    const int rloc = tid & 127;
    const int chb  = (tid >> 7) * 64;
    for (int c8 = 0; c8 < 64; c8 += 8) {
        union { bf16x8 v; __hip_bfloat16 h[8]; } u;
        #pragma unroll
        for (int uu = 0; uu < 8; ++uu) {
            int n1 = chb + c8 + uu;
            int gi = soff + n1 * 256 + nbase + rloc;
            float xv = isf32 ? ((const float*)xsrc)[gi]
                             : bf2f(((const __hip_bfloat16*)xsrc)[gi]);
            u.h[uu] = __float2bfloat16(xv);
        }
        *(bf16x8*)(&xT[rloc][chb + c8]) = u.v;
    }
    __syncthreads();

    const int tl = tid & 15, quad = (tid >> 4) & 3, w = tid >> 6;
    const int k1 = kgrp + w * 16 + tl;         // A row m = lane&15
    bf16x8 Arh[4], Arl[4], Aih[4], Ail[4];
    #pragma unroll
    for (int ki = 0; ki < 4; ++ki) {
        union { bf16x8 v; __hip_bfloat16 h[8]; } rh, rl, ih, il;
        #pragma unroll
        for (int j = 0; j < 8; ++j) {
            int n1 = ki * 32 + quad * 8 + j;
            int tt = (k1 * n1) & 127;
            float wre = ct[tt], wim = -st[tt]; // e^{-ia}
            __hip_bfloat16 h1 = __float2bfloat16(wre);
            rh.h[j] = h1;
            rl.h[j] = __float2bfloat16(wre - bf2f(h1));
            __hip_bfloat16 h2 = __float2bfloat16(wim);
            ih.h[j] = h2;
            il.h[j] = __float2bfloat16(wim - bf2f(h2));
        }
        Arh[ki] = rh.v; Arl[ki] = rl.v; Aih[ki] = ih.v; Ail[ki] = il.v;
    }

    float2* To = (float2*)T + (size_t)sig * 128 * 256;
    const int mk = kgrp + w * 16 + quad * 4;   // D row = quad*4+reg
    for (int ni = 0; ni < 8; ++ni) {
        bf16x8 B[4];
        #pragma unroll
        for (int ki = 0; ki < 4; ++ki)         // B[k=n1][n=n2]: b128, aligned
            B[ki] = *(const bf16x8*)(&xT[ni * 16 + tl][ki * 32 + quad * 8]);
        f32x4 aR = {0.f,0.f,0.f,0.f}, aI = {0.f,0.f,0.f,0.f};
        #pragma unroll
        for (int ki = 0; ki < 4; ++ki) {
            aR = __builtin_amdgcn_mfma_f32_16x16x32_bf16(Arh[ki], B[ki], aR, 0, 0, 0);
            aR = __builtin_amdgcn_mfma_f32_16x16x32_bf16(Arl[ki], B[ki], aR, 0, 0, 0);
            aI = __builtin_amdgcn_mfma_f32_16x16x32_bf16(Aih[ki], B[ki], aI, 0, 0, 0);
            aI = __builtin_amdgcn_mfma_f32_16x16x32_bf16(Ail[ki], B[ki], aI, 0, 0, 0);
        }
        const int n2 = nbase + ni * 16 + tl;
        #pragma unroll
        for (int rg = 0; rg < 4; ++rg) {
            int k1e = mk + rg;
            int m = k1e * n2;                  // < 32768, no mod needed
            float2 e1 = t256[m >> 7];
            float2 e2 = tF[m & 127];
            float er = e1.x * e2.x - e1.y * e2.y;   // e^{-i 2pi m/32768}
            float ei = e1.x * e2.y + e1.y * e2.x;
            float Tr = aR[rg] * er - aI[rg] * ei;
            float Ti = aI[rg] * er + aR[rg] * ei;
            To[(size_t)k1e * 256 + n2] = make_float2(Tr, Ti);
        }
    }
}

// Step2 with 4 independent rotation chains (proven r10) + W_256 LDS table (r13)
__global__ __launch_bounds__(128) void k_fwd2(
    const float* __restrict__ T, float* __restrict__ C)
{
    const int k2  = threadIdx.x;              // < 128
    const int k1  = blockIdx.x;
    const int sig = blockIdx.y;
    __shared__ float2 Ts[256];
    __shared__ float2 tw[256];                // e^{-i 2pi a/256}
    const float2* Tin = (const float2*)T + ((size_t)sig * 128 + k1) * 256;
    for (int i = k2; i < 256; i += 128) Ts[i] = Tin[i];
    {
        float sv, cv;
        sincosf(TWO_PI * (float)k2 * (1.f / 256.f), &sv, &cv);
        tw[k2]       = make_float2(cv, -sv);
        tw[k2 + 128] = make_float2(-cv, sv);   // angle + pi
    }
    __syncthreads();
    float er[4], ei[4];
    #pragma unroll
    for (int c = 0; c < 4; ++c) {
        float2 e = tw[(c * k2) & 255];
        er[c] = e.x; ei[c] = e.y;
    }
    float2 e4 = tw[(4 * k2) & 255];
    const float c4 = e4.x, s4 = e4.y;
    float Xr[4] = {0.f,0.f,0.f,0.f}, Xi[4] = {0.f,0.f,0.f,0.f};
    for (int n2 = 0; n2 < 256; n2 += 4) {
        #pragma unroll
        for (int c = 0; c < 4; ++c) {
            float2 t = Ts[n2 + c];
            Xr[c] += t.x * er[c] - t.y * ei[c];
            Xi[c] += t.x * ei[c] + t.y * er[c];
            float nr = er[c] * c4 - ei[c] * s4;
            ei[c]    = er[c] * s4 + ei[c] * c4;
            er[c] = nr;
        }
    }
    const float inv = 5.5242717280199030e-3f;   // 1/sqrt(32768)
    float xr = (Xr[0] + Xr[1]) + (Xr[2] + Xr[3]);
    float xi = (Xi[0] + Xi[1]) + (Xi[2] + Xi[3]);
    float2* Co = (float2*)C + (size_t)sig * NBINS;
    Co[k1 + 128 * k2] = make_float2(xr * inv, xi * inv);
}

// ---------------------------------------------------------------------------
// Band synthesis — quarter-band decimation (proven r11)
__global__ __launch_bounds__(256) void k_synthA(
    const float* __restrict__ C, float* __restrict__ G)
{
    const int tid = threadIdx.x;
    const int sig = blockIdx.y;
    const int bix = 63 - blockIdx.x;
    const int band = (bix == 0) ? 0 : (32 - __clz(bix));
    const int lbx  = (band == 0) ? 0 : (bix - (1 << (band - 1)));
    const int s    = 512 << band;
    const int m1sh = band_M1sh(band);
    const int lsh  = band_Lsh(band);
    const int m2sh = band_M2sh(band);
    const int M2   = 1 << m2sh;
    const int L    = 1 << lsh;
    const int L4   = L >> 2;
    const int a    = (band == 0) ? 0 : (128 << band);
    const int tix  = lbx * 256 + tid;
    const int j1lo = (lbx * 256) >> (lsh - 2);
    int j1cnt = 256 >> (lsh - 2);
    if (j1cnt > (1 << m1sh)) j1cnt = 1 << m1sh;
    __shared__ float2 Ds[256];
    const float2* D = (const float2*)C + (size_t)sig * NBINS + a;
    for (int i = tid; i < (j1cnt << m2sh); i += 256) {
        int j1o = i >> m2sh, j2 = i & (M2 - 1);
        Ds[i] = D[(j1lo + j1o) + (j2 << m1sh)];
    }
    __syncthreads();
    if (tix >= (128 << band)) return;
    const int j1o = (tix >> (lsh - 2)) - j1lo;
    const int m   = tix & (L4 - 1);
    const float2* Dj = Ds + (j1o << m2sh);
    float e0r = 1.f, e0i = 0.f, e1r, e1i, sr, si;
    sincosf(TWO_PI * (float)m / (float)L, &e1i, &e1r);
    sincosf(TWO_PI * (float)(2 * m) / (float)L, &si, &sr);
    float ar[4] = {0.f,0.f,0.f,0.f}, ai[4] = {0.f,0.f,0.f,0.f};
    for (int j2 = 0; j2 < M2; j2 += 4) {
        {   float2 d = Dj[j2];
            float tr = d.x * e0r - d.y * e0i, ti = d.x * e0i + d.y * e0r;
            ar[0] += tr; ai[0] += ti; ar[1] += tr; ai[1] += ti;
            ar[2] += tr; ai[2] += ti; ar[3] += tr; ai[3] += ti;
            float nr = e0r * sr - e0i * si; e0i = e0r * si + e0i * sr; e0r = nr;
        }
        {   float2 d = Dj[j2 + 1];
            float tr = d.x * e1r - d.y * e1i, ti = d.x * e1i + d.y * e1r;
            ar[0] += tr; ai[0] += ti;
            ar[1] -= ti; ai[1] += tr;
            ar[2] -= tr; ai[2] -= ti;
            ar[3] += ti; ai[3] -= tr;
            float nr = e1r * sr - e1i * si; e1i = e1r * si + e1i * sr; e1r = nr;
        }
        {   float2 d = Dj[j2 + 2];
            float tr = d.x * e0r - d.y * e0i, ti = d.x * e0i + d.y * e0r;
            ar[0] += tr; ai[0] += ti;
            ar[1] -= tr; ai[1] -= ti;
            ar[2] += tr; ai[2] += ti;
            ar[3] -= tr; ai[3] -= ti;
            float nr = e0r * sr - e0i * si; e0i = e0r * si + e0i * sr; e0r = nr;
        }
        {   float2 d = Dj[j2 + 3];
            float tr = d.x * e1r - d.y * e1i, ti = d.x * e1i + d.y * e1r;
            ar[0] += tr; ai[0] += ti;
            ar[1] += ti; ai[1] -= tr;
            ar[2] -= tr; ai[2] -= ti;
            ar[3] -= ti; ai[3] += tr;
            float nr = e1r * sr - e1i * si; e1i = e1r * si + e1i * sr; e1r = nr;
        }
    }
    const float sc = 2.f * rsqrtf((float)s);
    float2* Go = (float2*)G + (size_t)sig * 65024 + 512 * ((1 << band) - 1);
    const int base = ((tix >> (lsh - 2)) << lsh) + m;
    #pragma unroll
    for (int q = 0; q < 4; ++q)
        Go[base + q * L4] = make_float2(ar[q] * sc, ai[q] * sc);
}

__global__ __launch_bounds__(256) void k_synthB(
    const float* __restrict__ C, const float* __restrict__ G,
    float* __restrict__ bands)
{
    const int tid = threadIdx.x;
    const int sig = blockIdx.y;
    const int bix = 63 - blockIdx.x;
    const int band = (bix == 0) ? 0 : (32 - __clz(bix));
    const int lbx  = (band == 0) ? 0 : (bix - (1 << (band - 1)));
    const int s    = 512 << band;
    const int M1   = 1 << band_M1sh(band);
    const int lsh  = band_Lsh(band);
    const int n    = lbx * 256 + tid;
    const int s4   = s >> 2;
    if (n >= s4) return;
    const int m    = n & ((1 << lsh) - 1);
    const float2* Gi = (const float2*)G + (size_t)sig * 65024 + 512 * ((1 << band) - 1);
    float e0r = 1.f, e0i = 0.f, e1r, e1i, sr, si;
    sincosf(TWO_PI * (float)n / (float)s, &e1i, &e1r);
    sincosf(TWO_PI * (float)(2 * n) / (float)s, &si, &sr);
    float zr[4] = {0.f,0.f,0.f,0.f}, zi[4] = {0.f,0.f,0.f,0.f};
    for (int j1 = 0; j1 < M1; j1 += 4) {
        {   float2 g = Gi[((j1 + 0) << lsh) + m];
            float tr = g.x * e0r - g.y * e0i, ti = g.x * e0i + g.y * e0r;
            zr[0] += tr; zi[0] += ti; zr[1] += tr; zi[1] += ti;
            zr[2] += tr; zi[2] += ti; zr[3] += tr; zi[3] += ti;
            float nr = e0r * sr - e0i * si; e0i = e0r * si + e0i * sr; e0r = nr;
        }
        {   float2 g = Gi[((j1 + 1) << lsh) + m];
            float tr = g.x * e1r - g.y * e1i, ti = g.x * e1i + g.y * e1r;
            zr[0] += tr; zi[0] += ti;
            zr[1] -= ti; zi[1] += tr;
            zr[2] -= tr; zi[2] -= ti;
            zr[3] += ti; zi[3] -= tr;
            float nr = e1r * sr - e1i * si; e1i = e1r * si + e1i * sr; e1r = nr;
        }
        {   float2 g = Gi[((j1 + 2) << lsh) + m];
            float tr = g.x * e0r - g.y * e0i, ti = g.x * e0i + g.y * e0r;
            zr[0] += tr; zi[0] += ti;
            zr[1] -= tr; zi[1] -= ti;
            zr[2] += tr; zi[2] += ti;
            zr[3] -= tr; zi[3] -= ti;
            float nr = e0r * sr - e0i * si; e0i = e0r * si + e0i * sr; e0r = nr;
        }
        {   float2 g = Gi[((j1 + 3) << lsh) + m];
            float tr = g.x * e1r - g.y * e1i, ti = g.x * e1i + g.y * e1r;
            zr[0] += tr; zi[0] += ti;
            zr[1] += ti; zi[1] -= tr;
            zr[2] -= tr; zi[2] -= ti;
            zr[3] -= ti; zi[3] += tr;
            float nr = e1r * sr - e1i * si; e1i = e1r * si + e1i * sr; e1r = nr;
        }
    }
    const int poff = 64 * (band + 1) + 512 * ((1 << band) - 1);
    float* bo = bands + (size_t)sig * BAND_STRIDE + poff;
    if (band == 0) {
        const float dc = C[(size_t)sig * NBINS * 2] * 0.04419417382415922f;
        #pragma unroll
        for (int q = 0; q < 4; ++q) bo[n + q * s4] = zr[q] - dc;
    } else {
        #pragma unroll
        for (int q = 0; q < 4; ++q) {
            float val;
            switch (n & 3) {
                case 0:  val =  zr[q]; break;
                case 1:  val = -zi[q]; break;
                case 2:  val = -zr[q]; break;
                default: val =  zi[q]; break;
            }
            bo[n + q * s4] = val;
        }
    }
}

// ---------------------------------------------------------------------------
// K3: MFMA conv + fused segment-max pooling (proven r8, bit-exact)
__global__ __launch_bounds__(256) void k_conv(
    const float* __restrict__ bands,
    const __hip_bfloat16* __restrict__ filters,
    float* __restrict__ segG)
{
    const int tid  = threadIdx.x;
    const int sig  = blockIdx.y;
    const int c    = blockIdx.x;               // 0..126
    const int band = 31 - __clz(c + 1);
    const int cidx = c + 1 - (1 << band);
    const int poff = 64 * (band + 1) + 512 * ((1 << band) - 1);
    const float* bp = bands + (size_t)sig * BAND_STRIDE + poff + cidx * 512;

    __shared__ __align__(16) __hip_bfloat16 xr[8][584];
    __shared__ float segP[64 * 4];

    for (int i = tid; i < 576; i += 256) {
        __hip_bfloat16 b = __float2bfloat16(bp[511 - i]);
        #pragma unroll
        for (int p = 0; p < 8; ++p) {
            int idx = i - p;
            if (idx >= 0) xr[p][idx] = b;
        }
    }
    __syncthreads();

    const int tl   = tid & 15;
    const int quad = (tid >> 4) & 3;
    const int wave = tid >> 6;

    bf16x8 bf0[4], bf1[4];
    #pragma unroll
    for (int ft = 0; ft < 4; ++ft) {
        const __hip_bfloat16* fp = filters + ((ft * 16 + tl) * 64 + quad * 8);
        bf0[ft] = *(const bf16x8*)(fp);
        bf1[ft] = *(const bf16x8*)(fp + 32);
    }

    int s0 = 511 - wave * 128 - tl + 8 * quad;
    const __hip_bfloat16* xp = &xr[0][0] + (s0 & 7) * 584 + (s0 & ~7);

    const int spc = 512 >> (2 + band);
    float* segO = segG + (size_t)(sig * NBANDS + band) * 64 * 128 + cidx * spc;

    const float NEG = -3.4e38f;
    float run0 = NEG, run1 = NEG, run2 = NEG, run3 = NEG;
    const int per = (band >= 2) ? (1 << (band - 2)) : 1;

    for (int it = 0; it < 8; ++it) {
        const int t0 = wave * 128 + it * 16;
        bf16x8 a0 = *(const bf16x8*)(xp);
        bf16x8 a1 = *(const bf16x8*)(xp + 32);
        xp -= 16;
        f32x4 ac0 = {0.f,0.f,0.f,0.f}, ac1 = ac0, ac2 = ac0, ac3 = ac0;
        ac0 = __builtin_amdgcn_mfma_f32_16x16x32_bf16(a0, bf0[0], ac0, 0, 0, 0);
        ac0 = __builtin_amdgcn_mfma_f32_16x16x32_bf16(a1, bf1[0], ac0, 0, 0, 0);
        ac1 = __builtin_amdgcn_mfma_f32_16x16x32_bf16(a0, bf0[1], ac1, 0, 0, 0);
        ac1 = __builtin_amdgcn_mfma_f32_16x16x32_bf16(a1, bf1[1], ac1, 0, 0, 0);
        ac2 = __builtin_amdgcn_mfma_f32_16x16x32_bf16(a0, bf0[2], ac2, 0, 0, 0);
        ac2 = __builtin_amdgcn_mfma_f32_16x16x32_bf16(a1, bf1[2], ac2, 0, 0, 0);
        ac3 = __builtin_amdgcn_mfma_f32_16x16x32_bf16(a0, bf0[3], ac3, 0, 0, 0);
        ac3 = __builtin_amdgcn_mfma_f32_16x16x32_bf16(a1, bf1[3], ac3, 0, 0, 0);
        float m0 = fmaxf(fmaxf(ac0[0], ac0[1]), fmaxf(ac0[2], ac0[3]));
        float m1 = fmaxf(fmaxf(ac1[0], ac1[1]), fmaxf(ac1[2], ac1[3]));
        float m2 = fmaxf(fmaxf(ac2[0], ac2[1]), fmaxf(ac2[2], ac2[3]));
        float m3 = fmaxf(fmaxf(ac3[0], ac3[1]), fmaxf(ac3[2], ac3[3]));
        if (band == 0) {
            int sb = (t0 >> 2) + quad;
            segO[(tl     ) * 128 + sb] = m0;
            segO[(tl + 16) * 128 + sb] = m1;
            segO[(tl + 32) * 128 + sb] = m2;
            segO[(tl + 48) * 128 + sb] = m3;
        } else if (band == 1) {
            m0 = fmaxf(m0, __shfl_xor(m0, 16));
            m1 = fmaxf(m1, __shfl_xor(m1, 16));
            m2 = fmaxf(m2, __shfl_xor(m2, 16));
            m3 = fmaxf(m3, __shfl_xor(m3, 16));
            if ((quad & 1) == 0) {
                int sb = (t0 >> 3) + (quad >> 1);
                segO[(tl     ) * 128 + sb] = m0;
                segO[(tl + 16) * 128 + sb] = m1;
                segO[(tl + 32) * 128 + sb] = m2;
                segO[(tl + 48) * 128 + sb] = m3;
            }
        } else {
            m0 = fmaxf(m0, __shfl_xor(m0, 16)); m0 = fmaxf(m0, __shfl_xor(m0, 32));
            m1 = fmaxf(m1, __shfl_xor(m1, 16)); m1 = fmaxf(m1, __shfl_xor(m1, 32));
            m2 = fmaxf(m2, __shfl_xor(m2, 16)); m2 = fmaxf(m2, __shfl_xor(m2, 32));
            m3 = fmaxf(m3, __shfl_xor(m3, 16)); m3 = fmaxf(m3, __shfl_xor(m3, 32));
            run0 = fmaxf(run0, m0); run1 = fmaxf(run1, m1);
            run2 = fmaxf(run2, m2); run3 = fmaxf(run3, m3);
            if (((it + 1) & (per - 1)) == 0) {
                int sb = t0 >> (2 + band);
                float rv = quad == 0 ? run0 : quad == 1 ? run1
                         : quad == 2 ? run2 : run3;
                segO[(tl + 16 * quad) * 128 + sb] = rv;
                run0 = NEG; run1 = NEG; run2 = NEG; run3 = NEG;
            }
        }
    }
    if (band == 6) {
        float rv = quad == 0 ? run0 : quad == 1 ? run1
                 : quad == 2 ? run2 : run3;
        segP[(tl + 16 * quad) * 4 + wave] = rv;
        __syncthreads();
        if (tid < 128) {
            int f = tid & 63, sg = tid >> 6;
            segO[f * 128 + sg] =
                fmaxf(segP[f * 4 + 2 * sg], segP[f * 4 + 2 * sg + 1]);
        }
    }
}

// ---------------------------------------------------------------------------
// K4: pool + top-128 via radix select + small bitonic sort (proven r9)
__global__ __launch_bounds__(256) void k_topk(
    const float* __restrict__ segG,
    float* __restrict__ topv, int* __restrict__ topi)
{
    const int tid = threadIdx.x;
    const int band = blockIdx.x, sig = blockIdx.y;
    const float* segB = segG + (size_t)(sig * NBANDS + band) * 64 * 128;

    __shared__ unsigned hist[256];
    __shared__ unsigned scan[256];
    __shared__ unsigned long long list[512];
    __shared__ int sh_B, sh_nA, sh_cnt, sh_num;

    unsigned long long kk[16];
    #pragma unroll
    for (int q = 0; q < 16; ++q) {
        int i = q * 256 + tid;
        int f = i >> 6, t = i & 63;
        const float* sg = segB + f * 128;
        float m = fmaxf(sg[2 * t], sg[2 * t + 1]);
        if (t > 0)  m = fmaxf(m, sg[2 * t - 1]);
        if (t < 63) m = fmaxf(m, sg[2 * t + 2]);
        kk[q] = ((unsigned long long)encf(m) << 32) | (unsigned)(4095 - i);
    }

    int shift = 56;
    unsigned long long prefix = 0;
    int nA = 0;
    for (int lev = 0; lev < 8; ++lev) {
        hist[tid] = 0;
        __syncthreads();
        #pragma unroll
        for (int q = 0; q < 16; ++q) {
            bool inpre = (lev == 0) || ((kk[q] >> (shift + 8)) == prefix);
            if (inpre) atomicAdd(&hist[(unsigned)((kk[q] >> shift) & 255u)], 1u);
        }
        __syncthreads();
        scan[tid] = hist[tid];
        __syncthreads();
        for (int off = 1; off < 256; off <<= 1) {
            unsigned v = scan[tid] + ((tid + off < 256) ? scan[tid + off] : 0u);
            __syncthreads();
            scan[tid] = v;
            __syncthreads();
        }
        {
            unsigned ge = (unsigned)nA + scan[tid];
            unsigned gt = (unsigned)nA + ((tid < 255) ? scan[tid + 1] : 0u);
            if (ge >= 128u && gt < 128u) {
                sh_B = tid; sh_nA = (int)gt; sh_cnt = (int)hist[tid];
            }
        }
        __syncthreads();
        prefix = (prefix << 8) | (unsigned)sh_B;
        nA = sh_nA;
        if (nA + sh_cnt <= 511 || shift == 0) break;
        shift -= 8;
        __syncthreads();
    }

    list[tid] = 0ull; list[tid + 256] = 0ull;
    if (tid == 0) sh_num = 0;
    __syncthreads();
    #pragma unroll
    for (int q = 0; q < 16; ++q) {
        if ((kk[q] >> shift) >= prefix) {
            int p = atomicAdd(&sh_num, 1);
            if (p < 512) list[p] = kk[q];
        }
    }
    __syncthreads();

    for (int k = 2; k <= 512; k <<= 1) {
        for (int j = k >> 1; j > 0; j >>= 1) {
            for (int w = tid; w < 512; w += 256) {
                int l = w ^ j;
                if (l > w) {
                    unsigned long long av = list[w], bv = list[l];
                    bool up = ((w & k) == 0);
                    if ((av > bv) == up) { list[w] = bv; list[l] = av; }
                }
            }
            __syncthreads();
        }
    }
    if (tid < K_TOP) {
        unsigned long long key = list[511 - tid];
        const size_t ob = ((size_t)sig * NBANDS + band) * K_TOP + tid;
        topv[ob] = decf((unsigned)(key >> 32));
        topi[ob] = 4095 - (int)(key & 0xFFFFFFFFu);
    }
}

// ---------------------------------------------------------------------------
// K5: loss with LDS-prefetched indices (breaks the dependent-load chain) +
// counter-elected finalize (value-level codes only; scans dropped).
__global__ __launch_bounds__(256) void k_loss(
    const float* __restrict__ topv, const int* __restrict__ topi,
    const __hip_bfloat16* __restrict__ PT, const __hip_bfloat16* __restrict__ PF,
    float* __restrict__ accum, int* __restrict__ counter,
    unsigned* __restrict__ out)
{
    const int tid = threadIdx.x;
    const int band = blockIdx.x, b = blockIdx.y;
    const size_t bt = ((size_t)b * NBANDS + band) * K_TOP;
    const size_t br = ((size_t)(8 + b) * NBANDS + band) * K_TOP;
    __shared__ float vT[128], vR[128];
    __shared__ int   iT[128], iR[128];
    if (tid < 128) { vT[tid] = topv[bt + tid]; iT[tid] = topi[bt + tid]; }
    else { int j = tid - 128; vR[j] = topv[br + j]; iR[j] = topi[br + j]; }
    __syncthreads();
    float sum = 0.f;
    if (tid < 128) {
        #pragma unroll 4
        for (int k = 0; k < K_TOP; ++k) {
            float a = vT[k] * bf2f(PT[(iT[k] & 63) * 128 + tid]);
            float c = vR[k] * bf2f(PT[(iR[k] & 63) * 128 + tid]);
            sum += fabsf(a - c);
        }
    } else {
        const int j = tid - 128;
        #pragma unroll 4
        for (int k = 0; k < K_TOP; ++k) {
            float a = bf2f(PF[(iT[k] >> 6) * 128 + j]);
            float c = bf2f(PF[(iR[k] >> 6) * 128 + j]);
            sum += fabsf(a - c);
        }
    }
    __shared__ float red[256];
    __shared__ int amLast;
    red[tid] = sum;
    __syncthreads();
    for (int ofs = 128; ofs > 0; ofs >>= 1) {
        if (tid < ofs) red[tid] += red[tid + ofs];
        __syncthreads();
    }
    if (tid == 0) {
        atomicAdd(accum, red[0]);
        __threadfence();
        amLast = (atomicAdd(counter, 1) == NBANDS * 8 - 1);
    }
    __syncthreads();
    if (!amLast) return;
    if (tid == 0) {
        __threadfence();
        float L = atomicAdd(accum, 0.f) * (1.0f / 1835008.0f);
        unsigned lu = __float_as_uint(L);
        bool isnanL = ((lu & 0x7F800000u) == 0x7F800000u) && (lu & 0x007FFFFFu);
        float code;
        if      (isnanL)           code = 500.f;
        else if (L == 0.f)         code = 400.f;
        else if (fabsf(L) < 1e-6f) code = 600.f;
        else                       code = L;
        unsigned fb = __float_as_uint(code);
        unsigned hb = (fb + 0x7FFFu + ((fb >> 16) & 1u)) >> 16;
        out[0] = (hb << 16) | hb;    // dual-format store (proven r4)
    }
}

// ---------------------------------------------------------------------------
extern "C" void kernel_launch(void* const* d_in, const int* in_sizes, int n_in,
                              void* d_out, int out_size, void* d_ws, size_t ws_size,
                              hipStream_t stream)
{
    float* C      = (float*)d_ws;                          // 524288 f
    float* bands  = C + (size_t)NSIG * NBINS * 2;          // 1047552 f
    float* segG   = bands + (size_t)NSIG * BAND_STRIDE;    // 917504 f
    float* topv   = segG + (size_t)NSIG * NBANDS * 64 * 128; // 14336 f
    int*   topi   = (int*)(topv + (size_t)NSIG * NBANDS * K_TOP);
    float* accum  = (float*)(topi + (size_t)NSIG * NBANDS * K_TOP);
    int*   counter= (int*)(accum + 1);
    __hip_bfloat16* staged = (__hip_bfloat16*)(accum + 4);  // 16B-aligned
    float* TG = (float*)(staged + SST_TOT);   // T and G alias (T dead before G)
    float* T  = TG;
    float* G  = TG;

    const __hip_bfloat16* fst = staged + SST_F;
    const __hip_bfloat16* pts = staged + SST_PT;
    const __hip_bfloat16* pfs = staged + SST_PF;

    k_fwd1   <<<dim3(5, NSIG),       256, 0, stream>>>(d_in[0], d_in[1],
                 d_in[2], d_in[3], d_in[4], staged, bands, accum, counter, T);
    k_fwd2   <<<dim3(128, NSIG),     128, 0, stream>>>(T, C);
    k_synthA <<<dim3(64, NSIG),      256, 0, stream>>>(C, G);
    k_synthB <<<dim3(64, NSIG),      256, 0, stream>>>(C, G, bands);
    k_conv   <<<dim3(127, NSIG),     256, 0, stream>>>(bands, fst, segG);
    k_topk   <<<dim3(NBANDS, NSIG),  256, 0, stream>>>(segG, topv, topi);
    k_loss   <<<dim3(NBANDS, 8),     256, 0, stream>>>(topv, topi, pts, pfs,
                 accum, counter, (unsigned*)d_out);
}

// Round 4
// 198.755 us; speedup vs baseline: 1.7073x; 1.0419x over previous
//
#include <hip/hip_runtime.h>
#include <hip/hip_bf16.h>

#define N_SAMP    32768
#define NBINS     16384
#define NSIG      16
#define NBANDS    7
#define K_TOP     128
// padded per-signal band buffer: 64 zero-floats of guard before each band
#define BAND_STRIDE 65472   // 448 pad + 65024 payload

// staged bf16 layout (small): [filters 4096 | PT 8192 | PF 8192]
#define SST_F   0
#define SST_PT  4096
#define SST_PF  12288
#define SST_TOT 20480

#define TWO_PI 6.283185307179586f

typedef __attribute__((ext_vector_type(8))) short bf16x8;
typedef __attribute__((ext_vector_type(4))) float f32x4;

__device__ __forceinline__ float bf2f(__hip_bfloat16 v) { return __bfloat162float(v); }

__device__ __forceinline__ unsigned encf(float f) {
    unsigned u = __float_as_uint(f);
    return (u & 0x80000000u) ? ~u : (u | 0x80000000u);
}
__device__ __forceinline__ float decf(unsigned u) {
    return __uint_as_float((u & 0x80000000u) ? (u ^ 0x80000000u) : ~u);
}

__device__ __forceinline__ int band_M1sh(int b) { return b < 3 ? 4 : (b < 4 ? 5 : 6); }
__device__ __forceinline__ int band_Lsh(int b) {
    return b == 0 ? 5 : (b == 1 ? 6 : (b < 5 ? 7 : (b == 5 ? 8 : 9)));
}
__device__ __forceinline__ int band_M2sh(int b) {
    return b < 2 ? 4 : (b < 5 ? 5 : (b == 5 ? 6 : 7));
}

// ---------------------------------------------------------------------------
// K_fwd1 — MFMA step 1 (128x256 decomposition), staging folded in (r15).
// r16: ni-range split — grid (9,16); bx<8 work blocks each own half the n2
// subtiles (ni 0..3 or 4..7) and stage only the 64 xT rows they consume.
// 2.25x more CUs busy, half the serial depth, same total staged bytes.
// bx==8 stages filters/PT/PF + zeroes guards (fence-free; consumed 4 kernel
// boundaries later).
__global__ __launch_bounds__(256) void k_fwd1(
    const void* __restrict__ tgt, const void* __restrict__ rec,
    const void* __restrict__ f, const void* __restrict__ pt,
    const void* __restrict__ pf,
    __hip_bfloat16* __restrict__ staged,
    float* __restrict__ bands, float* __restrict__ accum,
    int* __restrict__ counter,
    float* __restrict__ T)
{
    const int tid   = threadIdx.x;
    const int sig   = blockIdx.y;

    if (blockIdx.x == 8) {                     // staging slice for this sig
        float pv0 = bf2f(((const __hip_bfloat16*)tgt)[tid & 63]);
        int bad0 = (fabsf(pv0) > 1e8f) || (pv0 != pv0);
        const int isf = (__ballot(bad0) != 0ull);
        #pragma unroll
        for (int k = 0; k < 5; ++k) {          // 1280 elements per sig
            int id = sig * 1280 + k * 256 + tid;
            const void* src; int idx;
            if (id < SST_PT)      { src = f;  idx = id; }
            else if (id < SST_PF) { src = pt; idx = id - SST_PT; }
            else                  { src = pf; idx = id - SST_PF; }
            float v = isf ? ((const float*)src)[idx]
                          : bf2f(((const __hip_bfloat16*)src)[idx]);
            staged[id] = __float2bfloat16(v);
        }
        for (int i = tid; i < 448; i += 256) { // band guards for this sig
            int g = i >> 6, j = i & 63;
            int off = 64 * g + 512 * ((1 << g) - 1);
            bands[(size_t)sig * BAND_STRIDE + off + j] = 0.f;
        }
        if (sig == 0 && tid == 0) { accum[0] = 0.f; counter[0] = 0; }
        return;
    }

    const int nbase = (blockIdx.x & 1) * 128;        // n2 half
    const int kgrp  = ((blockIdx.x >> 1) & 1) * 64;  // k1 group base
    const int nqh   = (blockIdx.x >> 2) & 1;         // ni half (n2 quarter)
    __shared__ __align__(16) __hip_bfloat16 xT[64][136];  // [n2-local][n1]
    __shared__ float ct[128], st[128];
    __shared__ float2 t256[256];               // W_32768^(128a) = W_256^a, e^{-i}
    __shared__ float2 tF[128];                 // W_32768^a, a<128, e^{-i}

    {
        float sv, cv;
        sincosf(TWO_PI * (float)tid * (1.f / 256.f), &sv, &cv);
        t256[tid] = make_float2(cv, -sv);
        if (tid < 128) {
            sincosf(TWO_PI * (float)tid * (1.f / 128.f), &sv, &cv);
            ct[tid] = cv; st[tid] = sv;
            sincosf(TWO_PI * (float)tid * (1.f / 32768.f), &sv, &cv);
            tF[tid] = make_float2(cv, -sv);
        }
    }

    float pv = bf2f(((const __hip_bfloat16*)tgt)[tid & 63]);
    int bad = (fabsf(pv) > 1e8f) || (pv != pv);
    const int isf32 = (__ballot(bad) != 0ull);
    const void* xsrc = (sig < 8) ? tgt : rec;
    const int soff = (sig & 7) * N_SAMP;

    // stage transpose: 64 rows (this block's n2 quarter), thread covers a
    // 32-wide n1 quarter of one row
    const int rloc = tid & 63;
    const int chb  = (tid >> 6) * 32;
    for (int c8 = 0; c8 < 32; c8 += 8) {
        union { bf16x8 v; __hip_bfloat16 h[8]; } u;
        #pragma unroll
        for (int uu = 0; uu < 8; ++uu) {
            int n1 = chb + c8 + uu;
            int gi = soff + n1 * 256 + nbase + nqh * 64 + rloc;
            float xv = isf32 ? ((const float*)xsrc)[gi]
                             : bf2f(((const __hip_bfloat16*)xsrc)[gi]);
            u.h[uu] = __float2bfloat16(xv);
        }
        *(bf16x8*)(&xT[rloc][chb + c8]) = u.v;
    }
    __syncthreads();

    const int tl = tid & 15, quad = (tid >> 4) & 3, w = tid >> 6;
    const int k1 = kgrp + w * 16 + tl;         // A row m = lane&15
    bf16x8 Arh[4], Arl[4], Aih[4], Ail[4];
    #pragma unroll
    for (int ki = 0; ki < 4; ++ki) {
        union { bf16x8 v; __hip_bfloat16 h[8]; } rh, rl, ih, il;
        #pragma unroll
        for (int j = 0; j < 8; ++j) {
            int n1 = ki * 32 + quad * 8 + j;
            int tt = (k1 * n1) & 127;
            float wre = ct[tt], wim = -st[tt]; // e^{-ia}
            __hip_bfloat16 h1 = __float2bfloat16(wre);
            rh.h[j] = h1;
            rl.h[j] = __float2bfloat16(wre - bf2f(h1));
            __hip_bfloat16 h2 = __float2bfloat16(wim);
            ih.h[j] = h2;
            il.h[j] = __float2bfloat16(wim - bf2f(h2));
        }
        Arh[ki] = rh.v; Arl[ki] = rl.v; Aih[ki] = ih.v; Ail[ki] = il.v;
    }

    float2* To = (float2*)T + (size_t)sig * 128 * 256;
    const int mk = kgrp + w * 16 + quad * 4;   // D row = quad*4+reg
    for (int ni = 0; ni < 4; ++ni) {
        bf16x8 B[4];
        #pragma unroll
        for (int ki = 0; ki < 4; ++ki)         // B[k=n1][n=n2]: b128, aligned
            B[ki] = *(const bf16x8*)(&xT[ni * 16 + tl][ki * 32 + quad * 8]);
        f32x4 aR = {0.f,0.f,0.f,0.f}, aI = {0.f,0.f,0.f,0.f};
        #pragma unroll
        for (int ki = 0; ki < 4; ++ki) {
            aR = __builtin_amdgcn_mfma_f32_16x16x32_bf16(Arh[ki], B[ki], aR, 0, 0, 0);
            aR = __builtin_amdgcn_mfma_f32_16x16x32_bf16(Arl[ki], B[ki], aR, 0, 0, 0);
            aI = __builtin_amdgcn_mfma_f32_16x16x32_bf16(Aih[ki], B[ki], aI, 0, 0, 0);
            aI = __builtin_amdgcn_mfma_f32_16x16x32_bf16(Ail[ki], B[ki], aI, 0, 0, 0);
        }
        const int n2 = nbase + nqh * 64 + ni * 16 + tl;
        #pragma unroll
        for (int rg = 0; rg < 4; ++rg) {
            int k1e = mk + rg;
            int m = k1e * n2;                  // < 32768, no mod needed
            float2 e1 = t256[m >> 7];
            float2 e2 = tF[m & 127];
            float er = e1.x * e2.x - e1.y * e2.y;   // e^{-i 2pi m/32768}
            float ei = e1.x * e2.y + e1.y * e2.x;
            float Tr = aR[rg] * er - aI[rg] * ei;
            float Ti = aI[rg] * er + aR[rg] * ei;
            To[(size_t)k1e * 256 + n2] = make_float2(Tr, Ti);
        }
    }
}

// Step2 with 4 independent rotation chains (proven r10) + W_256 LDS table (r13)
__global__ __launch_bounds__(128) void k_fwd2(
    const float* __restrict__ T, float* __restrict__ C)
{
    const int k2  = threadIdx.x;              // < 128
    const int k1  = blockIdx.x;
    const int sig = blockIdx.y;
    __shared__ float2 Ts[256];
    __shared__ float2 tw[256];                // e^{-i 2pi a/256}
    const float2* Tin = (const float2*)T + ((size_t)sig * 128 + k1) * 256;
    for (int i = k2; i < 256; i += 128) Ts[i] = Tin[i];
    {
        float sv, cv;
        sincosf(TWO_PI * (float)k2 * (1.f / 256.f), &sv, &cv);
        tw[k2]       = make_float2(cv, -sv);
        tw[k2 + 128] = make_float2(-cv, sv);   // angle + pi
    }
    __syncthreads();
    float er[4], ei[4];
    #pragma unroll
    for (int c = 0; c < 4; ++c) {
        float2 e = tw[(c * k2) & 255];
        er[c] = e.x; ei[c] = e.y;
    }
    float2 e4 = tw[(4 * k2) & 255];
    const float c4 = e4.x, s4 = e4.y;
    float Xr[4] = {0.f,0.f,0.f,0.f}, Xi[4] = {0.f,0.f,0.f,0.f};
    for (int n2 = 0; n2 < 256; n2 += 4) {
        #pragma unroll
        for (int c = 0; c < 4; ++c) {
            float2 t = Ts[n2 + c];
            Xr[c] += t.x * er[c] - t.y * ei[c];
            Xi[c] += t.x * ei[c] + t.y * er[c];
            float nr = er[c] * c4 - ei[c] * s4;
            ei[c]    = er[c] * s4 + ei[c] * c4;
            er[c] = nr;
        }
    }
    const float inv = 5.5242717280199030e-3f;   // 1/sqrt(32768)
    float xr = (Xr[0] + Xr[1]) + (Xr[2] + Xr[3]);
    float xi = (Xi[0] + Xi[1]) + (Xi[2] + Xi[3]);
    float2* Co = (float2*)C + (size_t)sig * NBINS;
    Co[k1 + 128 * k2] = make_float2(xr * inv, xi * inv);
}

// ---------------------------------------------------------------------------
// Band synthesis — quarter-band decimation (proven r11)
__global__ __launch_bounds__(256) void k_synthA(
    const float* __restrict__ C, float* __restrict__ G)
{
    const int tid = threadIdx.x;
    const int sig = blockIdx.y;
    const int bix = 63 - blockIdx.x;
    const int band = (bix == 0) ? 0 : (32 - __clz(bix));
    const int lbx  = (band == 0) ? 0 : (bix - (1 << (band - 1)));
    const int s    = 512 << band;
    const int m1sh = band_M1sh(band);
    const int lsh  = band_Lsh(band);
    const int m2sh = band_M2sh(band);
    const int M2   = 1 << m2sh;
    const int L    = 1 << lsh;
    const int L4   = L >> 2;
    const int a    = (band == 0) ? 0 : (128 << band);
    const int tix  = lbx * 256 + tid;
    const int j1lo = (lbx * 256) >> (lsh - 2);
    int j1cnt = 256 >> (lsh - 2);
    if (j1cnt > (1 << m1sh)) j1cnt = 1 << m1sh;
    __shared__ float2 Ds[256];
    const float2* D = (const float2*)C + (size_t)sig * NBINS + a;
    for (int i = tid; i < (j1cnt << m2sh); i += 256) {
        int j1o = i >> m2sh, j2 = i & (M2 - 1);
        Ds[i] = D[(j1lo + j1o) + (j2 << m1sh)];
    }
    __syncthreads();
    if (tix >= (128 << band)) return;
    const int j1o = (tix >> (lsh - 2)) - j1lo;
    const int m   = tix & (L4 - 1);
    const float2* Dj = Ds + (j1o << m2sh);
    float e0r = 1.f, e0i = 0.f, e1r, e1i, sr, si;
    sincosf(TWO_PI * (float)m / (float)L, &e1i, &e1r);
    sincosf(TWO_PI * (float)(2 * m) / (float)L, &si, &sr);
    float ar[4] = {0.f,0.f,0.f,0.f}, ai[4] = {0.f,0.f,0.f,0.f};
    for (int j2 = 0; j2 < M2; j2 += 4) {
        {   float2 d = Dj[j2];
            float tr = d.x * e0r - d.y * e0i, ti = d.x * e0i + d.y * e0r;
            ar[0] += tr; ai[0] += ti; ar[1] += tr; ai[1] += ti;
            ar[2] += tr; ai[2] += ti; ar[3] += tr; ai[3] += ti;
            float nr = e0r * sr - e0i * si; e0i = e0r * si + e0i * sr; e0r = nr;
        }
        {   float2 d = Dj[j2 + 1];
            float tr = d.x * e1r - d.y * e1i, ti = d.x * e1i + d.y * e1r;
            ar[0] += tr; ai[0] += ti;
            ar[1] -= ti; ai[1] += tr;
            ar[2] -= tr; ai[2] -= ti;
            ar[3] += ti; ai[3] -= tr;
            float nr = e1r * sr - e1i * si; e1i = e1r * si + e1i * sr; e1r = nr;
        }
        {   float2 d = Dj[j2 + 2];
            float tr = d.x * e0r - d.y * e0i, ti = d.x * e0i + d.y * e0r;
            ar[0] += tr; ai[0] += ti;
            ar[1] -= tr; ai[1] -= ti;
            ar[2] += tr; ai[2] += ti;
            ar[3] -= tr; ai[3] -= ti;
            float nr = e0r * sr - e0i * si; e0i = e0r * si + e0i * sr; e0r = nr;
        }
        {   float2 d = Dj[j2 + 3];
            float tr = d.x * e1r - d.y * e1i, ti = d.x * e1i + d.y * e1r;
            ar[0] += tr; ai[0] += ti;
            ar[1] += ti; ai[1] -= tr;
            ar[2] -= tr; ai[2] -= ti;
            ar[3] -= ti; ai[3] += tr;
            float nr = e1r * sr - e1i * si; e1i = e1r * si + e1i * sr; e1r = nr;
        }
    }
    const float sc = 2.f * rsqrtf((float)s);
    float2* Go = (float2*)G + (size_t)sig * 65024 + 512 * ((1 << band) - 1);
    const int base = ((tix >> (lsh - 2)) << lsh) + m;
    #pragma unroll
    for (int q = 0; q < 4; ++q)
        Go[base + q * L4] = make_float2(ar[q] * sc, ai[q] * sc);
}

__global__ __launch_bounds__(256) void k_synthB(
    const float* __restrict__ C, const float* __restrict__ G,
    float* __restrict__ bands)
{
    const int tid = threadIdx.x;
    const int sig = blockIdx.y;
    const int bix = 63 - blockIdx.x;
    const int band = (bix == 0) ? 0 : (32 - __clz(bix));
    const int lbx  = (band == 0) ? 0 : (bix - (1 << (band - 1)));
    const int s    = 512 << band;
    const int M1   = 1 << band_M1sh(band);
    const int lsh  = band_Lsh(band);
    const int n    = lbx * 256 + tid;
    const int s4   = s >> 2;
    if (n >= s4) return;
    const int m    = n & ((1 << lsh) - 1);
    const float2* Gi = (const float2*)G + (size_t)sig * 65024 + 512 * ((1 << band) - 1);
    float e0r = 1.f, e0i = 0.f, e1r, e1i, sr, si;
    sincosf(TWO_PI * (float)n / (float)s, &e1i, &e1r);
    sincosf(TWO_PI * (float)(2 * n) / (float)s, &si, &sr);
    float zr[4] = {0.f,0.f,0.f,0.f}, zi[4] = {0.f,0.f,0.f,0.f};
    for (int j1 = 0; j1 < M1; j1 += 4) {
        {   float2 g = Gi[((j1 + 0) << lsh) + m];
            float tr = g.x * e0r - g.y * e0i, ti = g.x * e0i + g.y * e0r;
            zr[0] += tr; zi[0] += ti; zr[1] += tr; zi[1] += ti;
            zr[2] += tr; zi[2] += ti; zr[3] += tr; zi[3] += ti;
            float nr = e0r * sr - e0i * si; e0i = e0r * si + e0i * sr; e0r = nr;
        }
        {   float2 g = Gi[((j1 + 1) << lsh) + m];
            float tr = g.x * e1r - g.y * e1i, ti = g.x * e1i + g.y * e1r;
            zr[0] += tr; zi[0] += ti;
            zr[1] -= ti; zi[1] += tr;
            zr[2] -= tr; zi[2] -= ti;
            zr[3] += ti; zi[3] -= tr;
            float nr = e1r * sr - e1i * si; e1i = e1r * si + e1i * sr; e1r = nr;
        }
        {   float2 g = Gi[((j1 + 2) << lsh) + m];
            float tr = g.x * e0r - g.y * e0i, ti = g.x * e0i + g.y * e0r;
            zr[0] += tr; zi[0] += ti;
            zr[1] -= tr; zi[1] -= ti;
            zr[2] += tr; zi[2] += ti;
            zr[3] -= tr; zi[3] -= ti;
            float nr = e0r * sr - e0i * si; e0i = e0r * si + e0i * sr; e0r = nr;
        }
        {   float2 g = Gi[((j1 + 3) << lsh) + m];
            float tr = g.x * e1r - g.y * e1i, ti = g.x * e1i + g.y * e1r;
            zr[0] += tr; zi[0] += ti;
            zr[1] += ti; zi[1] -= tr;
            zr[2] -= tr; zi[2] -= ti;
            zr[3] -= ti; zi[3] += tr;
            float nr = e1r * sr - e1i * si; e1i = e1r * si + e1i * sr; e1r = nr;
        }
    }
    const int poff = 64 * (band + 1) + 512 * ((1 << band) - 1);
    float* bo = bands + (size_t)sig * BAND_STRIDE + poff;
    if (band == 0) {
        const float dc = C[(size_t)sig * NBINS * 2] * 0.04419417382415922f;
        #pragma unroll
        for (int q = 0; q < 4; ++q) bo[n + q * s4] = zr[q] - dc;
    } else {
        #pragma unroll
        for (int q = 0; q < 4; ++q) {
            float val;
            switch (n & 3) {
                case 0:  val =  zr[q]; break;
                case 1:  val = -zi[q]; break;
                case 2:  val = -zr[q]; break;
                default: val =  zi[q]; break;
            }
            bo[n + q * s4] = val;
        }
    }
}

// ---------------------------------------------------------------------------
// K3: MFMA conv + fused segment-max pooling (proven r8).
// r16: staging rewritten — thread j<72 loads its 16-float window as 4
// reversed float4, converts once, and writes all 8 phase-shifted bf16x8
// vectors with compile-time shifts (576 ds_write_b128 vs 4608 scalar
// writes). Read region of xr is bit-identical; cols >= 568 may hold
// garbage but are never read by the MFMA path.
__global__ __launch_bounds__(256) void k_conv(
    const float* __restrict__ bands,
    const __hip_bfloat16* __restrict__ filters,
    float* __restrict__ segG)
{
    const int tid  = threadIdx.x;
    const int sig  = blockIdx.y;
    const int c    = blockIdx.x;               // 0..126
    const int band = 31 - __clz(c + 1);
    const int cidx = c + 1 - (1 << band);
    const int poff = 64 * (band + 1) + 512 * ((1 << band) - 1);
    const float* bp = bands + (size_t)sig * BAND_STRIDE + poff + cidx * 512;

    __shared__ __align__(16) __hip_bfloat16 xr[8][584];
    __shared__ float segP[64 * 4];

    if (tid < 72) {
        const int j = tid;
        // xrev[m] = bf16(bp[511-m]); this thread covers m = 8j .. 8j+15.
        // bp[496-8j .. 511-8j] is 16 contiguous, 16B-aligned floats.
        // Worst case (j=71) reads 8 floats before the 64-zero guard:
        // still inside the workspace; lands only in unread LDS columns.
        const float* src = bp + 496 - 8 * j;
        float4 f0 = *(const float4*)(src + 12);
        float4 f1 = *(const float4*)(src + 8);
        float4 f2 = *(const float4*)(src + 4);
        float4 f3 = *(const float4*)(src + 0);
        __hip_bfloat16 w[16];
        w[0]  = __float2bfloat16(f0.w); w[1]  = __float2bfloat16(f0.z);
        w[2]  = __float2bfloat16(f0.y); w[3]  = __float2bfloat16(f0.x);
        w[4]  = __float2bfloat16(f1.w); w[5]  = __float2bfloat16(f1.z);
        w[6]  = __float2bfloat16(f1.y); w[7]  = __float2bfloat16(f1.x);
        w[8]  = __float2bfloat16(f2.w); w[9]  = __float2bfloat16(f2.z);
        w[10] = __float2bfloat16(f2.y); w[11] = __float2bfloat16(f2.x);
        w[12] = __float2bfloat16(f3.w); w[13] = __float2bfloat16(f3.z);
        w[14] = __float2bfloat16(f3.y); w[15] = __float2bfloat16(f3.x);
        #pragma unroll
        for (int p = 0; p < 8; ++p) {          // xr[p][8j..8j+7] = xrev[8j+p ..]
            union { bf16x8 v; __hip_bfloat16 h[8]; } o;
            #pragma unroll
            for (int e = 0; e < 8; ++e) o.h[e] = w[p + e];
            *(bf16x8*)(&xr[p][8 * j]) = o.v;
        }
    }
    __syncthreads();

    const int tl   = tid & 15;
    const int quad = (tid >> 4) & 3;
    const int wave = tid >> 6;

    bf16x8 bf0[4], bf1[4];
    #pragma unroll
    for (int ft = 0; ft < 4; ++ft) {
        const __hip_bfloat16* fp = filters + ((ft * 16 + tl) * 64 + quad * 8);
        bf0[ft] = *(const bf16x8*)(fp);
        bf1[ft] = *(const bf16x8*)(fp + 32);
    }

    int s0 = 511 - wave * 128 - tl + 8 * quad;
    const __hip_bfloat16* xp = &xr[0][0] + (s0 & 7) * 584 + (s0 & ~7);

    const int spc = 512 >> (2 + band);
    float* segO = segG + (size_t)(sig * NBANDS + band) * 64 * 128 + cidx * spc;

    const float NEG = -3.4e38f;
    float run0 = NEG, run1 = NEG, run2 = NEG, run3 = NEG;
    const int per = (band >= 2) ? (1 << (band - 2)) : 1;

    for (int it = 0; it < 8; ++it) {
        const int t0 = wave * 128 + it * 16;
        bf16x8 a0 = *(const bf16x8*)(xp);
        bf16x8 a1 = *(const bf16x8*)(xp + 32);
        xp -= 16;
        f32x4 ac0 = {0.f,0.f,0.f,0.f}, ac1 = ac0, ac2 = ac0, ac3 = ac0;
        ac0 = __builtin_amdgcn_mfma_f32_16x16x32_bf16(a0, bf0[0], ac0, 0, 0, 0);
        ac0 = __builtin_amdgcn_mfma_f32_16x16x32_bf16(a1, bf1[0], ac0, 0, 0, 0);
        ac1 = __builtin_amdgcn_mfma_f32_16x16x32_bf16(a0, bf0[1], ac1, 0, 0, 0);
        ac1 = __builtin_amdgcn_mfma_f32_16x16x32_bf16(a1, bf1[1], ac1, 0, 0, 0);
        ac2 = __builtin_amdgcn_mfma_f32_16x16x32_bf16(a0, bf0[2], ac2, 0, 0, 0);
        ac2 = __builtin_amdgcn_mfma_f32_16x16x32_bf16(a1, bf1[2], ac2, 0, 0, 0);
        ac3 = __builtin_amdgcn_mfma_f32_16x16x32_bf16(a0, bf0[3], ac3, 0, 0, 0);
        ac3 = __builtin_amdgcn_mfma_f32_16x16x32_bf16(a1, bf1[3], ac3, 0, 0, 0);
        float m0 = fmaxf(fmaxf(ac0[0], ac0[1]), fmaxf(ac0[2], ac0[3]));
        float m1 = fmaxf(fmaxf(ac1[0], ac1[1]), fmaxf(ac1[2], ac1[3]));
        float m2 = fmaxf(fmaxf(ac2[0], ac2[1]), fmaxf(ac2[2], ac2[3]));
        float m3 = fmaxf(fmaxf(ac3[0], ac3[1]), fmaxf(ac3[2], ac3[3]));
        if (band == 0) {
            int sb = (t0 >> 2) + quad;
            segO[(tl     ) * 128 + sb] = m0;
            segO[(tl + 16) * 128 + sb] = m1;
            segO[(tl + 32) * 128 + sb] = m2;
            segO[(tl + 48) * 128 + sb] = m3;
        } else if (band == 1) {
            m0 = fmaxf(m0, __shfl_xor(m0, 16));
            m1 = fmaxf(m1, __shfl_xor(m1, 16));
            m2 = fmaxf(m2, __shfl_xor(m2, 16));
            m3 = fmaxf(m3, __shfl_xor(m3, 16));
            if ((quad & 1) == 0) {
                int sb = (t0 >> 3) + (quad >> 1);
                segO[(tl     ) * 128 + sb] = m0;
                segO[(tl + 16) * 128 + sb] = m1;
                segO[(tl + 32) * 128 + sb] = m2;
                segO[(tl + 48) * 128 + sb] = m3;
            }
        } else {
            m0 = fmaxf(m0, __shfl_xor(m0, 16)); m0 = fmaxf(m0, __shfl_xor(m0, 32));
            m1 = fmaxf(m1, __shfl_xor(m1, 16)); m1 = fmaxf(m1, __shfl_xor(m1, 32));
            m2 = fmaxf(m2, __shfl_xor(m2, 16)); m2 = fmaxf(m2, __shfl_xor(m2, 32));
            m3 = fmaxf(m3, __shfl_xor(m3, 16)); m3 = fmaxf(m3, __shfl_xor(m3, 32));
            run0 = fmaxf(run0, m0); run1 = fmaxf(run1, m1);
            run2 = fmaxf(run2, m2); run3 = fmaxf(run3, m3);
            if (((it + 1) & (per - 1)) == 0) {
                int sb = t0 >> (2 + band);
                float rv = quad == 0 ? run0 : quad == 1 ? run1
                         : quad == 2 ? run2 : run3;
                segO[(tl + 16 * quad) * 128 + sb] = rv;
                run0 = NEG; run1 = NEG; run2 = NEG; run3 = NEG;
            }
        }
    }
    if (band == 6) {
        float rv = quad == 0 ? run0 : quad == 1 ? run1
                 : quad == 2 ? run2 : run3;
        segP[(tl + 16 * quad) * 4 + wave] = rv;
        __syncthreads();
        if (tid < 128) {
            int f = tid & 63, sg = tid >> 6;
            segO[f * 128 + sg] =
                fmaxf(segP[f * 4 + 2 * sg], segP[f * 4 + 2 * sg + 1]);
        }
    }
}

// ---------------------------------------------------------------------------
// K4: pool + top-128 via radix select + small bitonic sort (proven r9)
__global__ __launch_bounds__(256) void k_topk(
    const float* __restrict__ segG,
    float* __restrict__ topv, int* __restrict__ topi)
{
    const int tid = threadIdx.x;
    const int band = blockIdx.x, sig = blockIdx.y;
    const float* segB = segG + (size_t)(sig * NBANDS + band) * 64 * 128;

    __shared__ unsigned hist[256];
    __shared__ unsigned scan[256];
    __shared__ unsigned long long list[512];
    __shared__ int sh_B, sh_nA, sh_cnt, sh_num;

    unsigned long long kk[16];
    #pragma unroll
    for (int q = 0; q < 16; ++q) {
        int i = q * 256 + tid;
        int f = i >> 6, t = i & 63;
        const float* sg = segB + f * 128;
        float m = fmaxf(sg[2 * t], sg[2 * t + 1]);
        if (t > 0)  m = fmaxf(m, sg[2 * t - 1]);
        if (t < 63) m = fmaxf(m, sg[2 * t + 2]);
        kk[q] = ((unsigned long long)encf(m) << 32) | (unsigned)(4095 - i);
    }

    int shift = 56;
    unsigned long long prefix = 0;
    int nA = 0;
    for (int lev = 0; lev < 8; ++lev) {
        hist[tid] = 0;
        __syncthreads();
        #pragma unroll
        for (int q = 0; q < 16; ++q) {
            bool inpre = (lev == 0) || ((kk[q] >> (shift + 8)) == prefix);
            if (inpre) atomicAdd(&hist[(unsigned)((kk[q] >> shift) & 255u)], 1u);
        }
        __syncthreads();
        scan[tid] = hist[tid];
        __syncthreads();
        for (int off = 1; off < 256; off <<= 1) {
            unsigned v = scan[tid] + ((tid + off < 256) ? scan[tid + off] : 0u);
            __syncthreads();
            scan[tid] = v;
            __syncthreads();
        }
        {
            unsigned ge = (unsigned)nA + scan[tid];
            unsigned gt = (unsigned)nA + ((tid < 255) ? scan[tid + 1] : 0u);
            if (ge >= 128u && gt < 128u) {
                sh_B = tid; sh_nA = (int)gt; sh_cnt = (int)hist[tid];
            }
        }
        __syncthreads();
        prefix = (prefix << 8) | (unsigned)sh_B;
        nA = sh_nA;
        if (nA + sh_cnt <= 511 || shift == 0) break;
        shift -= 8;
        __syncthreads();
    }

    list[tid] = 0ull; list[tid + 256] = 0ull;
    if (tid == 0) sh_num = 0;
    __syncthreads();
    #pragma unroll
    for (int q = 0; q < 16; ++q) {
        if ((kk[q] >> shift) >= prefix) {
            int p = atomicAdd(&sh_num, 1);
            if (p < 512) list[p] = kk[q];
        }
    }
    __syncthreads();

    for (int k = 2; k <= 512; k <<= 1) {
        for (int j = k >> 1; j > 0; j >>= 1) {
            for (int w = tid; w < 512; w += 256) {
                int l = w ^ j;
                if (l > w) {
                    unsigned long long av = list[w], bv = list[l];
                    bool up = ((w & k) == 0);
                    if ((av > bv) == up) { list[w] = bv; list[l] = av; }
                }
            }
            __syncthreads();
        }
    }
    if (tid < K_TOP) {
        unsigned long long key = list[511 - tid];
        const size_t ob = ((size_t)sig * NBANDS + band) * K_TOP + tid;
        topv[ob] = decf((unsigned)(key >> 32));
        topi[ob] = 4095 - (int)(key & 0xFFFFFFFFu);
    }
}

// ---------------------------------------------------------------------------
// K5: loss with LDS-prefetched indices (breaks the dependent-load chain) +
// counter-elected finalize (value-level codes only; scans dropped).
__global__ __launch_bounds__(256) void k_loss(
    const float* __restrict__ topv, const int* __restrict__ topi,
    const __hip_bfloat16* __restrict__ PT, const __hip_bfloat16* __restrict__ PF,
    float* __restrict__ accum, int* __restrict__ counter,
    unsigned* __restrict__ out)
{
    const int tid = threadIdx.x;
    const int band = blockIdx.x, b = blockIdx.y;
    const size_t bt = ((size_t)b * NBANDS + band) * K_TOP;
    const size_t br = ((size_t)(8 + b) * NBANDS + band) * K_TOP;
    __shared__ float vT[128], vR[128];
    __shared__ int   iT[128], iR[128];
    if (tid < 128) { vT[tid] = topv[bt + tid]; iT[tid] = topi[bt + tid]; }
    else { int j = tid - 128; vR[j] = topv[br + j]; iR[j] = topi[br + j]; }
    __syncthreads();
    float sum = 0.f;
    if (tid < 128) {
        #pragma unroll 4
        for (int k = 0; k < K_TOP; ++k) {
            float a = vT[k] * bf2f(PT[(iT[k] & 63) * 128 + tid]);
            float c = vR[k] * bf2f(PT[(iR[k] & 63) * 128 + tid]);
            sum += fabsf(a - c);
        }
    } else {
        const int j = tid - 128;
        #pragma unroll 4
        for (int k = 0; k < K_TOP; ++k) {
            float a = bf2f(PF[(iT[k] >> 6) * 128 + j]);
            float c = bf2f(PF[(iR[k] >> 6) * 128 + j]);
            sum += fabsf(a - c);
        }
    }
    __shared__ float red[256];
    __shared__ int amLast;
    red[tid] = sum;
    __syncthreads();
    for (int ofs = 128; ofs > 0; ofs >>= 1) {
        if (tid < ofs) red[tid] += red[tid + ofs];
        __syncthreads();
    }
    if (tid == 0) {
        atomicAdd(accum, red[0]);
        __threadfence();
        amLast = (atomicAdd(counter, 1) == NBANDS * 8 - 1);
    }
    __syncthreads();
    if (!amLast) return;
    if (tid == 0) {
        __threadfence();
        float L = atomicAdd(accum, 0.f) * (1.0f / 1835008.0f);
        unsigned lu = __float_as_uint(L);
        bool isnanL = ((lu & 0x7F800000u) == 0x7F800000u) && (lu & 0x007FFFFFu);
        float code;
        if      (isnanL)           code = 500.f;
        else if (L == 0.f)         code = 400.f;
        else if (fabsf(L) < 1e-6f) code = 600.f;
        else                       code = L;
        unsigned fb = __float_as_uint(code);
        unsigned hb = (fb + 0x7FFFu + ((fb >> 16) & 1u)) >> 16;
        out[0] = (hb << 16) | hb;    // dual-format store (proven r4)
    }
}

// ---------------------------------------------------------------------------
extern "C" void kernel_launch(void* const* d_in, const int* in_sizes, int n_in,
                              void* d_out, int out_size, void* d_ws, size_t ws_size,
                              hipStream_t stream)
{
    float* C      = (float*)d_ws;                          // 524288 f
    float* bands  = C + (size_t)NSIG * NBINS * 2;          // 1047552 f
    float* segG   = bands + (size_t)NSIG * BAND_STRIDE;    // 917504 f
    float* topv   = segG + (size_t)NSIG * NBANDS * 64 * 128; // 14336 f
    int*   topi   = (int*)(topv + (size_t)NSIG * NBANDS * K_TOP);
    float* accum  = (float*)(topi + (size_t)NSIG * NBANDS * K_TOP);
    int*   counter= (int*)(accum + 1);
    __hip_bfloat16* staged = (__hip_bfloat16*)(accum + 4);  // 16B-aligned
    float* TG = (float*)(staged + SST_TOT);   // T and G alias (T dead before G)
    float* T  = TG;
    float* G  = TG;

    const __hip_bfloat16* fst = staged + SST_F;
    const __hip_bfloat16* pts = staged + SST_PT;
    const __hip_bfloat16* pfs = staged + SST_PF;

    k_fwd1   <<<dim3(9, NSIG),       256, 0, stream>>>(d_in[0], d_in[1],
                 d_in[2], d_in[3], d_in[4], staged, bands, accum, counter, T);
    k_fwd2   <<<dim3(128, NSIG),     128, 0, stream>>>(T, C);
    k_synthA <<<dim3(64, NSIG),      256, 0, stream>>>(C, G);
    k_synthB <<<dim3(64, NSIG),      256, 0, stream>>>(C, G, bands);
    k_conv   <<<dim3(127, NSIG),     256, 0, stream>>>(bands, fst, segG);
    k_topk   <<<dim3(NBANDS, NSIG),  256, 0, stream>>>(segG, topv, topi);
    k_loss   <<<dim3(NBANDS, 8),     256, 0, stream>>>(topv, topi, pts, pfs,
                 accum, counter, (unsigned*)d_out);
}

// Round 5
// 190.778 us; speedup vs baseline: 1.7787x; 1.0418x over previous
//
#include <hip/hip_runtime.h>
#include <hip/hip_bf16.h>

#define N_SAMP    32768
#define NBINS     16384
#define NSIG      16
#define NBANDS    7
#define K_TOP     128
// padded per-signal band buffer: 64 zero-floats of guard before each band
#define BAND_STRIDE 65472   // 448 pad + 65024 payload

// staged bf16 layout (small): [filters 4096 | PT 8192 | PF 8192]
#define SST_F   0
#define SST_PT  4096
#define SST_PF  12288
#define SST_TOT 20480

#define TWO_PI 6.283185307179586f

typedef __attribute__((ext_vector_type(8))) short bf16x8;
typedef __attribute__((ext_vector_type(4))) float f32x4;

__device__ __forceinline__ float bf2f(__hip_bfloat16 v) { return __bfloat162float(v); }

__device__ __forceinline__ unsigned encf(float f) {
    unsigned u = __float_as_uint(f);
    return (u & 0x80000000u) ? ~u : (u | 0x80000000u);
}
__device__ __forceinline__ float decf(unsigned u) {
    return __uint_as_float((u & 0x80000000u) ? (u ^ 0x80000000u) : ~u);
}

__device__ __forceinline__ int band_M1sh(int b) { return b < 3 ? 4 : (b < 4 ? 5 : 6); }
__device__ __forceinline__ int band_Lsh(int b) {
    return b == 0 ? 5 : (b == 1 ? 6 : (b < 5 ? 7 : (b == 5 ? 8 : 9)));
}
__device__ __forceinline__ int band_M2sh(int b) {
    return b < 2 ? 4 : (b < 5 ? 5 : (b == 5 ? 6 : 7));
}

// ---------------------------------------------------------------------------
// K_fwd1 — MFMA step 1 (128x256 decomposition), staging folded in (r15),
// ni-range split (r16). r17: staging block also zeroes lossCnt (topk+loss
// fusion counters). Fence-free: staged data crosses kernel boundaries.
__global__ __launch_bounds__(256) void k_fwd1(
    const void* __restrict__ tgt, const void* __restrict__ rec,
    const void* __restrict__ f, const void* __restrict__ pt,
    const void* __restrict__ pf,
    __hip_bfloat16* __restrict__ staged,
    float* __restrict__ bands, float* __restrict__ accum,
    int* __restrict__ counter, int* __restrict__ lossCnt,
    float* __restrict__ T)
{
    const int tid   = threadIdx.x;
    const int sig   = blockIdx.y;

    if (blockIdx.x == 8) {                     // staging slice for this sig
        float pv0 = bf2f(((const __hip_bfloat16*)tgt)[tid & 63]);
        int bad0 = (fabsf(pv0) > 1e8f) || (pv0 != pv0);
        const int isf = (__ballot(bad0) != 0ull);
        #pragma unroll
        for (int k = 0; k < 5; ++k) {          // 1280 elements per sig
            int id = sig * 1280 + k * 256 + tid;
            const void* src; int idx;
            if (id < SST_PT)      { src = f;  idx = id; }
            else if (id < SST_PF) { src = pt; idx = id - SST_PT; }
            else                  { src = pf; idx = id - SST_PF; }
            float v = isf ? ((const float*)src)[idx]
                          : bf2f(((const __hip_bfloat16*)src)[idx]);
            staged[id] = __float2bfloat16(v);
        }
        for (int i = tid; i < 448; i += 256) { // band guards for this sig
            int g = i >> 6, j = i & 63;
            int off = 64 * g + 512 * ((1 << g) - 1);
            bands[(size_t)sig * BAND_STRIDE + off + j] = 0.f;
        }
        if (sig == 0) {
            if (tid == 0) { accum[0] = 0.f; counter[0] = 0; }
            if (tid < 8 * NBANDS) lossCnt[tid] = 0;   // 56
        }
        return;
    }

    const int nbase = (blockIdx.x & 1) * 128;        // n2 half
    const int kgrp  = ((blockIdx.x >> 1) & 1) * 64;  // k1 group base
    const int nqh   = (blockIdx.x >> 2) & 1;         // ni half (n2 quarter)
    __shared__ __align__(16) __hip_bfloat16 xT[64][136];  // [n2-local][n1]
    __shared__ float ct[128], st[128];
    __shared__ float2 t256[256];               // W_32768^(128a) = W_256^a, e^{-i}
    __shared__ float2 tF[128];                 // W_32768^a, a<128, e^{-i}

    {
        float sv, cv;
        sincosf(TWO_PI * (float)tid * (1.f / 256.f), &sv, &cv);
        t256[tid] = make_float2(cv, -sv);
        if (tid < 128) {
            sincosf(TWO_PI * (float)tid * (1.f / 128.f), &sv, &cv);
            ct[tid] = cv; st[tid] = sv;
            sincosf(TWO_PI * (float)tid * (1.f / 32768.f), &sv, &cv);
            tF[tid] = make_float2(cv, -sv);
        }
    }

    float pv = bf2f(((const __hip_bfloat16*)tgt)[tid & 63]);
    int bad = (fabsf(pv) > 1e8f) || (pv != pv);
    const int isf32 = (__ballot(bad) != 0ull);
    const void* xsrc = (sig < 8) ? tgt : rec;
    const int soff = (sig & 7) * N_SAMP;

    // stage transpose: 64 rows (this block's n2 quarter), thread covers a
    // 32-wide n1 quarter of one row
    const int rloc = tid & 63;
    const int chb  = (tid >> 6) * 32;
    for (int c8 = 0; c8 < 32; c8 += 8) {
        union { bf16x8 v; __hip_bfloat16 h[8]; } u;
        #pragma unroll
        for (int uu = 0; uu < 8; ++uu) {
            int n1 = chb + c8 + uu;
            int gi = soff + n1 * 256 + nbase + nqh * 64 + rloc;
            float xv = isf32 ? ((const float*)xsrc)[gi]
                             : bf2f(((const __hip_bfloat16*)xsrc)[gi]);
            u.h[uu] = __float2bfloat16(xv);
        }
        *(bf16x8*)(&xT[rloc][chb + c8]) = u.v;
    }
    __syncthreads();

    const int tl = tid & 15, quad = (tid >> 4) & 3, w = tid >> 6;
    const int k1 = kgrp + w * 16 + tl;         // A row m = lane&15
    bf16x8 Arh[4], Arl[4], Aih[4], Ail[4];
    #pragma unroll
    for (int ki = 0; ki < 4; ++ki) {
        union { bf16x8 v; __hip_bfloat16 h[8]; } rh, rl, ih, il;
        #pragma unroll
        for (int j = 0; j < 8; ++j) {
            int n1 = ki * 32 + quad * 8 + j;
            int tt = (k1 * n1) & 127;
            float wre = ct[tt], wim = -st[tt]; // e^{-ia}
            __hip_bfloat16 h1 = __float2bfloat16(wre);
            rh.h[j] = h1;
            rl.h[j] = __float2bfloat16(wre - bf2f(h1));
            __hip_bfloat16 h2 = __float2bfloat16(wim);
            ih.h[j] = h2;
            il.h[j] = __float2bfloat16(wim - bf2f(h2));
        }
        Arh[ki] = rh.v; Arl[ki] = rl.v; Aih[ki] = ih.v; Ail[ki] = il.v;
    }

    float2* To = (float2*)T + (size_t)sig * 128 * 256;
    const int mk = kgrp + w * 16 + quad * 4;   // D row = quad*4+reg
    for (int ni = 0; ni < 4; ++ni) {
        bf16x8 B[4];
        #pragma unroll
        for (int ki = 0; ki < 4; ++ki)         // B[k=n1][n=n2]: b128, aligned
            B[ki] = *(const bf16x8*)(&xT[ni * 16 + tl][ki * 32 + quad * 8]);
        f32x4 aR = {0.f,0.f,0.f,0.f}, aI = {0.f,0.f,0.f,0.f};
        #pragma unroll
        for (int ki = 0; ki < 4; ++ki) {
            aR = __builtin_amdgcn_mfma_f32_16x16x32_bf16(Arh[ki], B[ki], aR, 0, 0, 0);
            aR = __builtin_amdgcn_mfma_f32_16x16x32_bf16(Arl[ki], B[ki], aR, 0, 0, 0);
            aI = __builtin_amdgcn_mfma_f32_16x16x32_bf16(Aih[ki], B[ki], aI, 0, 0, 0);
            aI = __builtin_amdgcn_mfma_f32_16x16x32_bf16(Ail[ki], B[ki], aI, 0, 0, 0);
        }
        const int n2 = nbase + nqh * 64 + ni * 16 + tl;
        #pragma unroll
        for (int rg = 0; rg < 4; ++rg) {
            int k1e = mk + rg;
            int m = k1e * n2;                  // < 32768, no mod needed
            float2 e1 = t256[m >> 7];
            float2 e2 = tF[m & 127];
            float er = e1.x * e2.x - e1.y * e2.y;   // e^{-i 2pi m/32768}
            float ei = e1.x * e2.y + e1.y * e2.x;
            float Tr = aR[rg] * er - aI[rg] * ei;
            float Ti = aI[rg] * er + aR[rg] * ei;
            To[(size_t)k1e * 256 + n2] = make_float2(Tr, Ti);
        }
    }
}

// Step2 with 4 independent rotation chains (proven r10) + W_256 LDS table (r13)
__global__ __launch_bounds__(128) void k_fwd2(
    const float* __restrict__ T, float* __restrict__ C)
{
    const int k2  = threadIdx.x;              // < 128
    const int k1  = blockIdx.x;
    const int sig = blockIdx.y;
    __shared__ float2 Ts[256];
    __shared__ float2 tw[256];                // e^{-i 2pi a/256}
    const float2* Tin = (const float2*)T + ((size_t)sig * 128 + k1) * 256;
    for (int i = k2; i < 256; i += 128) Ts[i] = Tin[i];
    {
        float sv, cv;
        sincosf(TWO_PI * (float)k2 * (1.f / 256.f), &sv, &cv);
        tw[k2]       = make_float2(cv, -sv);
        tw[k2 + 128] = make_float2(-cv, sv);   // angle + pi
    }
    __syncthreads();
    float er[4], ei[4];
    #pragma unroll
    for (int c = 0; c < 4; ++c) {
        float2 e = tw[(c * k2) & 255];
        er[c] = e.x; ei[c] = e.y;
    }
    float2 e4 = tw[(4 * k2) & 255];
    const float c4 = e4.x, s4 = e4.y;
    float Xr[4] = {0.f,0.f,0.f,0.f}, Xi[4] = {0.f,0.f,0.f,0.f};
    for (int n2 = 0; n2 < 256; n2 += 4) {
        #pragma unroll
        for (int c = 0; c < 4; ++c) {
            float2 t = Ts[n2 + c];
            Xr[c] += t.x * er[c] - t.y * ei[c];
            Xi[c] += t.x * ei[c] + t.y * er[c];
            float nr = er[c] * c4 - ei[c] * s4;
            ei[c]    = er[c] * s4 + ei[c] * c4;
            er[c] = nr;
        }
    }
    const float inv = 5.5242717280199030e-3f;   // 1/sqrt(32768)
    float xr = (Xr[0] + Xr[1]) + (Xr[2] + Xr[3]);
    float xi = (Xi[0] + Xi[1]) + (Xi[2] + Xi[3]);
    float2* Co = (float2*)C + (size_t)sig * NBINS;
    Co[k1 + 128 * k2] = make_float2(xr * inv, xi * inv);
}

// ---------------------------------------------------------------------------
// Band synthesis — quarter-band decimation (proven r11)
__global__ __launch_bounds__(256) void k_synthA(
    const float* __restrict__ C, float* __restrict__ G)
{
    const int tid = threadIdx.x;
    const int sig = blockIdx.y;
    const int bix = 63 - blockIdx.x;
    const int band = (bix == 0) ? 0 : (32 - __clz(bix));
    const int lbx  = (band == 0) ? 0 : (bix - (1 << (band - 1)));
    const int s    = 512 << band;
    const int m1sh = band_M1sh(band);
    const int lsh  = band_Lsh(band);
    const int m2sh = band_M2sh(band);
    const int M2   = 1 << m2sh;
    const int L    = 1 << lsh;
    const int L4   = L >> 2;
    const int a    = (band == 0) ? 0 : (128 << band);
    const int tix  = lbx * 256 + tid;
    const int j1lo = (lbx * 256) >> (lsh - 2);
    int j1cnt = 256 >> (lsh - 2);
    if (j1cnt > (1 << m1sh)) j1cnt = 1 << m1sh;
    __shared__ float2 Ds[256];
    const float2* D = (const float2*)C + (size_t)sig * NBINS + a;
    for (int i = tid; i < (j1cnt << m2sh); i += 256) {
        int j1o = i >> m2sh, j2 = i & (M2 - 1);
        Ds[i] = D[(j1lo + j1o) + (j2 << m1sh)];
    }
    __syncthreads();
    if (tix >= (128 << band)) return;
    const int j1o = (tix >> (lsh - 2)) - j1lo;
    const int m   = tix & (L4 - 1);
    const float2* Dj = Ds + (j1o << m2sh);
    float e0r = 1.f, e0i = 0.f, e1r, e1i, sr, si;
    sincosf(TWO_PI * (float)m / (float)L, &e1i, &e1r);
    sincosf(TWO_PI * (float)(2 * m) / (float)L, &si, &sr);
    float ar[4] = {0.f,0.f,0.f,0.f}, ai[4] = {0.f,0.f,0.f,0.f};
    for (int j2 = 0; j2 < M2; j2 += 4) {
        {   float2 d = Dj[j2];
            float tr = d.x * e0r - d.y * e0i, ti = d.x * e0i + d.y * e0r;
            ar[0] += tr; ai[0] += ti; ar[1] += tr; ai[1] += ti;
            ar[2] += tr; ai[2] += ti; ar[3] += tr; ai[3] += ti;
            float nr = e0r * sr - e0i * si; e0i = e0r * si + e0i * sr; e0r = nr;
        }
        {   float2 d = Dj[j2 + 1];
            float tr = d.x * e1r - d.y * e1i, ti = d.x * e1i + d.y * e1r;
            ar[0] += tr; ai[0] += ti;
            ar[1] -= ti; ai[1] += tr;
            ar[2] -= tr; ai[2] -= ti;
            ar[3] += ti; ai[3] -= tr;
            float nr = e1r * sr - e1i * si; e1i = e1r * si + e1i * sr; e1r = nr;
        }
        {   float2 d = Dj[j2 + 2];
            float tr = d.x * e0r - d.y * e0i, ti = d.x * e0i + d.y * e0r;
            ar[0] += tr; ai[0] += ti;
            ar[1] -= tr; ai[1] -= ti;
            ar[2] += tr; ai[2] += ti;
            ar[3] -= tr; ai[3] -= ti;
            float nr = e0r * sr - e0i * si; e0i = e0r * si + e0i * sr; e0r = nr;
        }
        {   float2 d = Dj[j2 + 3];
            float tr = d.x * e1r - d.y * e1i, ti = d.x * e1i + d.y * e1r;
            ar[0] += tr; ai[0] += ti;
            ar[1] += ti; ai[1] -= tr;
            ar[2] -= tr; ai[2] -= ti;
            ar[3] -= ti; ai[3] += tr;
            float nr = e1r * sr - e1i * si; e1i = e1r * si + e1i * sr; e1r = nr;
        }
    }
    const float sc = 2.f * rsqrtf((float)s);
    float2* Go = (float2*)G + (size_t)sig * 65024 + 512 * ((1 << band) - 1);
    const int base = ((tix >> (lsh - 2)) << lsh) + m;
    #pragma unroll
    for (int q = 0; q < 4; ++q)
        Go[base + q * L4] = make_float2(ar[q] * sc, ai[q] * sc);
}

__global__ __launch_bounds__(256) void k_synthB(
    const float* __restrict__ C, const float* __restrict__ G,
    float* __restrict__ bands)
{
    const int tid = threadIdx.x;
    const int sig = blockIdx.y;
    const int bix = 63 - blockIdx.x;
    const int band = (bix == 0) ? 0 : (32 - __clz(bix));
    const int lbx  = (band == 0) ? 0 : (bix - (1 << (band - 1)));
    const int s    = 512 << band;
    const int M1   = 1 << band_M1sh(band);
    const int lsh  = band_Lsh(band);
    const int n    = lbx * 256 + tid;
    const int s4   = s >> 2;
    if (n >= s4) return;
    const int m    = n & ((1 << lsh) - 1);
    const float2* Gi = (const float2*)G + (size_t)sig * 65024 + 512 * ((1 << band) - 1);
    float e0r = 1.f, e0i = 0.f, e1r, e1i, sr, si;
    sincosf(TWO_PI * (float)n / (float)s, &e1i, &e1r);
    sincosf(TWO_PI * (float)(2 * n) / (float)s, &si, &sr);
    float zr[4] = {0.f,0.f,0.f,0.f}, zi[4] = {0.f,0.f,0.f,0.f};
    for (int j1 = 0; j1 < M1; j1 += 4) {
        {   float2 g = Gi[((j1 + 0) << lsh) + m];
            float tr = g.x * e0r - g.y * e0i, ti = g.x * e0i + g.y * e0r;
            zr[0] += tr; zi[0] += ti; zr[1] += tr; zi[1] += ti;
            zr[2] += tr; zi[2] += ti; zr[3] += tr; zi[3] += ti;
            float nr = e0r * sr - e0i * si; e0i = e0r * si + e0i * sr; e0r = nr;
        }
        {   float2 g = Gi[((j1 + 1) << lsh) + m];
            float tr = g.x * e1r - g.y * e1i, ti = g.x * e1i + g.y * e1r;
            zr[0] += tr; zi[0] += ti;
            zr[1] -= ti; zi[1] += tr;
            zr[2] -= tr; zi[2] -= ti;
            zr[3] += ti; zi[3] -= tr;
            float nr = e1r * sr - e1i * si; e1i = e1r * si + e1i * sr; e1r = nr;
        }
        {   float2 g = Gi[((j1 + 2) << lsh) + m];
            float tr = g.x * e0r - g.y * e0i, ti = g.x * e0i + g.y * e0r;
            zr[0] += tr; zi[0] += ti;
            zr[1] -= tr; zi[1] -= ti;
            zr[2] += tr; zi[2] += ti;
            zr[3] -= tr; zi[3] -= ti;
            float nr = e0r * sr - e0i * si; e0i = e0r * si + e0i * sr; e0r = nr;
        }
        {   float2 g = Gi[((j1 + 3) << lsh) + m];
            float tr = g.x * e1r - g.y * e1i, ti = g.x * e1i + g.y * e1r;
            zr[0] += tr; zi[0] += ti;
            zr[1] += ti; zi[1] -= tr;
            zr[2] -= tr; zi[2] -= ti;
            zr[3] -= ti; zi[3] += tr;
            float nr = e1r * sr - e1i * si; e1i = e1r * si + e1i * sr; e1r = nr;
        }
    }
    const int poff = 64 * (band + 1) + 512 * ((1 << band) - 1);
    float* bo = bands + (size_t)sig * BAND_STRIDE + poff;
    if (band == 0) {
        const float dc = C[(size_t)sig * NBINS * 2] * 0.04419417382415922f;
        #pragma unroll
        for (int q = 0; q < 4; ++q) bo[n + q * s4] = zr[q] - dc;
    } else {
        #pragma unroll
        for (int q = 0; q < 4; ++q) {
            float val;
            switch (n & 3) {
                case 0:  val =  zr[q]; break;
                case 1:  val = -zi[q]; break;
                case 2:  val = -zr[q]; break;
                default: val =  zi[q]; break;
            }
            bo[n + q * s4] = val;
        }
    }
}

// ---------------------------------------------------------------------------
// K3: MFMA conv + fused segment-max pooling (proven r8, r16 vector staging)
__global__ __launch_bounds__(256) void k_conv(
    const float* __restrict__ bands,
    const __hip_bfloat16* __restrict__ filters,
    float* __restrict__ segG)
{
    const int tid  = threadIdx.x;
    const int sig  = blockIdx.y;
    const int c    = blockIdx.x;               // 0..126
    const int band = 31 - __clz(c + 1);
    const int cidx = c + 1 - (1 << band);
    const int poff = 64 * (band + 1) + 512 * ((1 << band) - 1);
    const float* bp = bands + (size_t)sig * BAND_STRIDE + poff + cidx * 512;

    __shared__ __align__(16) __hip_bfloat16 xr[8][584];
    __shared__ float segP[64 * 4];

    if (tid < 72) {
        const int j = tid;
        const float* src = bp + 496 - 8 * j;
        float4 f0 = *(const float4*)(src + 12);
        float4 f1 = *(const float4*)(src + 8);
        float4 f2 = *(const float4*)(src + 4);
        float4 f3 = *(const float4*)(src + 0);
        __hip_bfloat16 w[16];
        w[0]  = __float2bfloat16(f0.w); w[1]  = __float2bfloat16(f0.z);
        w[2]  = __float2bfloat16(f0.y); w[3]  = __float2bfloat16(f0.x);
        w[4]  = __float2bfloat16(f1.w); w[5]  = __float2bfloat16(f1.z);
        w[6]  = __float2bfloat16(f1.y); w[7]  = __float2bfloat16(f1.x);
        w[8]  = __float2bfloat16(f2.w); w[9]  = __float2bfloat16(f2.z);
        w[10] = __float2bfloat16(f2.y); w[11] = __float2bfloat16(f2.x);
        w[12] = __float2bfloat16(f3.w); w[13] = __float2bfloat16(f3.z);
        w[14] = __float2bfloat16(f3.y); w[15] = __float2bfloat16(f3.x);
        #pragma unroll
        for (int p = 0; p < 8; ++p) {
            union { bf16x8 v; __hip_bfloat16 h[8]; } o;
            #pragma unroll
            for (int e = 0; e < 8; ++e) o.h[e] = w[p + e];
            *(bf16x8*)(&xr[p][8 * j]) = o.v;
        }
    }
    __syncthreads();

    const int tl   = tid & 15;
    const int quad = (tid >> 4) & 3;
    const int wave = tid >> 6;

    bf16x8 bf0[4], bf1[4];
    #pragma unroll
    for (int ft = 0; ft < 4; ++ft) {
        const __hip_bfloat16* fp = filters + ((ft * 16 + tl) * 64 + quad * 8);
        bf0[ft] = *(const bf16x8*)(fp);
        bf1[ft] = *(const bf16x8*)(fp + 32);
    }

    int s0 = 511 - wave * 128 - tl + 8 * quad;
    const __hip_bfloat16* xp = &xr[0][0] + (s0 & 7) * 584 + (s0 & ~7);

    const int spc = 512 >> (2 + band);
    float* segO = segG + (size_t)(sig * NBANDS + band) * 64 * 128 + cidx * spc;

    const float NEG = -3.4e38f;
    float run0 = NEG, run1 = NEG, run2 = NEG, run3 = NEG;
    const int per = (band >= 2) ? (1 << (band - 2)) : 1;

    for (int it = 0; it < 8; ++it) {
        const int t0 = wave * 128 + it * 16;
        bf16x8 a0 = *(const bf16x8*)(xp);
        bf16x8 a1 = *(const bf16x8*)(xp + 32);
        xp -= 16;
        f32x4 ac0 = {0.f,0.f,0.f,0.f}, ac1 = ac0, ac2 = ac0, ac3 = ac0;
        ac0 = __builtin_amdgcn_mfma_f32_16x16x32_bf16(a0, bf0[0], ac0, 0, 0, 0);
        ac0 = __builtin_amdgcn_mfma_f32_16x16x32_bf16(a1, bf1[0], ac0, 0, 0, 0);
        ac1 = __builtin_amdgcn_mfma_f32_16x16x32_bf16(a0, bf0[1], ac1, 0, 0, 0);
        ac1 = __builtin_amdgcn_mfma_f32_16x16x32_bf16(a1, bf1[1], ac1, 0, 0, 0);
        ac2 = __builtin_amdgcn_mfma_f32_16x16x32_bf16(a0, bf0[2], ac2, 0, 0, 0);
        ac2 = __builtin_amdgcn_mfma_f32_16x16x32_bf16(a1, bf1[2], ac2, 0, 0, 0);
        ac3 = __builtin_amdgcn_mfma_f32_16x16x32_bf16(a0, bf0[3], ac3, 0, 0, 0);
        ac3 = __builtin_amdgcn_mfma_f32_16x16x32_bf16(a1, bf1[3], ac3, 0, 0, 0);
        float m0 = fmaxf(fmaxf(ac0[0], ac0[1]), fmaxf(ac0[2], ac0[3]));
        float m1 = fmaxf(fmaxf(ac1[0], ac1[1]), fmaxf(ac1[2], ac1[3]));
        float m2 = fmaxf(fmaxf(ac2[0], ac2[1]), fmaxf(ac2[2], ac2[3]));
        float m3 = fmaxf(fmaxf(ac3[0], ac3[1]), fmaxf(ac3[2], ac3[3]));
        if (band == 0) {
            int sb = (t0 >> 2) + quad;
            segO[(tl     ) * 128 + sb] = m0;
            segO[(tl + 16) * 128 + sb] = m1;
            segO[(tl + 32) * 128 + sb] = m2;
            segO[(tl + 48) * 128 + sb] = m3;
        } else if (band == 1) {
            m0 = fmaxf(m0, __shfl_xor(m0, 16));
            m1 = fmaxf(m1, __shfl_xor(m1, 16));
            m2 = fmaxf(m2, __shfl_xor(m2, 16));
            m3 = fmaxf(m3, __shfl_xor(m3, 16));
            if ((quad & 1) == 0) {
                int sb = (t0 >> 3) + (quad >> 1);
                segO[(tl     ) * 128 + sb] = m0;
                segO[(tl + 16) * 128 + sb] = m1;
                segO[(tl + 32) * 128 + sb] = m2;
                segO[(tl + 48) * 128 + sb] = m3;
            }
        } else {
            m0 = fmaxf(m0, __shfl_xor(m0, 16)); m0 = fmaxf(m0, __shfl_xor(m0, 32));
            m1 = fmaxf(m1, __shfl_xor(m1, 16)); m1 = fmaxf(m1, __shfl_xor(m1, 32));
            m2 = fmaxf(m2, __shfl_xor(m2, 16)); m2 = fmaxf(m2, __shfl_xor(m2, 32));
            m3 = fmaxf(m3, __shfl_xor(m3, 16)); m3 = fmaxf(m3, __shfl_xor(m3, 32));
            run0 = fmaxf(run0, m0); run1 = fmaxf(run1, m1);
            run2 = fmaxf(run2, m2); run3 = fmaxf(run3, m3);
            if (((it + 1) & (per - 1)) == 0) {
                int sb = t0 >> (2 + band);
                float rv = quad == 0 ? run0 : quad == 1 ? run1
                         : quad == 2 ? run2 : run3;
                segO[(tl + 16 * quad) * 128 + sb] = rv;
                run0 = NEG; run1 = NEG; run2 = NEG; run3 = NEG;
            }
        }
    }
    if (band == 6) {
        float rv = quad == 0 ? run0 : quad == 1 ? run1
                 : quad == 2 ? run2 : run3;
        segP[(tl + 16 * quad) * 4 + wave] = rv;
        __syncthreads();
        if (tid < 128) {
            int f = tid & 63, sg = tid >> 6;
            segO[f * 128 + sg] =
                fmaxf(segP[f * 4 + 2 * sg], segP[f * 4 + 2 * sg + 1]);
        }
    }
}

// ---------------------------------------------------------------------------
// K4 (r17): pool + top-128 via radix select + bitonic sort, now 512 threads
// (8 waves: half the per-thread radix/sort depth, 2x waves in flight), with
// LOSS fused in via 56-counter election (proven amLast pattern at 112-block
// scale — NOT r2's 2032-block fence storm). Selection math and loss
// arithmetic bit-identical; candidate list canonicalized by the
// deterministic bitonic sort.
__global__ __launch_bounds__(512) void k_topk(
    const float* __restrict__ segG,
    float* __restrict__ topv, int* __restrict__ topi,
    const __hip_bfloat16* __restrict__ PT, const __hip_bfloat16* __restrict__ PF,
    int* __restrict__ lossCnt, float* __restrict__ accum,
    int* __restrict__ counter, unsigned* __restrict__ out)
{
    const int tid = threadIdx.x;
    const int band = blockIdx.x, sig = blockIdx.y;
    const float* segB = segG + (size_t)(sig * NBANDS + band) * 64 * 128;

    __shared__ unsigned hist[256];
    __shared__ unsigned scan[256];
    __shared__ unsigned long long list[512];
    __shared__ int sh_B, sh_nA, sh_cnt, sh_num, sh_w2;
    __shared__ float vT[128], vR[128];
    __shared__ int   iT[128], iR[128];
    __shared__ float red[256];
    __shared__ int amLast;

    unsigned long long kk[8];
    #pragma unroll
    for (int q = 0; q < 8; ++q) {
        int i = q * 512 + tid;
        int f = i >> 6, t = i & 63;
        const float* sg = segB + f * 128;
        float m = fmaxf(sg[2 * t], sg[2 * t + 1]);
        if (t > 0)  m = fmaxf(m, sg[2 * t - 1]);
        if (t < 63) m = fmaxf(m, sg[2 * t + 2]);
        kk[q] = ((unsigned long long)encf(m) << 32) | (unsigned)(4095 - i);
    }

    int shift = 56;
    unsigned long long prefix = 0;
    int nA = 0;
    for (int lev = 0; lev < 8; ++lev) {
        if (tid < 256) hist[tid] = 0;
        __syncthreads();
        #pragma unroll
        for (int q = 0; q < 8; ++q) {
            bool inpre = (lev == 0) || ((kk[q] >> (shift + 8)) == prefix);
            if (inpre) atomicAdd(&hist[(unsigned)((kk[q] >> shift) & 255u)], 1u);
        }
        __syncthreads();
        if (tid < 256) scan[tid] = hist[tid];
        __syncthreads();
        for (int off = 1; off < 256; off <<= 1) {
            unsigned v = 0;
            if (tid < 256) v = scan[tid] + ((tid + off < 256) ? scan[tid + off] : 0u);
            __syncthreads();
            if (tid < 256) scan[tid] = v;
            __syncthreads();
        }
        if (tid < 256) {
            unsigned ge = (unsigned)nA + scan[tid];
            unsigned gt = (unsigned)nA + ((tid < 255) ? scan[tid + 1] : 0u);
            if (ge >= 128u && gt < 128u) {
                sh_B = tid; sh_nA = (int)gt; sh_cnt = (int)hist[tid];
            }
        }
        __syncthreads();
        prefix = (prefix << 8) | (unsigned)sh_B;
        nA = sh_nA;
        if (nA + sh_cnt <= 511 || shift == 0) break;
        shift -= 8;
        __syncthreads();
    }

    if (tid < 256) { list[tid] = 0ull; list[tid + 256] = 0ull; }
    if (tid == 0) sh_num = 0;
    __syncthreads();
    #pragma unroll
    for (int q = 0; q < 8; ++q) {
        if ((kk[q] >> shift) >= prefix) {
            int p = atomicAdd(&sh_num, 1);
            if (p < 512) list[p] = kk[q];
        }
    }
    __syncthreads();

    for (int k = 2; k <= 512; k <<= 1) {
        for (int j = k >> 1; j > 0; j >>= 1) {
            const int w = tid;
            const int l = w ^ j;
            if (l > w) {
                unsigned long long av = list[w], bv = list[l];
                bool up = ((w & k) == 0);
                if ((av > bv) == up) { list[w] = bv; list[l] = av; }
            }
            __syncthreads();
        }
    }
    if (tid < K_TOP) {
        unsigned long long key = list[511 - tid];
        const size_t ob = ((size_t)sig * NBANDS + band) * K_TOP + tid;
        topv[ob] = decf((unsigned)(key >> 32));
        topi[ob] = 4095 - (int)(key & 0xFFFFFFFFu);
    }

    // ---- election: second finisher of this (band, sig&7) pair runs loss ----
    __syncthreads();
    if (tid == 0) {
        __threadfence();
        sh_w2 = (atomicAdd(&lossCnt[(sig & 7) * NBANDS + band], 1) == 1);
    }
    __syncthreads();
    if (!sh_w2) return;
    __threadfence();   // acquire: see partner block's topv/topi

    // ---- loss (proven k_loss body; tid < 256 active) ----
    const int b = sig & 7;
    const size_t bt = ((size_t)b * NBANDS + band) * K_TOP;
    const size_t br = ((size_t)(8 + b) * NBANDS + band) * K_TOP;
    if (tid < 128) { vT[tid] = topv[bt + tid]; iT[tid] = topi[bt + tid]; }
    else if (tid < 256) {
        int j = tid - 128; vR[j] = topv[br + j]; iR[j] = topi[br + j];
    }
    __syncthreads();
    float sum = 0.f;
    if (tid < 128) {
        #pragma unroll 4
        for (int k = 0; k < K_TOP; ++k) {
            float a = vT[k] * bf2f(PT[(iT[k] & 63) * 128 + tid]);
            float cc = vR[k] * bf2f(PT[(iR[k] & 63) * 128 + tid]);
            sum += fabsf(a - cc);
        }
    } else if (tid < 256) {
        const int j = tid - 128;
        #pragma unroll 4
        for (int k = 0; k < K_TOP; ++k) {
            float a = bf2f(PF[(iT[k] >> 6) * 128 + j]);
            float cc = bf2f(PF[(iR[k] >> 6) * 128 + j]);
            sum += fabsf(a - cc);
        }
    }
    if (tid < 256) red[tid] = sum;
    __syncthreads();
    for (int ofs = 128; ofs > 0; ofs >>= 1) {
        if (tid < ofs) red[tid] += red[tid + ofs];
        __syncthreads();
    }
    if (tid == 0) {
        atomicAdd(accum, red[0]);
        __threadfence();
        amLast = (atomicAdd(counter, 1) == NBANDS * 8 - 1);
    }
    __syncthreads();
    if (!amLast) return;
    if (tid == 0) {
        __threadfence();
        float L = atomicAdd(accum, 0.f) * (1.0f / 1835008.0f);
        unsigned lu = __float_as_uint(L);
        bool isnanL = ((lu & 0x7F800000u) == 0x7F800000u) && (lu & 0x007FFFFFu);
        float code;
        if      (isnanL)           code = 500.f;
        else if (L == 0.f)         code = 400.f;
        else if (fabsf(L) < 1e-6f) code = 600.f;
        else                       code = L;
        unsigned fb = __float_as_uint(code);
        unsigned hb = (fb + 0x7FFFu + ((fb >> 16) & 1u)) >> 16;
        out[0] = (hb << 16) | hb;    // dual-format store (proven r4)
    }
}

// ---------------------------------------------------------------------------
extern "C" void kernel_launch(void* const* d_in, const int* in_sizes, int n_in,
                              void* d_out, int out_size, void* d_ws, size_t ws_size,
                              hipStream_t stream)
{
    float* C      = (float*)d_ws;                          // 524288 f
    float* bands  = C + (size_t)NSIG * NBINS * 2;          // 1047552 f
    float* segG   = bands + (size_t)NSIG * BAND_STRIDE;    // 917504 f
    float* topv   = segG + (size_t)NSIG * NBANDS * 64 * 128; // 14336 f
    int*   topi   = (int*)(topv + (size_t)NSIG * NBANDS * K_TOP);
    float* accum  = (float*)(topi + (size_t)NSIG * NBANDS * K_TOP);
    int*   counter= (int*)(accum + 1);
    int*   lossCnt= (int*)(accum + 4);                     // 56 ints
    __hip_bfloat16* staged = (__hip_bfloat16*)(accum + 64); // 16B-aligned
    float* TG = (float*)(staged + SST_TOT);   // T and G alias (T dead before G)
    float* T  = TG;
    float* G  = TG;

    const __hip_bfloat16* fst = staged + SST_F;
    const __hip_bfloat16* pts = staged + SST_PT;
    const __hip_bfloat16* pfs = staged + SST_PF;

    k_fwd1   <<<dim3(9, NSIG),       256, 0, stream>>>(d_in[0], d_in[1],
                 d_in[2], d_in[3], d_in[4], staged, bands, accum, counter,
                 lossCnt, T);
    k_fwd2   <<<dim3(128, NSIG),     128, 0, stream>>>(T, C);
    k_synthA <<<dim3(64, NSIG),      256, 0, stream>>>(C, G);
    k_synthB <<<dim3(64, NSIG),      256, 0, stream>>>(C, G, bands);
    k_conv   <<<dim3(127, NSIG),     256, 0, stream>>>(bands, fst, segG);
    k_topk   <<<dim3(NBANDS, NSIG),  512, 0, stream>>>(segG, topv, topi,
                 pts, pfs, lossCnt, accum, counter, (unsigned*)d_out);
}

// Round 6
// 186.061 us; speedup vs baseline: 1.8238x; 1.0254x over previous
//
#include <hip/hip_runtime.h>
#include <hip/hip_bf16.h>

#define N_SAMP    32768
#define NBINS     16384
#define NSIG      16
#define NBANDS    7
#define K_TOP     128
// padded per-signal band buffer: 64 zero-floats of guard before each band
#define BAND_STRIDE 65472   // 448 pad + 65024 payload

// staged bf16 layout (small): [filters 4096 | PT 8192 | PF 8192]
#define SST_F   0
#define SST_PT  4096
#define SST_PF  12288
#define SST_TOT 20480

#define TWO_PI 6.283185307179586f

typedef __attribute__((ext_vector_type(8))) short bf16x8;
typedef __attribute__((ext_vector_type(4))) float f32x4;

__device__ __forceinline__ float bf2f(__hip_bfloat16 v) { return __bfloat162float(v); }

__device__ __forceinline__ unsigned encf(float f) {
    unsigned u = __float_as_uint(f);
    return (u & 0x80000000u) ? ~u : (u | 0x80000000u);
}
__device__ __forceinline__ float decf(unsigned u) {
    return __uint_as_float((u & 0x80000000u) ? (u ^ 0x80000000u) : ~u);
}

__device__ __forceinline__ int band_M1sh(int b) { return b < 3 ? 4 : (b < 4 ? 5 : 6); }
__device__ __forceinline__ int band_Lsh(int b) {
    return b == 0 ? 5 : (b == 1 ? 6 : (b < 5 ? 7 : (b == 5 ? 8 : 9)));
}
__device__ __forceinline__ int band_M2sh(int b) {
    return b < 2 ? 4 : (b < 5 ? 5 : (b == 5 ? 6 : 7));
}

// ---------------------------------------------------------------------------
// K_fwd1 — MFMA step 1 (128x256 decomposition), staging folded in (r15).
// r18: ni-range split to QUARTERS — grid (17,16); 16 work blocks/sig
// (bit0 = n2 half, bit1 = k1 group, bits2-3 = ni quarter). Each block
// stages only the 32 xT rows it consumes; serial MFMA depth = 2 ni.
// 272 blocks total (was 144): >1 block/CU, LDS 13 KB. Bit-identical math.
__global__ __launch_bounds__(256) void k_fwd1(
    const void* __restrict__ tgt, const void* __restrict__ rec,
    const void* __restrict__ f, const void* __restrict__ pt,
    const void* __restrict__ pf,
    __hip_bfloat16* __restrict__ staged,
    float* __restrict__ bands, float* __restrict__ accum,
    int* __restrict__ counter, int* __restrict__ lossCnt,
    float* __restrict__ T)
{
    const int tid   = threadIdx.x;
    const int sig   = blockIdx.y;

    if (blockIdx.x == 16) {                    // staging slice for this sig
        float pv0 = bf2f(((const __hip_bfloat16*)tgt)[tid & 63]);
        int bad0 = (fabsf(pv0) > 1e8f) || (pv0 != pv0);
        const int isf = (__ballot(bad0) != 0ull);
        #pragma unroll
        for (int k = 0; k < 5; ++k) {          // 1280 elements per sig
            int id = sig * 1280 + k * 256 + tid;
            const void* src; int idx;
            if (id < SST_PT)      { src = f;  idx = id; }
            else if (id < SST_PF) { src = pt; idx = id - SST_PT; }
            else                  { src = pf; idx = id - SST_PF; }
            float v = isf ? ((const float*)src)[idx]
                          : bf2f(((const __hip_bfloat16*)src)[idx]);
            staged[id] = __float2bfloat16(v);
        }
        for (int i = tid; i < 448; i += 256) { // band guards for this sig
            int g = i >> 6, j = i & 63;
            int off = 64 * g + 512 * ((1 << g) - 1);
            bands[(size_t)sig * BAND_STRIDE + off + j] = 0.f;
        }
        if (sig == 0) {
            if (tid == 0) { accum[0] = 0.f; counter[0] = 0; }
            if (tid < 8 * NBANDS) lossCnt[tid] = 0;   // 56
        }
        return;
    }

    const int nbase = (blockIdx.x & 1) * 128;        // n2 half
    const int kgrp  = ((blockIdx.x >> 1) & 1) * 64;  // k1 group base
    const int nqq   = (blockIdx.x >> 2) & 3;         // ni quarter
    __shared__ __align__(16) __hip_bfloat16 xT[32][136];  // [n2-local][n1]
    __shared__ float ct[128], st[128];
    __shared__ float2 t256[256];               // W_32768^(128a) = W_256^a, e^{-i}
    __shared__ float2 tF[128];                 // W_32768^a, a<128, e^{-i}

    {
        float sv, cv;
        sincosf(TWO_PI * (float)tid * (1.f / 256.f), &sv, &cv);
        t256[tid] = make_float2(cv, -sv);
        if (tid < 128) {
            sincosf(TWO_PI * (float)tid * (1.f / 128.f), &sv, &cv);
            ct[tid] = cv; st[tid] = sv;
            sincosf(TWO_PI * (float)tid * (1.f / 32768.f), &sv, &cv);
            tF[tid] = make_float2(cv, -sv);
        }
    }

    float pv = bf2f(((const __hip_bfloat16*)tgt)[tid & 63]);
    int bad = (fabsf(pv) > 1e8f) || (pv != pv);
    const int isf32 = (__ballot(bad) != 0ull);
    const void* xsrc = (sig < 8) ? tgt : rec;
    const int soff = (sig & 7) * N_SAMP;

    // stage transpose: 32 rows (this block's ni quarter), thread covers a
    // 16-wide n1 slice of one row
    const int rloc = tid & 31;
    const int chb  = (tid >> 5) * 16;
    for (int c8 = 0; c8 < 16; c8 += 8) {
        union { bf16x8 v; __hip_bfloat16 h[8]; } u;
        #pragma unroll
        for (int uu = 0; uu < 8; ++uu) {
            int n1 = chb + c8 + uu;
            int gi = soff + n1 * 256 + nbase + nqq * 32 + rloc;
            float xv = isf32 ? ((const float*)xsrc)[gi]
                             : bf2f(((const __hip_bfloat16*)xsrc)[gi]);
            u.h[uu] = __float2bfloat16(xv);
        }
        *(bf16x8*)(&xT[rloc][chb + c8]) = u.v;
    }
    __syncthreads();

    const int tl = tid & 15, quad = (tid >> 4) & 3, w = tid >> 6;
    const int k1 = kgrp + w * 16 + tl;         // A row m = lane&15
    bf16x8 Arh[4], Arl[4], Aih[4], Ail[4];
    #pragma unroll
    for (int ki = 0; ki < 4; ++ki) {
        union { bf16x8 v; __hip_bfloat16 h[8]; } rh, rl, ih, il;
        #pragma unroll
        for (int j = 0; j < 8; ++j) {
            int n1 = ki * 32 + quad * 8 + j;
            int tt = (k1 * n1) & 127;
            float wre = ct[tt], wim = -st[tt]; // e^{-ia}
            __hip_bfloat16 h1 = __float2bfloat16(wre);
            rh.h[j] = h1;
            rl.h[j] = __float2bfloat16(wre - bf2f(h1));
            __hip_bfloat16 h2 = __float2bfloat16(wim);
            ih.h[j] = h2;
            il.h[j] = __float2bfloat16(wim - bf2f(h2));
        }
        Arh[ki] = rh.v; Arl[ki] = rl.v; Aih[ki] = ih.v; Ail[ki] = il.v;
    }

    float2* To = (float2*)T + (size_t)sig * 128 * 256;
    const int mk = kgrp + w * 16 + quad * 4;   // D row = quad*4+reg
    for (int ni = 0; ni < 2; ++ni) {
        bf16x8 B[4];
        #pragma unroll
        for (int ki = 0; ki < 4; ++ki)         // B[k=n1][n=n2]: b128, aligned
            B[ki] = *(const bf16x8*)(&xT[ni * 16 + tl][ki * 32 + quad * 8]);
        f32x4 aR = {0.f,0.f,0.f,0.f}, aI = {0.f,0.f,0.f,0.f};
        #pragma unroll
        for (int ki = 0; ki < 4; ++ki) {
            aR = __builtin_amdgcn_mfma_f32_16x16x32_bf16(Arh[ki], B[ki], aR, 0, 0, 0);
            aR = __builtin_amdgcn_mfma_f32_16x16x32_bf16(Arl[ki], B[ki], aR, 0, 0, 0);
            aI = __builtin_amdgcn_mfma_f32_16x16x32_bf16(Aih[ki], B[ki], aI, 0, 0, 0);
            aI = __builtin_amdgcn_mfma_f32_16x16x32_bf16(Ail[ki], B[ki], aI, 0, 0, 0);
        }
        const int n2 = nbase + nqq * 32 + ni * 16 + tl;
        #pragma unroll
        for (int rg = 0; rg < 4; ++rg) {
            int k1e = mk + rg;
            int m = k1e * n2;                  // < 32768, no mod needed
            float2 e1 = t256[m >> 7];
            float2 e2 = tF[m & 127];
            float er = e1.x * e2.x - e1.y * e2.y;   // e^{-i 2pi m/32768}
            float ei = e1.x * e2.y + e1.y * e2.x;
            float Tr = aR[rg] * er - aI[rg] * ei;
            float Ti = aI[rg] * er + aR[rg] * ei;
            To[(size_t)k1e * 256 + n2] = make_float2(Tr, Ti);
        }
    }
}

// Step2 with 4 independent rotation chains (proven r10) + W_256 LDS table (r13)
__global__ __launch_bounds__(128) void k_fwd2(
    const float* __restrict__ T, float* __restrict__ C)
{
    const int k2  = threadIdx.x;              // < 128
    const int k1  = blockIdx.x;
    const int sig = blockIdx.y;
    __shared__ float2 Ts[256];
    __shared__ float2 tw[256];                // e^{-i 2pi a/256}
    const float2* Tin = (const float2*)T + ((size_t)sig * 128 + k1) * 256;
    for (int i = k2; i < 256; i += 128) Ts[i] = Tin[i];
    {
        float sv, cv;
        sincosf(TWO_PI * (float)k2 * (1.f / 256.f), &sv, &cv);
        tw[k2]       = make_float2(cv, -sv);
        tw[k2 + 128] = make_float2(-cv, sv);   // angle + pi
    }
    __syncthreads();
    float er[4], ei[4];
    #pragma unroll
    for (int c = 0; c < 4; ++c) {
        float2 e = tw[(c * k2) & 255];
        er[c] = e.x; ei[c] = e.y;
    }
    float2 e4 = tw[(4 * k2) & 255];
    const float c4 = e4.x, s4 = e4.y;
    float Xr[4] = {0.f,0.f,0.f,0.f}, Xi[4] = {0.f,0.f,0.f,0.f};
    for (int n2 = 0; n2 < 256; n2 += 4) {
        #pragma unroll
        for (int c = 0; c < 4; ++c) {
            float2 t = Ts[n2 + c];
            Xr[c] += t.x * er[c] - t.y * ei[c];
            Xi[c] += t.x * ei[c] + t.y * er[c];
            float nr = er[c] * c4 - ei[c] * s4;
            ei[c]    = er[c] * s4 + ei[c] * c4;
            er[c] = nr;
        }
    }
    const float inv = 5.5242717280199030e-3f;   // 1/sqrt(32768)
    float xr = (Xr[0] + Xr[1]) + (Xr[2] + Xr[3]);
    float xi = (Xi[0] + Xi[1]) + (Xi[2] + Xi[3]);
    float2* Co = (float2*)C + (size_t)sig * NBINS;
    Co[k1 + 128 * k2] = make_float2(xr * inv, xi * inv);
}

// ---------------------------------------------------------------------------
// Band synthesis — quarter-band decimation (proven r11).
// r18: second sincosf replaced by complex square (e^{i2a} = (e^{ia})^2) —
// halves the serial transcendental chain in thread setup.
__global__ __launch_bounds__(256) void k_synthA(
    const float* __restrict__ C, float* __restrict__ G)
{
    const int tid = threadIdx.x;
    const int sig = blockIdx.y;
    const int bix = 63 - blockIdx.x;
    const int band = (bix == 0) ? 0 : (32 - __clz(bix));
    const int lbx  = (band == 0) ? 0 : (bix - (1 << (band - 1)));
    const int s    = 512 << band;
    const int m1sh = band_M1sh(band);
    const int lsh  = band_Lsh(band);
    const int m2sh = band_M2sh(band);
    const int M2   = 1 << m2sh;
    const int L    = 1 << lsh;
    const int L4   = L >> 2;
    const int a    = (band == 0) ? 0 : (128 << band);
    const int tix  = lbx * 256 + tid;
    const int j1lo = (lbx * 256) >> (lsh - 2);
    int j1cnt = 256 >> (lsh - 2);
    if (j1cnt > (1 << m1sh)) j1cnt = 1 << m1sh;
    __shared__ float2 Ds[256];
    const float2* D = (const float2*)C + (size_t)sig * NBINS + a;
    for (int i = tid; i < (j1cnt << m2sh); i += 256) {
        int j1o = i >> m2sh, j2 = i & (M2 - 1);
        Ds[i] = D[(j1lo + j1o) + (j2 << m1sh)];
    }
    __syncthreads();
    if (tix >= (128 << band)) return;
    const int j1o = (tix >> (lsh - 2)) - j1lo;
    const int m   = tix & (L4 - 1);
    const float2* Dj = Ds + (j1o << m2sh);
    float e0r = 1.f, e0i = 0.f, e1r, e1i, sr, si;
    sincosf(TWO_PI * (float)m / (float)L, &e1i, &e1r);
    sr = e1r * e1r - e1i * e1i;               // e^{i 2a} = (e^{ia})^2
    si = 2.f * e1r * e1i;
    float ar[4] = {0.f,0.f,0.f,0.f}, ai[4] = {0.f,0.f,0.f,0.f};
    for (int j2 = 0; j2 < M2; j2 += 4) {
        {   float2 d = Dj[j2];
            float tr = d.x * e0r - d.y * e0i, ti = d.x * e0i + d.y * e0r;
            ar[0] += tr; ai[0] += ti; ar[1] += tr; ai[1] += ti;
            ar[2] += tr; ai[2] += ti; ar[3] += tr; ai[3] += ti;
            float nr = e0r * sr - e0i * si; e0i = e0r * si + e0i * sr; e0r = nr;
        }
        {   float2 d = Dj[j2 + 1];
            float tr = d.x * e1r - d.y * e1i, ti = d.x * e1i + d.y * e1r;
            ar[0] += tr; ai[0] += ti;
            ar[1] -= ti; ai[1] += tr;
            ar[2] -= tr; ai[2] -= ti;
            ar[3] += ti; ai[3] -= tr;
            float nr = e1r * sr - e1i * si; e1i = e1r * si + e1i * sr; e1r = nr;
        }
        {   float2 d = Dj[j2 + 2];
            float tr = d.x * e0r - d.y * e0i, ti = d.x * e0i + d.y * e0r;
            ar[0] += tr; ai[0] += ti;
            ar[1] -= tr; ai[1] -= ti;
            ar[2] += tr; ai[2] += ti;
            ar[3] -= tr; ai[3] -= ti;
            float nr = e0r * sr - e0i * si; e0i = e0r * si + e0i * sr; e0r = nr;
        }
        {   float2 d = Dj[j2 + 3];
            float tr = d.x * e1r - d.y * e1i, ti = d.x * e1i + d.y * e1r;
            ar[0] += tr; ai[0] += ti;
            ar[1] += ti; ai[1] -= tr;
            ar[2] -= tr; ai[2] -= ti;
            ar[3] -= ti; ai[3] += tr;
            float nr = e1r * sr - e1i * si; e1i = e1r * si + e1i * sr; e1r = nr;
        }
    }
    const float sc = 2.f * rsqrtf((float)s);
    float2* Go = (float2*)G + (size_t)sig * 65024 + 512 * ((1 << band) - 1);
    const int base = ((tix >> (lsh - 2)) << lsh) + m;
    #pragma unroll
    for (int q = 0; q < 4; ++q)
        Go[base + q * L4] = make_float2(ar[q] * sc, ai[q] * sc);
}

__global__ __launch_bounds__(256) void k_synthB(
    const float* __restrict__ C, const float* __restrict__ G,
    float* __restrict__ bands)
{
    const int tid = threadIdx.x;
    const int sig = blockIdx.y;
    const int bix = 63 - blockIdx.x;
    const int band = (bix == 0) ? 0 : (32 - __clz(bix));
    const int lbx  = (band == 0) ? 0 : (bix - (1 << (band - 1)));
    const int s    = 512 << band;
    const int M1   = 1 << band_M1sh(band);
    const int lsh  = band_Lsh(band);
    const int n    = lbx * 256 + tid;
    const int s4   = s >> 2;
    if (n >= s4) return;
    const int m    = n & ((1 << lsh) - 1);
    const float2* Gi = (const float2*)G + (size_t)sig * 65024 + 512 * ((1 << band) - 1);
    float e0r = 1.f, e0i = 0.f, e1r, e1i, sr, si;
    sincosf(TWO_PI * (float)n / (float)s, &e1i, &e1r);
    sr = e1r * e1r - e1i * e1i;               // e^{i 2a} = (e^{ia})^2
    si = 2.f * e1r * e1i;
    float zr[4] = {0.f,0.f,0.f,0.f}, zi[4] = {0.f,0.f,0.f,0.f};
    for (int j1 = 0; j1 < M1; j1 += 4) {
        {   float2 g = Gi[((j1 + 0) << lsh) + m];
            float tr = g.x * e0r - g.y * e0i, ti = g.x * e0i + g.y * e0r;
            zr[0] += tr; zi[0] += ti; zr[1] += tr; zi[1] += ti;
            zr[2] += tr; zi[2] += ti; zr[3] += tr; zi[3] += ti;
            float nr = e0r * sr - e0i * si; e0i = e0r * si + e0i * sr; e0r = nr;
        }
        {   float2 g = Gi[((j1 + 1) << lsh) + m];
            float tr = g.x * e1r - g.y * e1i, ti = g.x * e1i + g.y * e1r;
            zr[0] += tr; zi[0] += ti;
            zr[1] -= ti; zi[1] += tr;
            zr[2] -= tr; zi[2] -= ti;
            zr[3] += ti; zi[3] -= tr;
            float nr = e1r * sr - e1i * si; e1i = e1r * si + e1i * sr; e1r = nr;
        }
        {   float2 g = Gi[((j1 + 2) << lsh) + m];
            float tr = g.x * e0r - g.y * e0i, ti = g.x * e0i + g.y * e0r;
            zr[0] += tr; zi[0] += ti;
            zr[1] -= tr; zi[1] -= ti;
            zr[2] += tr; zi[2] += ti;
            zr[3] -= tr; zi[3] -= ti;
            float nr = e0r * sr - e0i * si; e0i = e0r * si + e0i * sr; e0r = nr;
        }
        {   float2 g = Gi[((j1 + 3) << lsh) + m];
            float tr = g.x * e1r - g.y * e1i, ti = g.x * e1i + g.y * e1r;
            zr[0] += tr; zi[0] += ti;
            zr[1] += ti; zi[1] -= tr;
            zr[2] -= tr; zi[2] -= ti;
            zr[3] -= ti; zi[3] += tr;
            float nr = e1r * sr - e1i * si; e1i = e1r * si + e1i * sr; e1r = nr;
        }
    }
    const int poff = 64 * (band + 1) + 512 * ((1 << band) - 1);
    float* bo = bands + (size_t)sig * BAND_STRIDE + poff;
    if (band == 0) {
        const float dc = C[(size_t)sig * NBINS * 2] * 0.04419417382415922f;
        #pragma unroll
        for (int q = 0; q < 4; ++q) bo[n + q * s4] = zr[q] - dc;
    } else {
        #pragma unroll
        for (int q = 0; q < 4; ++q) {
            float val;
            switch (n & 3) {
                case 0:  val =  zr[q]; break;
                case 1:  val = -zi[q]; break;
                case 2:  val = -zr[q]; break;
                default: val =  zi[q]; break;
            }
            bo[n + q * s4] = val;
        }
    }
}

// ---------------------------------------------------------------------------
// K3: MFMA conv + fused segment-max pooling (proven r8, r16 vector staging)
__global__ __launch_bounds__(256) void k_conv(
    const float* __restrict__ bands,
    const __hip_bfloat16* __restrict__ filters,
    float* __restrict__ segG)
{
    const int tid  = threadIdx.x;
    const int sig  = blockIdx.y;
    const int c    = blockIdx.x;               // 0..126
    const int band = 31 - __clz(c + 1);
    const int cidx = c + 1 - (1 << band);
    const int poff = 64 * (band + 1) + 512 * ((1 << band) - 1);
    const float* bp = bands + (size_t)sig * BAND_STRIDE + poff + cidx * 512;

    __shared__ __align__(16) __hip_bfloat16 xr[8][584];
    __shared__ float segP[64 * 4];

    if (tid < 72) {
        const int j = tid;
        const float* src = bp + 496 - 8 * j;
        float4 f0 = *(const float4*)(src + 12);
        float4 f1 = *(const float4*)(src + 8);
        float4 f2 = *(const float4*)(src + 4);
        float4 f3 = *(const float4*)(src + 0);
        __hip_bfloat16 w[16];
        w[0]  = __float2bfloat16(f0.w); w[1]  = __float2bfloat16(f0.z);
        w[2]  = __float2bfloat16(f0.y); w[3]  = __float2bfloat16(f0.x);
        w[4]  = __float2bfloat16(f1.w); w[5]  = __float2bfloat16(f1.z);
        w[6]  = __float2bfloat16(f1.y); w[7]  = __float2bfloat16(f1.x);
        w[8]  = __float2bfloat16(f2.w); w[9]  = __float2bfloat16(f2.z);
        w[10] = __float2bfloat16(f2.y); w[11] = __float2bfloat16(f2.x);
        w[12] = __float2bfloat16(f3.w); w[13] = __float2bfloat16(f3.z);
        w[14] = __float2bfloat16(f3.y); w[15] = __float2bfloat16(f3.x);
        #pragma unroll
        for (int p = 0; p < 8; ++p) {
            union { bf16x8 v; __hip_bfloat16 h[8]; } o;
            #pragma unroll
            for (int e = 0; e < 8; ++e) o.h[e] = w[p + e];
            *(bf16x8*)(&xr[p][8 * j]) = o.v;
        }
    }
    __syncthreads();

    const int tl   = tid & 15;
    const int quad = (tid >> 4) & 3;
    const int wave = tid >> 6;

    bf16x8 bf0[4], bf1[4];
    #pragma unroll
    for (int ft = 0; ft < 4; ++ft) {
        const __hip_bfloat16* fp = filters + ((ft * 16 + tl) * 64 + quad * 8);
        bf0[ft] = *(const bf16x8*)(fp);
        bf1[ft] = *(const bf16x8*)(fp + 32);
    }

    int s0 = 511 - wave * 128 - tl + 8 * quad;
    const __hip_bfloat16* xp = &xr[0][0] + (s0 & 7) * 584 + (s0 & ~7);

    const int spc = 512 >> (2 + band);
    float* segO = segG + (size_t)(sig * NBANDS + band) * 64 * 128 + cidx * spc;

    const float NEG = -3.4e38f;
    float run0 = NEG, run1 = NEG, run2 = NEG, run3 = NEG;
    const int per = (band >= 2) ? (1 << (band - 2)) : 1;

    for (int it = 0; it < 8; ++it) {
        const int t0 = wave * 128 + it * 16;
        bf16x8 a0 = *(const bf16x8*)(xp);
        bf16x8 a1 = *(const bf16x8*)(xp + 32);
        xp -= 16;
        f32x4 ac0 = {0.f,0.f,0.f,0.f}, ac1 = ac0, ac2 = ac0, ac3 = ac0;
        ac0 = __builtin_amdgcn_mfma_f32_16x16x32_bf16(a0, bf0[0], ac0, 0, 0, 0);
        ac0 = __builtin_amdgcn_mfma_f32_16x16x32_bf16(a1, bf1[0], ac0, 0, 0, 0);
        ac1 = __builtin_amdgcn_mfma_f32_16x16x32_bf16(a0, bf0[1], ac1, 0, 0, 0);
        ac1 = __builtin_amdgcn_mfma_f32_16x16x32_bf16(a1, bf1[1], ac1, 0, 0, 0);
        ac2 = __builtin_amdgcn_mfma_f32_16x16x32_bf16(a0, bf0[2], ac2, 0, 0, 0);
        ac2 = __builtin_amdgcn_mfma_f32_16x16x32_bf16(a1, bf1[2], ac2, 0, 0, 0);
        ac3 = __builtin_amdgcn_mfma_f32_16x16x32_bf16(a0, bf0[3], ac3, 0, 0, 0);
        ac3 = __builtin_amdgcn_mfma_f32_16x16x32_bf16(a1, bf1[3], ac3, 0, 0, 0);
        float m0 = fmaxf(fmaxf(ac0[0], ac0[1]), fmaxf(ac0[2], ac0[3]));
        float m1 = fmaxf(fmaxf(ac1[0], ac1[1]), fmaxf(ac1[2], ac1[3]));
        float m2 = fmaxf(fmaxf(ac2[0], ac2[1]), fmaxf(ac2[2], ac2[3]));
        float m3 = fmaxf(fmaxf(ac3[0], ac3[1]), fmaxf(ac3[2], ac3[3]));
        if (band == 0) {
            int sb = (t0 >> 2) + quad;
            segO[(tl     ) * 128 + sb] = m0;
            segO[(tl + 16) * 128 + sb] = m1;
            segO[(tl + 32) * 128 + sb] = m2;
            segO[(tl + 48) * 128 + sb] = m3;
        } else if (band == 1) {
            m0 = fmaxf(m0, __shfl_xor(m0, 16));
            m1 = fmaxf(m1, __shfl_xor(m1, 16));
            m2 = fmaxf(m2, __shfl_xor(m2, 16));
            m3 = fmaxf(m3, __shfl_xor(m3, 16));
            if ((quad & 1) == 0) {
                int sb = (t0 >> 3) + (quad >> 1);
                segO[(tl     ) * 128 + sb] = m0;
                segO[(tl + 16) * 128 + sb] = m1;
                segO[(tl + 32) * 128 + sb] = m2;
                segO[(tl + 48) * 128 + sb] = m3;
            }
        } else {
            m0 = fmaxf(m0, __shfl_xor(m0, 16)); m0 = fmaxf(m0, __shfl_xor(m0, 32));
            m1 = fmaxf(m1, __shfl_xor(m1, 16)); m1 = fmaxf(m1, __shfl_xor(m1, 32));
            m2 = fmaxf(m2, __shfl_xor(m2, 16)); m2 = fmaxf(m2, __shfl_xor(m2, 32));
            m3 = fmaxf(m3, __shfl_xor(m3, 16)); m3 = fmaxf(m3, __shfl_xor(m3, 32));
            run0 = fmaxf(run0, m0); run1 = fmaxf(run1, m1);
            run2 = fmaxf(run2, m2); run3 = fmaxf(run3, m3);
            if (((it + 1) & (per - 1)) == 0) {
                int sb = t0 >> (2 + band);
                float rv = quad == 0 ? run0 : quad == 1 ? run1
                         : quad == 2 ? run2 : run3;
                segO[(tl + 16 * quad) * 128 + sb] = rv;
                run0 = NEG; run1 = NEG; run2 = NEG; run3 = NEG;
            }
        }
    }
    if (band == 6) {
        float rv = quad == 0 ? run0 : quad == 1 ? run1
                 : quad == 2 ? run2 : run3;
        segP[(tl + 16 * quad) * 4 + wave] = rv;
        __syncthreads();
        if (tid < 128) {
            int f = tid & 63, sg = tid >> 6;
            segO[f * 128 + sg] =
                fmaxf(segP[f * 4 + 2 * sg], segP[f * 4 + 2 * sg + 1]);
        }
    }
}

// ---------------------------------------------------------------------------
// K4 (r17): pool + top-128 via radix select + bitonic sort, 512 threads,
// with LOSS fused via 56-counter election (proven at 112-block scale).
__global__ __launch_bounds__(512) void k_topk(
    const float* __restrict__ segG,
    float* __restrict__ topv, int* __restrict__ topi,
    const __hip_bfloat16* __restrict__ PT, const __hip_bfloat16* __restrict__ PF,
    int* __restrict__ lossCnt, float* __restrict__ accum,
    int* __restrict__ counter, unsigned* __restrict__ out)
{
    const int tid = threadIdx.x;
    const int band = blockIdx.x, sig = blockIdx.y;
    const float* segB = segG + (size_t)(sig * NBANDS + band) * 64 * 128;

    __shared__ unsigned hist[256];
    __shared__ unsigned scan[256];
    __shared__ unsigned long long list[512];
    __shared__ int sh_B, sh_nA, sh_cnt, sh_num, sh_w2;
    __shared__ float vT[128], vR[128];
    __shared__ int   iT[128], iR[128];
    __shared__ float red[256];
    __shared__ int amLast;

    unsigned long long kk[8];
    #pragma unroll
    for (int q = 0; q < 8; ++q) {
        int i = q * 512 + tid;
        int f = i >> 6, t = i & 63;
        const float* sg = segB + f * 128;
        float m = fmaxf(sg[2 * t], sg[2 * t + 1]);
        if (t > 0)  m = fmaxf(m, sg[2 * t - 1]);
        if (t < 63) m = fmaxf(m, sg[2 * t + 2]);
        kk[q] = ((unsigned long long)encf(m) << 32) | (unsigned)(4095 - i);
    }

    int shift = 56;
    unsigned long long prefix = 0;
    int nA = 0;
    for (int lev = 0; lev < 8; ++lev) {
        if (tid < 256) hist[tid] = 0;
        __syncthreads();
        #pragma unroll
        for (int q = 0; q < 8; ++q) {
            bool inpre = (lev == 0) || ((kk[q] >> (shift + 8)) == prefix);
            if (inpre) atomicAdd(&hist[(unsigned)((kk[q] >> shift) & 255u)], 1u);
        }
        __syncthreads();
        if (tid < 256) scan[tid] = hist[tid];
        __syncthreads();
        for (int off = 1; off < 256; off <<= 1) {
            unsigned v = 0;
            if (tid < 256) v = scan[tid] + ((tid + off < 256) ? scan[tid + off] : 0u);
            __syncthreads();
            if (tid < 256) scan[tid] = v;
            __syncthreads();
        }
        if (tid < 256) {
            unsigned ge = (unsigned)nA + scan[tid];
            unsigned gt = (unsigned)nA + ((tid < 255) ? scan[tid + 1] : 0u);
            if (ge >= 128u && gt < 128u) {
                sh_B = tid; sh_nA = (int)gt; sh_cnt = (int)hist[tid];
            }
        }
        __syncthreads();
        prefix = (prefix << 8) | (unsigned)sh_B;
        nA = sh_nA;
        if (nA + sh_cnt <= 511 || shift == 0) break;
        shift -= 8;
        __syncthreads();
    }

    if (tid < 256) { list[tid] = 0ull; list[tid + 256] = 0ull; }
    if (tid == 0) sh_num = 0;
    __syncthreads();
    #pragma unroll
    for (int q = 0; q < 8; ++q) {
        if ((kk[q] >> shift) >= prefix) {
            int p = atomicAdd(&sh_num, 1);
            if (p < 512) list[p] = kk[q];
        }
    }
    __syncthreads();

    for (int k = 2; k <= 512; k <<= 1) {
        for (int j = k >> 1; j > 0; j >>= 1) {
            const int w = tid;
            const int l = w ^ j;
            if (l > w) {
                unsigned long long av = list[w], bv = list[l];
                bool up = ((w & k) == 0);
                if ((av > bv) == up) { list[w] = bv; list[l] = av; }
            }
            __syncthreads();
        }
    }
    if (tid < K_TOP) {
        unsigned long long key = list[511 - tid];
        const size_t ob = ((size_t)sig * NBANDS + band) * K_TOP + tid;
        topv[ob] = decf((unsigned)(key >> 32));
        topi[ob] = 4095 - (int)(key & 0xFFFFFFFFu);
    }

    // ---- election: second finisher of this (band, sig&7) pair runs loss ----
    __syncthreads();
    if (tid == 0) {
        __threadfence();
        sh_w2 = (atomicAdd(&lossCnt[(sig & 7) * NBANDS + band], 1) == 1);
    }
    __syncthreads();
    if (!sh_w2) return;
    __threadfence();   // acquire: see partner block's topv/topi

    // ---- loss (proven k_loss body; tid < 256 active) ----
    const int b = sig & 7;
    const size_t bt = ((size_t)b * NBANDS + band) * K_TOP;
    const size_t br = ((size_t)(8 + b) * NBANDS + band) * K_TOP;
    if (tid < 128) { vT[tid] = topv[bt + tid]; iT[tid] = topi[bt + tid]; }
    else if (tid < 256) {
        int j = tid - 128; vR[j] = topv[br + j]; iR[j] = topi[br + j];
    }
    __syncthreads();
    float sum = 0.f;
    if (tid < 128) {
        #pragma unroll 4
        for (int k = 0; k < K_TOP; ++k) {
            float a = vT[k] * bf2f(PT[(iT[k] & 63) * 128 + tid]);
            float cc = vR[k] * bf2f(PT[(iR[k] & 63) * 128 + tid]);
            sum += fabsf(a - cc);
        }
    } else if (tid < 256) {
        const int j = tid - 128;
        #pragma unroll 4
        for (int k = 0; k < K_TOP; ++k) {
            float a = bf2f(PF[(iT[k] >> 6) * 128 + j]);
            float cc = bf2f(PF[(iR[k] >> 6) * 128 + j]);
            sum += fabsf(a - cc);
        }
    }
    if (tid < 256) red[tid] = sum;
    __syncthreads();
    for (int ofs = 128; ofs > 0; ofs >>= 1) {
        if (tid < ofs) red[tid] += red[tid + ofs];
        __syncthreads();
    }
    if (tid == 0) {
        atomicAdd(accum, red[0]);
        __threadfence();
        amLast = (atomicAdd(counter, 1) == NBANDS * 8 - 1);
    }
    __syncthreads();
    if (!amLast) return;
    if (tid == 0) {
        __threadfence();
        float L = atomicAdd(accum, 0.f) * (1.0f / 1835008.0f);
        unsigned lu = __float_as_uint(L);
        bool isnanL = ((lu & 0x7F800000u) == 0x7F800000u) && (lu & 0x007FFFFFu);
        float code;
        if      (isnanL)           code = 500.f;
        else if (L == 0.f)         code = 400.f;
        else if (fabsf(L) < 1e-6f) code = 600.f;
        else                       code = L;
        unsigned fb = __float_as_uint(code);
        unsigned hb = (fb + 0x7FFFu + ((fb >> 16) & 1u)) >> 16;
        out[0] = (hb << 16) | hb;    // dual-format store (proven r4)
    }
}

// ---------------------------------------------------------------------------
extern "C" void kernel_launch(void* const* d_in, const int* in_sizes, int n_in,
                              void* d_out, int out_size, void* d_ws, size_t ws_size,
                              hipStream_t stream)
{
    float* C      = (float*)d_ws;                          // 524288 f
    float* bands  = C + (size_t)NSIG * NBINS * 2;          // 1047552 f
    float* segG   = bands + (size_t)NSIG * BAND_STRIDE;    // 917504 f
    float* topv   = segG + (size_t)NSIG * NBANDS * 64 * 128; // 14336 f
    int*   topi   = (int*)(topv + (size_t)NSIG * NBANDS * K_TOP);
    float* accum  = (float*)(topi + (size_t)NSIG * NBANDS * K_TOP);
    int*   counter= (int*)(accum + 1);
    int*   lossCnt= (int*)(accum + 4);                     // 56 ints
    __hip_bfloat16* staged = (__hip_bfloat16*)(accum + 64); // 16B-aligned
    float* TG = (float*)(staged + SST_TOT);   // T and G alias (T dead before G)
    float* T  = TG;
    float* G  = TG;

    const __hip_bfloat16* fst = staged + SST_F;
    const __hip_bfloat16* pts = staged + SST_PT;
    const __hip_bfloat16* pfs = staged + SST_PF;

    k_fwd1   <<<dim3(17, NSIG),      256, 0, stream>>>(d_in[0], d_in[1],
                 d_in[2], d_in[3], d_in[4], staged, bands, accum, counter,
                 lossCnt, T);
    k_fwd2   <<<dim3(128, NSIG),     128, 0, stream>>>(T, C);
    k_synthA <<<dim3(64, NSIG),      256, 0, stream>>>(C, G);
    k_synthB <<<dim3(64, NSIG),      256, 0, stream>>>(C, G, bands);
    k_conv   <<<dim3(127, NSIG),     256, 0, stream>>>(bands, fst, segG);
    k_topk   <<<dim3(NBANDS, NSIG),  512, 0, stream>>>(segG, topv, topi,
                 pts, pfs, lossCnt, accum, counter, (unsigned*)d_out);
}

// Round 7
// 183.018 us; speedup vs baseline: 1.8541x; 1.0166x over previous
//
#include <hip/hip_runtime.h>
#include <hip/hip_bf16.h>

#define N_SAMP    32768
#define NBINS     16384
#define NSIG      16
#define NBANDS    7
#define K_TOP     128
// padded per-signal band buffer: 64 zero-floats of guard before each band
#define BAND_STRIDE 65472   // 448 pad + 65024 payload

// staged bf16 layout (small): [filters 4096 | PT 8192 | PF 8192]
#define SST_F   0
#define SST_PT  4096
#define SST_PF  12288
#define SST_TOT 20480

#define TWO_PI 6.283185307179586f

typedef __attribute__((ext_vector_type(8))) short bf16x8;
typedef __attribute__((ext_vector_type(4))) float f32x4;

__device__ __forceinline__ float bf2f(__hip_bfloat16 v) { return __bfloat162float(v); }

__device__ __forceinline__ unsigned encf(float f) {
    unsigned u = __float_as_uint(f);
    return (u & 0x80000000u) ? ~u : (u | 0x80000000u);
}
__device__ __forceinline__ float decf(unsigned u) {
    return __uint_as_float((u & 0x80000000u) ? (u ^ 0x80000000u) : ~u);
}

__device__ __forceinline__ int band_M1sh(int b) { return b < 3 ? 4 : (b < 4 ? 5 : 6); }
__device__ __forceinline__ int band_Lsh(int b) {
    return b == 0 ? 5 : (b == 1 ? 6 : (b < 5 ? 7 : (b == 5 ? 8 : 9)));
}
__device__ __forceinline__ int band_M2sh(int b) {
    return b < 2 ? 4 : (b < 5 ? 5 : (b == 5 ? 6 : 7));
}

// ---------------------------------------------------------------------------
// K_fwd1 — MFMA step 1 (128x256 decomposition), staging folded in (r15),
// ni-quarter split (r18). r19: ct/st tables dropped — t256[2*tt] equals
// (ct[tt], -st[tt]) BIT-EXACTLY (power-of-2 argument scaling commutes with
// fp rounding), so the A-build reads t256 directly. -128 sincosf/block.
__global__ __launch_bounds__(256) void k_fwd1(
    const void* __restrict__ tgt, const void* __restrict__ rec,
    const void* __restrict__ f, const void* __restrict__ pt,
    const void* __restrict__ pf,
    __hip_bfloat16* __restrict__ staged,
    float* __restrict__ bands, float* __restrict__ accum,
    int* __restrict__ counter, int* __restrict__ lossCnt,
    float* __restrict__ T)
{
    const int tid   = threadIdx.x;
    const int sig   = blockIdx.y;

    if (blockIdx.x == 16) {                    // staging slice for this sig
        float pv0 = bf2f(((const __hip_bfloat16*)tgt)[tid & 63]);
        int bad0 = (fabsf(pv0) > 1e8f) || (pv0 != pv0);
        const int isf = (__ballot(bad0) != 0ull);
        #pragma unroll
        for (int k = 0; k < 5; ++k) {          // 1280 elements per sig
            int id = sig * 1280 + k * 256 + tid;
            const void* src; int idx;
            if (id < SST_PT)      { src = f;  idx = id; }
            else if (id < SST_PF) { src = pt; idx = id - SST_PT; }
            else                  { src = pf; idx = id - SST_PF; }
            float v = isf ? ((const float*)src)[idx]
                          : bf2f(((const __hip_bfloat16*)src)[idx]);
            staged[id] = __float2bfloat16(v);
        }
        for (int i = tid; i < 448; i += 256) { // band guards for this sig
            int g = i >> 6, j = i & 63;
            int off = 64 * g + 512 * ((1 << g) - 1);
            bands[(size_t)sig * BAND_STRIDE + off + j] = 0.f;
        }
        if (sig == 0) {
            if (tid == 0) { accum[0] = 0.f; counter[0] = 0; }
            if (tid < 8 * NBANDS) lossCnt[tid] = 0;   // 56
        }
        return;
    }

    const int nbase = (blockIdx.x & 1) * 128;        // n2 half
    const int kgrp  = ((blockIdx.x >> 1) & 1) * 64;  // k1 group base
    const int nqq   = (blockIdx.x >> 2) & 3;         // ni quarter
    __shared__ __align__(16) __hip_bfloat16 xT[32][136];  // [n2-local][n1]
    __shared__ float2 t256[256];               // W_32768^(128a) = W_256^a, e^{-i}
    __shared__ float2 tF[128];                 // W_32768^a, a<128, e^{-i}

    {
        float sv, cv;
        sincosf(TWO_PI * (float)tid * (1.f / 256.f), &sv, &cv);
        t256[tid] = make_float2(cv, -sv);
        if (tid < 128) {
            sincosf(TWO_PI * (float)tid * (1.f / 32768.f), &sv, &cv);
            tF[tid] = make_float2(cv, -sv);
        }
    }

    float pv = bf2f(((const __hip_bfloat16*)tgt)[tid & 63]);
    int bad = (fabsf(pv) > 1e8f) || (pv != pv);
    const int isf32 = (__ballot(bad) != 0ull);
    const void* xsrc = (sig < 8) ? tgt : rec;
    const int soff = (sig & 7) * N_SAMP;

    // stage transpose: 32 rows (this block's ni quarter), thread covers a
    // 16-wide n1 slice of one row
    const int rloc = tid & 31;
    const int chb  = (tid >> 5) * 16;
    for (int c8 = 0; c8 < 16; c8 += 8) {
        union { bf16x8 v; __hip_bfloat16 h[8]; } u;
        #pragma unroll
        for (int uu = 0; uu < 8; ++uu) {
            int n1 = chb + c8 + uu;
            int gi = soff + n1 * 256 + nbase + nqq * 32 + rloc;
            float xv = isf32 ? ((const float*)xsrc)[gi]
                             : bf2f(((const __hip_bfloat16*)xsrc)[gi]);
            u.h[uu] = __float2bfloat16(xv);
        }
        *(bf16x8*)(&xT[rloc][chb + c8]) = u.v;
    }
    __syncthreads();

    const int tl = tid & 15, quad = (tid >> 4) & 3, w = tid >> 6;
    const int k1 = kgrp + w * 16 + tl;         // A row m = lane&15
    bf16x8 Arh[4], Arl[4], Aih[4], Ail[4];
    #pragma unroll
    for (int ki = 0; ki < 4; ++ki) {
        union { bf16x8 v; __hip_bfloat16 h[8]; } rh, rl, ih, il;
        #pragma unroll
        for (int j = 0; j < 8; ++j) {
            int n1 = ki * 32 + quad * 8 + j;
            int tt = (k1 * n1) & 127;
            float2 e = t256[2 * tt];           // == (cos, -sin) of 2pi*tt/128
            float wre = e.x, wim = e.y;        // e^{-ia}
            __hip_bfloat16 h1 = __float2bfloat16(wre);
            rh.h[j] = h1;
            rl.h[j] = __float2bfloat16(wre - bf2f(h1));
            __hip_bfloat16 h2 = __float2bfloat16(wim);
            ih.h[j] = h2;
            il.h[j] = __float2bfloat16(wim - bf2f(h2));
        }
        Arh[ki] = rh.v; Arl[ki] = rl.v; Aih[ki] = ih.v; Ail[ki] = il.v;
    }

    float2* To = (float2*)T + (size_t)sig * 128 * 256;
    const int mk = kgrp + w * 16 + quad * 4;   // D row = quad*4+reg
    for (int ni = 0; ni < 2; ++ni) {
        bf16x8 B[4];
        #pragma unroll
        for (int ki = 0; ki < 4; ++ki)         // B[k=n1][n=n2]: b128, aligned
            B[ki] = *(const bf16x8*)(&xT[ni * 16 + tl][ki * 32 + quad * 8]);
        f32x4 aR = {0.f,0.f,0.f,0.f}, aI = {0.f,0.f,0.f,0.f};
        #pragma unroll
        for (int ki = 0; ki < 4; ++ki) {
            aR = __builtin_amdgcn_mfma_f32_16x16x32_bf16(Arh[ki], B[ki], aR, 0, 0, 0);
            aR = __builtin_amdgcn_mfma_f32_16x16x32_bf16(Arl[ki], B[ki], aR, 0, 0, 0);
            aI = __builtin_amdgcn_mfma_f32_16x16x32_bf16(Aih[ki], B[ki], aI, 0, 0, 0);
            aI = __builtin_amdgcn_mfma_f32_16x16x32_bf16(Ail[ki], B[ki], aI, 0, 0, 0);
        }
        const int n2 = nbase + nqq * 32 + ni * 16 + tl;
        #pragma unroll
        for (int rg = 0; rg < 4; ++rg) {
            int k1e = mk + rg;
            int m = k1e * n2;                  // < 32768, no mod needed
            float2 e1 = t256[m >> 7];
            float2 e2 = tF[m & 127];
            float er = e1.x * e2.x - e1.y * e2.y;   // e^{-i 2pi m/32768}
            float ei = e1.x * e2.y + e1.y * e2.x;
            float Tr = aR[rg] * er - aI[rg] * ei;
            float Ti = aI[rg] * er + aR[rg] * ei;
            To[(size_t)k1e * 256 + n2] = make_float2(Tr, Ti);
        }
    }
}

// Step2 with 4 independent rotation chains (proven r10) + W_256 LDS table (r13)
__global__ __launch_bounds__(128) void k_fwd2(
    const float* __restrict__ T, float* __restrict__ C)
{
    const int k2  = threadIdx.x;              // < 128
    const int k1  = blockIdx.x;
    const int sig = blockIdx.y;
    __shared__ float2 Ts[256];
    __shared__ float2 tw[256];                // e^{-i 2pi a/256}
    const float2* Tin = (const float2*)T + ((size_t)sig * 128 + k1) * 256;
    for (int i = k2; i < 256; i += 128) Ts[i] = Tin[i];
    {
        float sv, cv;
        sincosf(TWO_PI * (float)k2 * (1.f / 256.f), &sv, &cv);
        tw[k2]       = make_float2(cv, -sv);
        tw[k2 + 128] = make_float2(-cv, sv);   // angle + pi
    }
    __syncthreads();
    float er[4], ei[4];
    #pragma unroll
    for (int c = 0; c < 4; ++c) {
        float2 e = tw[(c * k2) & 255];
        er[c] = e.x; ei[c] = e.y;
    }
    float2 e4 = tw[(4 * k2) & 255];
    const float c4 = e4.x, s4 = e4.y;
    float Xr[4] = {0.f,0.f,0.f,0.f}, Xi[4] = {0.f,0.f,0.f,0.f};
    for (int n2 = 0; n2 < 256; n2 += 4) {
        #pragma unroll
        for (int c = 0; c < 4; ++c) {
            float2 t = Ts[n2 + c];
            Xr[c] += t.x * er[c] - t.y * ei[c];
            Xi[c] += t.x * ei[c] + t.y * er[c];
            float nr = er[c] * c4 - ei[c] * s4;
            ei[c]    = er[c] * s4 + ei[c] * c4;
            er[c] = nr;
        }
    }
    const float inv = 5.5242717280199030e-3f;   // 1/sqrt(32768)
    float xr = (Xr[0] + Xr[1]) + (Xr[2] + Xr[3]);
    float xi = (Xi[0] + Xi[1]) + (Xi[2] + Xi[3]);
    float2* Co = (float2*)C + (size_t)sig * NBINS;
    Co[k1 + 128 * k2] = make_float2(xr * inv, xi * inv);
}

// ---------------------------------------------------------------------------
// Band synthesis — quarter-band decimation (proven r11, r18 e^2 setup)
__global__ __launch_bounds__(256) void k_synthA(
    const float* __restrict__ C, float* __restrict__ G)
{
    const int tid = threadIdx.x;
    const int sig = blockIdx.y;
    const int bix = 63 - blockIdx.x;
    const int band = (bix == 0) ? 0 : (32 - __clz(bix));
    const int lbx  = (band == 0) ? 0 : (bix - (1 << (band - 1)));
    const int s    = 512 << band;
    const int m1sh = band_M1sh(band);
    const int lsh  = band_Lsh(band);
    const int m2sh = band_M2sh(band);
    const int M2   = 1 << m2sh;
    const int L    = 1 << lsh;
    const int L4   = L >> 2;
    const int a    = (band == 0) ? 0 : (128 << band);
    const int tix  = lbx * 256 + tid;
    const int j1lo = (lbx * 256) >> (lsh - 2);
    int j1cnt = 256 >> (lsh - 2);
    if (j1cnt > (1 << m1sh)) j1cnt = 1 << m1sh;
    __shared__ float2 Ds[256];
    const float2* D = (const float2*)C + (size_t)sig * NBINS + a;
    for (int i = tid; i < (j1cnt << m2sh); i += 256) {
        int j1o = i >> m2sh, j2 = i & (M2 - 1);
        Ds[i] = D[(j1lo + j1o) + (j2 << m1sh)];
    }
    __syncthreads();
    if (tix >= (128 << band)) return;
    const int j1o = (tix >> (lsh - 2)) - j1lo;
    const int m   = tix & (L4 - 1);
    const float2* Dj = Ds + (j1o << m2sh);
    float e0r = 1.f, e0i = 0.f, e1r, e1i, sr, si;
    sincosf(TWO_PI * (float)m / (float)L, &e1i, &e1r);
    sr = e1r * e1r - e1i * e1i;               // e^{i 2a} = (e^{ia})^2
    si = 2.f * e1r * e1i;
    float ar[4] = {0.f,0.f,0.f,0.f}, ai[4] = {0.f,0.f,0.f,0.f};
    for (int j2 = 0; j2 < M2; j2 += 4) {
        {   float2 d = Dj[j2];
            float tr = d.x * e0r - d.y * e0i, ti = d.x * e0i + d.y * e0r;
            ar[0] += tr; ai[0] += ti; ar[1] += tr; ai[1] += ti;
            ar[2] += tr; ai[2] += ti; ar[3] += tr; ai[3] += ti;
            float nr = e0r * sr - e0i * si; e0i = e0r * si + e0i * sr; e0r = nr;
        }
        {   float2 d = Dj[j2 + 1];
            float tr = d.x * e1r - d.y * e1i, ti = d.x * e1i + d.y * e1r;
            ar[0] += tr; ai[0] += ti;
            ar[1] -= ti; ai[1] += tr;
            ar[2] -= tr; ai[2] -= ti;
            ar[3] += ti; ai[3] -= tr;
            float nr = e1r * sr - e1i * si; e1i = e1r * si + e1i * sr; e1r = nr;
        }
        {   float2 d = Dj[j2 + 2];
            float tr = d.x * e0r - d.y * e0i, ti = d.x * e0i + d.y * e0r;
            ar[0] += tr; ai[0] += ti;
            ar[1] -= tr; ai[1] -= ti;
            ar[2] += tr; ai[2] += ti;
            ar[3] -= tr; ai[3] -= ti;
            float nr = e0r * sr - e0i * si; e0i = e0r * si + e0i * sr; e0r = nr;
        }
        {   float2 d = Dj[j2 + 3];
            float tr = d.x * e1r - d.y * e1i, ti = d.x * e1i + d.y * e1r;
            ar[0] += tr; ai[0] += ti;
            ar[1] += ti; ai[1] -= tr;
            ar[2] -= tr; ai[2] -= ti;
            ar[3] -= ti; ai[3] += tr;
            float nr = e1r * sr - e1i * si; e1i = e1r * si + e1i * sr; e1r = nr;
        }
    }
    const float sc = 2.f * rsqrtf((float)s);
    float2* Go = (float2*)G + (size_t)sig * 65024 + 512 * ((1 << band) - 1);
    const int base = ((tix >> (lsh - 2)) << lsh) + m;
    #pragma unroll
    for (int q = 0; q < 4; ++q)
        Go[base + q * L4] = make_float2(ar[q] * sc, ai[q] * sc);
}

__global__ __launch_bounds__(256) void k_synthB(
    const float* __restrict__ C, const float* __restrict__ G,
    float* __restrict__ bands)
{
    const int tid = threadIdx.x;
    const int sig = blockIdx.y;
    const int bix = 63 - blockIdx.x;
    const int band = (bix == 0) ? 0 : (32 - __clz(bix));
    const int lbx  = (band == 0) ? 0 : (bix - (1 << (band - 1)));
    const int s    = 512 << band;
    const int M1   = 1 << band_M1sh(band);
    const int lsh  = band_Lsh(band);
    const int n    = lbx * 256 + tid;
    const int s4   = s >> 2;
    if (n >= s4) return;
    const int m    = n & ((1 << lsh) - 1);
    const float2* Gi = (const float2*)G + (size_t)sig * 65024 + 512 * ((1 << band) - 1);
    float e0r = 1.f, e0i = 0.f, e1r, e1i, sr, si;
    sincosf(TWO_PI * (float)n / (float)s, &e1i, &e1r);
    sr = e1r * e1r - e1i * e1i;               // e^{i 2a} = (e^{ia})^2
    si = 2.f * e1r * e1i;
    float zr[4] = {0.f,0.f,0.f,0.f}, zi[4] = {0.f,0.f,0.f,0.f};
    for (int j1 = 0; j1 < M1; j1 += 4) {
        {   float2 g = Gi[((j1 + 0) << lsh) + m];
            float tr = g.x * e0r - g.y * e0i, ti = g.x * e0i + g.y * e0r;
            zr[0] += tr; zi[0] += ti; zr[1] += tr; zi[1] += ti;
            zr[2] += tr; zi[2] += ti; zr[3] += tr; zi[3] += ti;
            float nr = e0r * sr - e0i * si; e0i = e0r * si + e0i * sr; e0r = nr;
        }
        {   float2 g = Gi[((j1 + 1) << lsh) + m];
            float tr = g.x * e1r - g.y * e1i, ti = g.x * e1i + g.y * e1r;
            zr[0] += tr; zi[0] += ti;
            zr[1] -= ti; zi[1] += tr;
            zr[2] -= tr; zi[2] -= ti;
            zr[3] += ti; zi[3] -= tr;
            float nr = e1r * sr - e1i * si; e1i = e1r * si + e1i * sr; e1r = nr;
        }
        {   float2 g = Gi[((j1 + 2) << lsh) + m];
            float tr = g.x * e0r - g.y * e0i, ti = g.x * e0i + g.y * e0r;
            zr[0] += tr; zi[0] += ti;
            zr[1] -= tr; zi[1] -= ti;
            zr[2] += tr; zi[2] += ti;
            zr[3] -= tr; zi[3] -= ti;
            float nr = e0r * sr - e0i * si; e0i = e0r * si + e0i * sr; e0r = nr;
        }
        {   float2 g = Gi[((j1 + 3) << lsh) + m];
            float tr = g.x * e1r - g.y * e1i, ti = g.x * e1i + g.y * e1r;
            zr[0] += tr; zi[0] += ti;
            zr[1] += ti; zi[1] -= tr;
            zr[2] -= tr; zi[2] -= ti;
            zr[3] -= ti; zi[3] += tr;
            float nr = e1r * sr - e1i * si; e1i = e1r * si + e1i * sr; e1r = nr;
        }
    }
    const int poff = 64 * (band + 1) + 512 * ((1 << band) - 1);
    float* bo = bands + (size_t)sig * BAND_STRIDE + poff;
    if (band == 0) {
        const float dc = C[(size_t)sig * NBINS * 2] * 0.04419417382415922f;
        #pragma unroll
        for (int q = 0; q < 4; ++q) bo[n + q * s4] = zr[q] - dc;
    } else {
        #pragma unroll
        for (int q = 0; q < 4; ++q) {
            float val;
            switch (n & 3) {
                case 0:  val =  zr[q]; break;
                case 1:  val = -zi[q]; break;
                case 2:  val = -zr[q]; break;
                default: val =  zi[q]; break;
            }
            bo[n + q * s4] = val;
        }
    }
}

// ---------------------------------------------------------------------------
// K3: MFMA conv + fused segment-max pooling (proven r8, r16 vector staging)
__global__ __launch_bounds__(256) void k_conv(
    const float* __restrict__ bands,
    const __hip_bfloat16* __restrict__ filters,
    float* __restrict__ segG)
{
    const int tid  = threadIdx.x;
    const int sig  = blockIdx.y;
    const int c    = blockIdx.x;               // 0..126
    const int band = 31 - __clz(c + 1);
    const int cidx = c + 1 - (1 << band);
    const int poff = 64 * (band + 1) + 512 * ((1 << band) - 1);
    const float* bp = bands + (size_t)sig * BAND_STRIDE + poff + cidx * 512;

    __shared__ __align__(16) __hip_bfloat16 xr[8][584];
    __shared__ float segP[64 * 4];

    if (tid < 72) {
        const int j = tid;
        const float* src = bp + 496 - 8 * j;
        float4 f0 = *(const float4*)(src + 12);
        float4 f1 = *(const float4*)(src + 8);
        float4 f2 = *(const float4*)(src + 4);
        float4 f3 = *(const float4*)(src + 0);
        __hip_bfloat16 w[16];
        w[0]  = __float2bfloat16(f0.w); w[1]  = __float2bfloat16(f0.z);
        w[2]  = __float2bfloat16(f0.y); w[3]  = __float2bfloat16(f0.x);
        w[4]  = __float2bfloat16(f1.w); w[5]  = __float2bfloat16(f1.z);
        w[6]  = __float2bfloat16(f1.y); w[7]  = __float2bfloat16(f1.x);
        w[8]  = __float2bfloat16(f2.w); w[9]  = __float2bfloat16(f2.z);
        w[10] = __float2bfloat16(f2.y); w[11] = __float2bfloat16(f2.x);
        w[12] = __float2bfloat16(f3.w); w[13] = __float2bfloat16(f3.z);
        w[14] = __float2bfloat16(f3.y); w[15] = __float2bfloat16(f3.x);
        #pragma unroll
        for (int p = 0; p < 8; ++p) {
            union { bf16x8 v; __hip_bfloat16 h[8]; } o;
            #pragma unroll
            for (int e = 0; e < 8; ++e) o.h[e] = w[p + e];
            *(bf16x8*)(&xr[p][8 * j]) = o.v;
        }
    }
    __syncthreads();

    const int tl   = tid & 15;
    const int quad = (tid >> 4) & 3;
    const int wave = tid >> 6;

    bf16x8 bf0[4], bf1[4];
    #pragma unroll
    for (int ft = 0; ft < 4; ++ft) {
        const __hip_bfloat16* fp = filters + ((ft * 16 + tl) * 64 + quad * 8);
        bf0[ft] = *(const bf16x8*)(fp);
        bf1[ft] = *(const bf16x8*)(fp + 32);
    }

    int s0 = 511 - wave * 128 - tl + 8 * quad;
    const __hip_bfloat16* xp = &xr[0][0] + (s0 & 7) * 584 + (s0 & ~7);

    const int spc = 512 >> (2 + band);
    float* segO = segG + (size_t)(sig * NBANDS + band) * 64 * 128 + cidx * spc;

    const float NEG = -3.4e38f;
    float run0 = NEG, run1 = NEG, run2 = NEG, run3 = NEG;
    const int per = (band >= 2) ? (1 << (band - 2)) : 1;

    for (int it = 0; it < 8; ++it) {
        const int t0 = wave * 128 + it * 16;
        bf16x8 a0 = *(const bf16x8*)(xp);
        bf16x8 a1 = *(const bf16x8*)(xp + 32);
        xp -= 16;
        f32x4 ac0 = {0.f,0.f,0.f,0.f}, ac1 = ac0, ac2 = ac0, ac3 = ac0;
        ac0 = __builtin_amdgcn_mfma_f32_16x16x32_bf16(a0, bf0[0], ac0, 0, 0, 0);
        ac0 = __builtin_amdgcn_mfma_f32_16x16x32_bf16(a1, bf1[0], ac0, 0, 0, 0);
        ac1 = __builtin_amdgcn_mfma_f32_16x16x32_bf16(a0, bf0[1], ac1, 0, 0, 0);
        ac1 = __builtin_amdgcn_mfma_f32_16x16x32_bf16(a1, bf1[1], ac1, 0, 0, 0);
        ac2 = __builtin_amdgcn_mfma_f32_16x16x32_bf16(a0, bf0[2], ac2, 0, 0, 0);
        ac2 = __builtin_amdgcn_mfma_f32_16x16x32_bf16(a1, bf1[2], ac2, 0, 0, 0);
        ac3 = __builtin_amdgcn_mfma_f32_16x16x32_bf16(a0, bf0[3], ac3, 0, 0, 0);
        ac3 = __builtin_amdgcn_mfma_f32_16x16x32_bf16(a1, bf1[3], ac3, 0, 0, 0);
        float m0 = fmaxf(fmaxf(ac0[0], ac0[1]), fmaxf(ac0[2], ac0[3]));
        float m1 = fmaxf(fmaxf(ac1[0], ac1[1]), fmaxf(ac1[2], ac1[3]));
        float m2 = fmaxf(fmaxf(ac2[0], ac2[1]), fmaxf(ac2[2], ac2[3]));
        float m3 = fmaxf(fmaxf(ac3[0], ac3[1]), fmaxf(ac3[2], ac3[3]));
        if (band == 0) {
            int sb = (t0 >> 2) + quad;
            segO[(tl     ) * 128 + sb] = m0;
            segO[(tl + 16) * 128 + sb] = m1;
            segO[(tl + 32) * 128 + sb] = m2;
            segO[(tl + 48) * 128 + sb] = m3;
        } else if (band == 1) {
            m0 = fmaxf(m0, __shfl_xor(m0, 16));
            m1 = fmaxf(m1, __shfl_xor(m1, 16));
            m2 = fmaxf(m2, __shfl_xor(m2, 16));
            m3 = fmaxf(m3, __shfl_xor(m3, 16));
            if ((quad & 1) == 0) {
                int sb = (t0 >> 3) + (quad >> 1);
                segO[(tl     ) * 128 + sb] = m0;
                segO[(tl + 16) * 128 + sb] = m1;
                segO[(tl + 32) * 128 + sb] = m2;
                segO[(tl + 48) * 128 + sb] = m3;
            }
        } else {
            m0 = fmaxf(m0, __shfl_xor(m0, 16)); m0 = fmaxf(m0, __shfl_xor(m0, 32));
            m1 = fmaxf(m1, __shfl_xor(m1, 16)); m1 = fmaxf(m1, __shfl_xor(m1, 32));
            m2 = fmaxf(m2, __shfl_xor(m2, 16)); m2 = fmaxf(m2, __shfl_xor(m2, 32));
            m3 = fmaxf(m3, __shfl_xor(m3, 16)); m3 = fmaxf(m3, __shfl_xor(m3, 32));
            run0 = fmaxf(run0, m0); run1 = fmaxf(run1, m1);
            run2 = fmaxf(run2, m2); run3 = fmaxf(run3, m3);
            if (((it + 1) & (per - 1)) == 0) {
                int sb = t0 >> (2 + band);
                float rv = quad == 0 ? run0 : quad == 1 ? run1
                         : quad == 2 ? run2 : run3;
                segO[(tl + 16 * quad) * 128 + sb] = rv;
                run0 = NEG; run1 = NEG; run2 = NEG; run3 = NEG;
            }
        }
    }
    if (band == 6) {
        float rv = quad == 0 ? run0 : quad == 1 ? run1
                 : quad == 2 ? run2 : run3;
        segP[(tl + 16 * quad) * 4 + wave] = rv;
        __syncthreads();
        if (tid < 128) {
            int f = tid & 63, sg = tid >> 6;
            segO[f * 128 + sg] =
                fmaxf(segP[f * 4 + 2 * sg], segP[f * 4 + 2 * sg + 1]);
        }
    }
}

// ---------------------------------------------------------------------------
// K4 (r19): pool + top-128 via radix select + bitonic sort, 512 threads,
// LOSS fused via 56-counter election (r17). Barrier-chain shrunk:
// - suffix scan: wave-level __shfl_down over 64 bins/wave + 4-entry combine
//   (36 syncthreads/level -> 5); arithmetic identical (gt = ge - hist[tid]).
// - bitonic: stages with j<64 exchange within a wave -> register __shfl_xor,
//   no barrier; only j in {256,128,64} stay in LDS (45 barriers -> ~10).
//   Compare-exchange semantics identical -> bit-identical sorted list.
__global__ __launch_bounds__(512) void k_topk(
    const float* __restrict__ segG,
    float* __restrict__ topv, int* __restrict__ topi,
    const __hip_bfloat16* __restrict__ PT, const __hip_bfloat16* __restrict__ PF,
    int* __restrict__ lossCnt, float* __restrict__ accum,
    int* __restrict__ counter, unsigned* __restrict__ out)
{
    const int tid  = threadIdx.x;
    const int lane = tid & 63;
    const int wv4  = tid >> 6;                 // wave id (0..7); scan uses 0..3
    const int band = blockIdx.x, sig = blockIdx.y;
    const float* segB = segG + (size_t)(sig * NBANDS + band) * 64 * 128;

    __shared__ unsigned hist[256];
    __shared__ unsigned wsum[4];
    __shared__ unsigned long long list[512];
    __shared__ int sh_B, sh_nA, sh_cnt, sh_num, sh_w2;
    __shared__ float vT[128], vR[128];
    __shared__ int   iT[128], iR[128];
    __shared__ float red[256];
    __shared__ int amLast;

    unsigned long long kk[8];
    #pragma unroll
    for (int q = 0; q < 8; ++q) {
        int i = q * 512 + tid;
        int f = i >> 6, t = i & 63;
        const float* sg = segB + f * 128;
        float m = fmaxf(sg[2 * t], sg[2 * t + 1]);
        if (t > 0)  m = fmaxf(m, sg[2 * t - 1]);
        if (t < 63) m = fmaxf(m, sg[2 * t + 2]);
        kk[q] = ((unsigned long long)encf(m) << 32) | (unsigned)(4095 - i);
    }

    int shift = 56;
    unsigned long long prefix = 0;
    int nA = 0;
    for (int lev = 0; lev < 8; ++lev) {
        if (tid < 256) hist[tid] = 0;
        __syncthreads();
        #pragma unroll
        for (int q = 0; q < 8; ++q) {
            bool inpre = (lev == 0) || ((kk[q] >> (shift + 8)) == prefix);
            if (inpre) atomicAdd(&hist[(unsigned)((kk[q] >> shift) & 255u)], 1u);
        }
        __syncthreads();
        unsigned hcnt = 0, sfx = 0;
        if (tid < 256) {                       // waves 0-3 only (wave-uniform)
            hcnt = hist[tid];
            sfx = hcnt;                        // inclusive suffix scan in-wave
            #pragma unroll
            for (int off = 1; off < 64; off <<= 1) {
                unsigned o = __shfl_down(sfx, off);
                if (lane + off < 64) sfx += o;
            }
            if (lane == 0) wsum[wv4] = sfx;
        }
        __syncthreads();
        if (tid < 256) {
            unsigned addhi = 0;
            #pragma unroll
            for (int w2 = 1; w2 < 4; ++w2) addhi += (w2 > wv4) ? wsum[w2] : 0u;
            unsigned ge = (unsigned)nA + sfx + addhi;   // count >= bucket tid
            unsigned gt = ge - hcnt;                    // count >  bucket tid
            if (ge >= 128u && gt < 128u) {
                sh_B = tid; sh_nA = (int)gt; sh_cnt = (int)hcnt;
            }
        }
        __syncthreads();
        prefix = (prefix << 8) | (unsigned)sh_B;
        nA = sh_nA;
        if (nA + sh_cnt <= 511 || shift == 0) break;
        shift -= 8;
        __syncthreads();
    }

    if (tid < 256) { list[tid] = 0ull; list[tid + 256] = 0ull; }
    if (tid == 0) sh_num = 0;
    __syncthreads();
    #pragma unroll
    for (int q = 0; q < 8; ++q) {
        if ((kk[q] >> shift) >= prefix) {
            int p = atomicAdd(&sh_num, 1);
            if (p < 512) list[p] = kk[q];
        }
    }
    __syncthreads();

    // ---- bitonic sort, hybrid register/LDS ----
    unsigned long long v = list[tid];
    #pragma unroll
    for (int k = 2; k <= 64; k <<= 1) {        // all j < 64: pure shfl
        for (int j = k >> 1; j > 0; j >>= 1) {
            unsigned long long pv = __shfl_xor(v, j);
            bool takeMin = (((tid & j) == 0) == ((tid & k) == 0));
            unsigned long long mn = v < pv ? v : pv;
            unsigned long long mx = v < pv ? pv : v;
            v = takeMin ? mn : mx;
        }
    }
    list[tid] = v;
    __syncthreads();
    for (int k = 128; k <= 512; k <<= 1) {
        for (int j = k >> 1; j >= 64; j >>= 1) {   // cross-wave: LDS
            const int w = tid, l = w ^ j;
            if (l > w) {
                unsigned long long av = list[w], bv = list[l];
                bool up = ((w & k) == 0);
                if ((av > bv) == up) { list[w] = bv; list[l] = av; }
            }
            __syncthreads();
        }
        v = list[tid];
        #pragma unroll
        for (int j = 32; j > 0; j >>= 1) {         // in-wave: shfl
            unsigned long long pv = __shfl_xor(v, j);
            bool takeMin = (((tid & j) == 0) == ((tid & k) == 0));
            unsigned long long mn = v < pv ? v : pv;
            unsigned long long mx = v < pv ? pv : v;
            v = takeMin ? mn : mx;
        }
        list[tid] = v;
        __syncthreads();
    }

    if (tid < K_TOP) {
        unsigned long long key = list[511 - tid];
        const size_t ob = ((size_t)sig * NBANDS + band) * K_TOP + tid;
        topv[ob] = decf((unsigned)(key >> 32));
        topi[ob] = 4095 - (int)(key & 0xFFFFFFFFu);
    }

    // ---- election: second finisher of this (band, sig&7) pair runs loss ----
    __syncthreads();
    if (tid == 0) {
        __threadfence();
        sh_w2 = (atomicAdd(&lossCnt[(sig & 7) * NBANDS + band], 1) == 1);
    }
    __syncthreads();
    if (!sh_w2) return;
    __threadfence();   // acquire: see partner block's topv/topi

    // ---- loss (proven k_loss body; tid < 256 active) ----
    const int b = sig & 7;
    const size_t bt = ((size_t)b * NBANDS + band) * K_TOP;
    const size_t br = ((size_t)(8 + b) * NBANDS + band) * K_TOP;
    if (tid < 128) { vT[tid] = topv[bt + tid]; iT[tid] = topi[bt + tid]; }
    else if (tid < 256) {
        int j = tid - 128; vR[j] = topv[br + j]; iR[j] = topi[br + j];
    }
    __syncthreads();
    float sum = 0.f;
    if (tid < 128) {
        #pragma unroll 4
        for (int k = 0; k < K_TOP; ++k) {
            float a = vT[k] * bf2f(PT[(iT[k] & 63) * 128 + tid]);
            float cc = vR[k] * bf2f(PT[(iR[k] & 63) * 128 + tid]);
            sum += fabsf(a - cc);
        }
    } else if (tid < 256) {
        const int j = tid - 128;
        #pragma unroll 4
        for (int k = 0; k < K_TOP; ++k) {
            float a = bf2f(PF[(iT[k] >> 6) * 128 + j]);
            float cc = bf2f(PF[(iR[k] >> 6) * 128 + j]);
            sum += fabsf(a - cc);
        }
    }
    if (tid < 256) red[tid] = sum;
    __syncthreads();
    for (int ofs = 128; ofs > 0; ofs >>= 1) {
        if (tid < ofs) red[tid] += red[tid + ofs];
        __syncthreads();
    }
    if (tid == 0) {
        atomicAdd(accum, red[0]);
        __threadfence();
        amLast = (atomicAdd(counter, 1) == NBANDS * 8 - 1);
    }
    __syncthreads();
    if (!amLast) return;
    if (tid == 0) {
        __threadfence();
        float L = atomicAdd(accum, 0.f) * (1.0f / 1835008.0f);
        unsigned lu = __float_as_uint(L);
        bool isnanL = ((lu & 0x7F800000u) == 0x7F800000u) && (lu & 0x007FFFFFu);
        float code;
        if      (isnanL)           code = 500.f;
        else if (L == 0.f)         code = 400.f;
        else if (fabsf(L) < 1e-6f) code = 600.f;
        else                       code = L;
        unsigned fb = __float_as_uint(code);
        unsigned hb = (fb + 0x7FFFu + ((fb >> 16) & 1u)) >> 16;
        out[0] = (hb << 16) | hb;    // dual-format store (proven r4)
    }
}

// ---------------------------------------------------------------------------
extern "C" void kernel_launch(void* const* d_in, const int* in_sizes, int n_in,
                              void* d_out, int out_size, void* d_ws, size_t ws_size,
                              hipStream_t stream)
{
    float* C      = (float*)d_ws;                          // 524288 f
    float* bands  = C + (size_t)NSIG * NBINS * 2;          // 1047552 f
    float* segG   = bands + (size_t)NSIG * BAND_STRIDE;    // 917504 f
    float* topv   = segG + (size_t)NSIG * NBANDS * 64 * 128; // 14336 f
    int*   topi   = (int*)(topv + (size_t)NSIG * NBANDS * K_TOP);
    float* accum  = (float*)(topi + (size_t)NSIG * NBANDS * K_TOP);
    int*   counter= (int*)(accum + 1);
    int*   lossCnt= (int*)(accum + 4);                     // 56 ints
    __hip_bfloat16* staged = (__hip_bfloat16*)(accum + 64); // 16B-aligned
    float* TG = (float*)(staged + SST_TOT);   // T and G alias (T dead before G)
    float* T  = TG;
    float* G  = TG;

    const __hip_bfloat16* fst = staged + SST_F;
    const __hip_bfloat16* pts = staged + SST_PT;
    const __hip_bfloat16* pfs = staged + SST_PF;

    k_fwd1   <<<dim3(17, NSIG),      256, 0, stream>>>(d_in[0], d_in[1],
                 d_in[2], d_in[3], d_in[4], staged, bands, accum, counter,
                 lossCnt, T);
    k_fwd2   <<<dim3(128, NSIG),     128, 0, stream>>>(T, C);
    k_synthA <<<dim3(64, NSIG),      256, 0, stream>>>(C, G);
    k_synthB <<<dim3(64, NSIG),      256, 0, stream>>>(C, G, bands);
    k_conv   <<<dim3(127, NSIG),     256, 0, stream>>>(bands, fst, segG);
    k_topk   <<<dim3(NBANDS, NSIG),  512, 0, stream>>>(segG, topv, topi,
                 pts, pfs, lossCnt, accum, counter, (unsigned*)d_out);
}

// Round 8
// 182.079 us; speedup vs baseline: 1.8637x; 1.0052x over previous
//
#include <hip/hip_runtime.h>
#include <hip/hip_bf16.h>

#define N_SAMP    32768
#define NBINS     16384
#define NSIG      16
#define NBANDS    7
#define K_TOP     128
// padded per-signal band buffer: 64 zero-floats of guard before each band
#define BAND_STRIDE 65472   // 448 pad + 65024 payload

// staged bf16 layout (small): [filters 4096 | PT 8192 | PF 8192]
#define SST_F   0
#define SST_PT  4096
#define SST_PF  12288
#define SST_TOT 20480

#define TWO_PI 6.283185307179586f

typedef __attribute__((ext_vector_type(8))) short bf16x8;
typedef __attribute__((ext_vector_type(4))) float f32x4;

__device__ __forceinline__ float bf2f(__hip_bfloat16 v) { return __bfloat162float(v); }

__device__ __forceinline__ unsigned encf(float f) {
    unsigned u = __float_as_uint(f);
    return (u & 0x80000000u) ? ~u : (u | 0x80000000u);
}
__device__ __forceinline__ float decf(unsigned u) {
    return __uint_as_float((u & 0x80000000u) ? (u ^ 0x80000000u) : ~u);
}

__device__ __forceinline__ int band_M1sh(int b) { return b < 3 ? 4 : (b < 4 ? 5 : 6); }
__device__ __forceinline__ int band_Lsh(int b) {
    return b == 0 ? 5 : (b == 1 ? 6 : (b < 5 ? 7 : (b == 5 ? 8 : 9)));
}
__device__ __forceinline__ int band_M2sh(int b) {
    return b < 2 ? 4 : (b < 5 ? 5 : (b == 5 ? 6 : 7));
}

// ---------------------------------------------------------------------------
// K_fwd1 — MFMA step 1, staging folded in (r15), ni-quarter split (r18),
// t256-only A-build (r19). r20: staging blocks also build the GLOBAL twiddle
// tables consumed by fwd2/synthA/synthB one kernel boundary later:
//   Wtab[a] = e^{-i 2pi a/32768}, a < 8192  (512 entries per sig-block)
//   W256    = verbatim replica of fwd2's old per-block tw[] table
// (power-of-2 argument scaling commutes with fp rounding -> bit-exact).
__global__ __launch_bounds__(256) void k_fwd1(
    const void* __restrict__ tgt, const void* __restrict__ rec,
    const void* __restrict__ f, const void* __restrict__ pt,
    const void* __restrict__ pf,
    __hip_bfloat16* __restrict__ staged,
    float* __restrict__ bands, float* __restrict__ accum,
    int* __restrict__ counter, int* __restrict__ lossCnt,
    float2* __restrict__ W256, float2* __restrict__ Wtab,
    float* __restrict__ T)
{
    const int tid   = threadIdx.x;
    const int sig   = blockIdx.y;

    if (blockIdx.x == 16) {                    // staging slice for this sig
        float pv0 = bf2f(((const __hip_bfloat16*)tgt)[tid & 63]);
        int bad0 = (fabsf(pv0) > 1e8f) || (pv0 != pv0);
        const int isf = (__ballot(bad0) != 0ull);
        #pragma unroll
        for (int k = 0; k < 5; ++k) {          // 1280 elements per sig
            int id = sig * 1280 + k * 256 + tid;
            const void* src; int idx;
            if (id < SST_PT)      { src = f;  idx = id; }
            else if (id < SST_PF) { src = pt; idx = id - SST_PT; }
            else                  { src = pf; idx = id - SST_PF; }
            float v = isf ? ((const float*)src)[idx]
                          : bf2f(((const __hip_bfloat16*)src)[idx]);
            staged[id] = __float2bfloat16(v);
        }
        for (int i = tid; i < 448; i += 256) { // band guards for this sig
            int g = i >> 6, j = i & 63;
            int off = 64 * g + 512 * ((1 << g) - 1);
            bands[(size_t)sig * BAND_STRIDE + off + j] = 0.f;
        }
        #pragma unroll
        for (int k = 0; k < 2; ++k) {          // global Wtab: 512 entries/sig
            int a = sig * 512 + k * 256 + tid;
            float sv, cv;
            sincosf(TWO_PI * (float)a * (1.f / 32768.f), &sv, &cv);
            Wtab[a] = make_float2(cv, -sv);
        }
        if (sig == 0) {
            if (tid < 128) {                   // W256 = old fwd2 tw, verbatim
                float sv, cv;
                sincosf(TWO_PI * (float)tid * (1.f / 256.f), &sv, &cv);
                W256[tid]       = make_float2(cv, -sv);
                W256[tid + 128] = make_float2(-cv, sv);
            }
            if (tid == 0) { accum[0] = 0.f; counter[0] = 0; }
            if (tid < 8 * NBANDS) lossCnt[tid] = 0;   // 56
        }
        return;
    }

    const int nbase = (blockIdx.x & 1) * 128;        // n2 half
    const int kgrp  = ((blockIdx.x >> 1) & 1) * 64;  // k1 group base
    const int nqq   = (blockIdx.x >> 2) & 3;         // ni quarter
    __shared__ __align__(16) __hip_bfloat16 xT[32][136];  // [n2-local][n1]
    __shared__ float2 t256[256];               // W_32768^(128a) = W_256^a, e^{-i}
    __shared__ float2 tF[128];                 // W_32768^a, a<128, e^{-i}

    {
        float sv, cv;
        sincosf(TWO_PI * (float)tid * (1.f / 256.f), &sv, &cv);
        t256[tid] = make_float2(cv, -sv);
        if (tid < 128) {
            sincosf(TWO_PI * (float)tid * (1.f / 32768.f), &sv, &cv);
            tF[tid] = make_float2(cv, -sv);
        }
    }

    float pv = bf2f(((const __hip_bfloat16*)tgt)[tid & 63]);
    int bad = (fabsf(pv) > 1e8f) || (pv != pv);
    const int isf32 = (__ballot(bad) != 0ull);
    const void* xsrc = (sig < 8) ? tgt : rec;
    const int soff = (sig & 7) * N_SAMP;

    // stage transpose: 32 rows (this block's ni quarter), thread covers a
    // 16-wide n1 slice of one row
    const int rloc = tid & 31;
    const int chb  = (tid >> 5) * 16;
    for (int c8 = 0; c8 < 16; c8 += 8) {
        union { bf16x8 v; __hip_bfloat16 h[8]; } u;
        #pragma unroll
        for (int uu = 0; uu < 8; ++uu) {
            int n1 = chb + c8 + uu;
            int gi = soff + n1 * 256 + nbase + nqq * 32 + rloc;
            float xv = isf32 ? ((const float*)xsrc)[gi]
                             : bf2f(((const __hip_bfloat16*)xsrc)[gi]);
            u.h[uu] = __float2bfloat16(xv);
        }
        *(bf16x8*)(&xT[rloc][chb + c8]) = u.v;
    }
    __syncthreads();

    const int tl = tid & 15, quad = (tid >> 4) & 3, w = tid >> 6;
    const int k1 = kgrp + w * 16 + tl;         // A row m = lane&15
    bf16x8 Arh[4], Arl[4], Aih[4], Ail[4];
    #pragma unroll
    for (int ki = 0; ki < 4; ++ki) {
        union { bf16x8 v; __hip_bfloat16 h[8]; } rh, rl, ih, il;
        #pragma unroll
        for (int j = 0; j < 8; ++j) {
            int n1 = ki * 32 + quad * 8 + j;
            int tt = (k1 * n1) & 127;
            float2 e = t256[2 * tt];           // == (cos, -sin) of 2pi*tt/128
            float wre = e.x, wim = e.y;        // e^{-ia}
            __hip_bfloat16 h1 = __float2bfloat16(wre);
            rh.h[j] = h1;
            rl.h[j] = __float2bfloat16(wre - bf2f(h1));
            __hip_bfloat16 h2 = __float2bfloat16(wim);
            ih.h[j] = h2;
            il.h[j] = __float2bfloat16(wim - bf2f(h2));
        }
        Arh[ki] = rh.v; Arl[ki] = rl.v; Aih[ki] = ih.v; Ail[ki] = il.v;
    }

    float2* To = (float2*)T + (size_t)sig * 128 * 256;
    const int mk = kgrp + w * 16 + quad * 4;   // D row = quad*4+reg
    for (int ni = 0; ni < 2; ++ni) {
        bf16x8 B[4];
        #pragma unroll
        for (int ki = 0; ki < 4; ++ki)         // B[k=n1][n=n2]: b128, aligned
            B[ki] = *(const bf16x8*)(&xT[ni * 16 + tl][ki * 32 + quad * 8]);
        f32x4 aR = {0.f,0.f,0.f,0.f}, aI = {0.f,0.f,0.f,0.f};
        #pragma unroll
        for (int ki = 0; ki < 4; ++ki) {
            aR = __builtin_amdgcn_mfma_f32_16x16x32_bf16(Arh[ki], B[ki], aR, 0, 0, 0);
            aR = __builtin_amdgcn_mfma_f32_16x16x32_bf16(Arl[ki], B[ki], aR, 0, 0, 0);
            aI = __builtin_amdgcn_mfma_f32_16x16x32_bf16(Aih[ki], B[ki], aI, 0, 0, 0);
            aI = __builtin_amdgcn_mfma_f32_16x16x32_bf16(Ail[ki], B[ki], aI, 0, 0, 0);
        }
        const int n2 = nbase + nqq * 32 + ni * 16 + tl;
        #pragma unroll
        for (int rg = 0; rg < 4; ++rg) {
            int k1e = mk + rg;
            int m = k1e * n2;                  // < 32768, no mod needed
            float2 e1 = t256[m >> 7];
            float2 e2 = tF[m & 127];
            float er = e1.x * e2.x - e1.y * e2.y;   // e^{-i 2pi m/32768}
            float ei = e1.x * e2.y + e1.y * e2.x;
            float Tr = aR[rg] * er - aI[rg] * ei;
            float Ti = aI[rg] * er + aR[rg] * ei;
            To[(size_t)k1e * 256 + n2] = make_float2(Tr, Ti);
        }
    }
}

// Step2 with 4 independent rotation chains (proven r10). r20: the per-block
// tw[] LDS table build is gone — reads the global W256 (bit-identical
// replica built in fwd1 staging) from L2 instead. Removes 1 sincosf +
// 2 LDS stores from every thread's setup chain.
__global__ __launch_bounds__(128) void k_fwd2(
    const float* __restrict__ T, float* __restrict__ C,
    const float2* __restrict__ W256)
{
    const int k2  = threadIdx.x;              // < 128
    const int k1  = blockIdx.x;
    const int sig = blockIdx.y;
    __shared__ float2 Ts[256];
    const float2* Tin = (const float2*)T + ((size_t)sig * 128 + k1) * 256;
    for (int i = k2; i < 256; i += 128) Ts[i] = Tin[i];
    float er[4], ei[4];
    #pragma unroll
    for (int c = 0; c < 4; ++c) {
        float2 e = W256[(c * k2) & 255];
        er[c] = e.x; ei[c] = e.y;
    }
    float2 e4 = W256[(4 * k2) & 255];
    const float c4 = e4.x, s4 = e4.y;
    __syncthreads();
    float Xr[4] = {0.f,0.f,0.f,0.f}, Xi[4] = {0.f,0.f,0.f,0.f};
    for (int n2 = 0; n2 < 256; n2 += 4) {
        #pragma unroll
        for (int c = 0; c < 4; ++c) {
            float2 t = Ts[n2 + c];
            Xr[c] += t.x * er[c] - t.y * ei[c];
            Xi[c] += t.x * ei[c] + t.y * er[c];
            float nr = er[c] * c4 - ei[c] * s4;
            ei[c]    = er[c] * s4 + ei[c] * c4;
            er[c] = nr;
        }
    }
    const float inv = 5.5242717280199030e-3f;   // 1/sqrt(32768)
    float xr = (Xr[0] + Xr[1]) + (Xr[2] + Xr[3]);
    float xi = (Xi[0] + Xi[1]) + (Xi[2] + Xi[3]);
    float2* Co = (float2*)C + (size_t)sig * NBINS;
    Co[k1 + 128 * k2] = make_float2(xr * inv, xi * inv);
}

// ---------------------------------------------------------------------------
// Band synthesis — quarter-band decimation (proven r11, r18 e^2 setup).
// r20: setup sincosf -> global Wtab lookup. angle 2pi*m/2^lsh == Wtab index
// m << (15-lsh); (cos,+sin) = (W.x, -W.y). Bit-exact (scaling commutes).
__global__ __launch_bounds__(256) void k_synthA(
    const float* __restrict__ C, float* __restrict__ G,
    const float2* __restrict__ Wtab)
{
    const int tid = threadIdx.x;
    const int sig = blockIdx.y;
    const int bix = 63 - blockIdx.x;
    const int band = (bix == 0) ? 0 : (32 - __clz(bix));
    const int lbx  = (band == 0) ? 0 : (bix - (1 << (band - 1)));
    const int s    = 512 << band;
    const int m1sh = band_M1sh(band);
    const int lsh  = band_Lsh(band);
    const int m2sh = band_M2sh(band);
    const int M2   = 1 << m2sh;
    const int L4   = 1 << (lsh - 2);
    const int a    = (band == 0) ? 0 : (128 << band);
    const int tix  = lbx * 256 + tid;
    const int j1lo = (lbx * 256) >> (lsh - 2);
    int j1cnt = 256 >> (lsh - 2);
    if (j1cnt > (1 << m1sh)) j1cnt = 1 << m1sh;
    __shared__ float2 Ds[256];
    const float2* D = (const float2*)C + (size_t)sig * NBINS + a;
    for (int i = tid; i < (j1cnt << m2sh); i += 256) {
        int j1o = i >> m2sh, j2 = i & (M2 - 1);
        Ds[i] = D[(j1lo + j1o) + (j2 << m1sh)];
    }
    __syncthreads();
    if (tix >= (128 << band)) return;
    const int j1o = (tix >> (lsh - 2)) - j1lo;
    const int m   = tix & (L4 - 1);
    const float2* Dj = Ds + (j1o << m2sh);
    float2 eW = Wtab[m << (15 - lsh)];
    float e0r = 1.f, e0i = 0.f;
    float e1r = eW.x, e1i = -eW.y;
    float sr = e1r * e1r - e1i * e1i;          // e^{i 2a} = (e^{ia})^2
    float si = 2.f * e1r * e1i;
    float ar[4] = {0.f,0.f,0.f,0.f}, ai[4] = {0.f,0.f,0.f,0.f};
    for (int j2 = 0; j2 < M2; j2 += 4) {
        {   float2 d = Dj[j2];
            float tr = d.x * e0r - d.y * e0i, ti = d.x * e0i + d.y * e0r;
            ar[0] += tr; ai[0] += ti; ar[1] += tr; ai[1] += ti;
            ar[2] += tr; ai[2] += ti; ar[3] += tr; ai[3] += ti;
            float nr = e0r * sr - e0i * si; e0i = e0r * si + e0i * sr; e0r = nr;
        }
        {   float2 d = Dj[j2 + 1];
            float tr = d.x * e1r - d.y * e1i, ti = d.x * e1i + d.y * e1r;
            ar[0] += tr; ai[0] += ti;
            ar[1] -= ti; ai[1] += tr;
            ar[2] -= tr; ai[2] -= ti;
            ar[3] += ti; ai[3] -= tr;
            float nr = e1r * sr - e1i * si; e1i = e1r * si + e1i * sr; e1r = nr;
        }
        {   float2 d = Dj[j2 + 2];
            float tr = d.x * e0r - d.y * e0i, ti = d.x * e0i + d.y * e0r;
            ar[0] += tr; ai[0] += ti;
            ar[1] -= tr; ai[1] -= ti;
            ar[2] += tr; ai[2] += ti;
            ar[3] -= tr; ai[3] -= ti;
            float nr = e0r * sr - e0i * si; e0i = e0r * si + e0i * sr; e0r = nr;
        }
        {   float2 d = Dj[j2 + 3];
            float tr = d.x * e1r - d.y * e1i, ti = d.x * e1i + d.y * e1r;
            ar[0] += tr; ai[0] += ti;
            ar[1] += ti; ai[1] -= tr;
            ar[2] -= tr; ai[2] -= ti;
            ar[3] -= ti; ai[3] += tr;
            float nr = e1r * sr - e1i * si; e1i = e1r * si + e1i * sr; e1r = nr;
        }
    }
    const float sc = 2.f * rsqrtf((float)s);
    float2* Go = (float2*)G + (size_t)sig * 65024 + 512 * ((1 << band) - 1);
    const int base = ((tix >> (lsh - 2)) << lsh) + m;
    #pragma unroll
    for (int q = 0; q < 4; ++q)
        Go[base + q * L4] = make_float2(ar[q] * sc, ai[q] * sc);
}

__global__ __launch_bounds__(256) void k_synthB(
    const float* __restrict__ C, const float* __restrict__ G,
    float* __restrict__ bands, const float2* __restrict__ Wtab)
{
    const int tid = threadIdx.x;
    const int sig = blockIdx.y;
    const int bix = 63 - blockIdx.x;
    const int band = (bix == 0) ? 0 : (32 - __clz(bix));
    const int lbx  = (band == 0) ? 0 : (bix - (1 << (band - 1)));
    const int s    = 512 << band;
    const int M1   = 1 << band_M1sh(band);
    const int lsh  = band_Lsh(band);
    const int n    = lbx * 256 + tid;
    const int s4   = s >> 2;
    if (n >= s4) return;
    const int m    = n & ((1 << lsh) - 1);
    const float2* Gi = (const float2*)G + (size_t)sig * 65024 + 512 * ((1 << band) - 1);
    float2 eW = Wtab[n << (6 - band)];         // angle 2pi*n/2^(9+band)
    float e0r = 1.f, e0i = 0.f;
    float e1r = eW.x, e1i = -eW.y;
    float sr = e1r * e1r - e1i * e1i;          // e^{i 2a} = (e^{ia})^2
    float si = 2.f * e1r * e1i;
    float zr[4] = {0.f,0.f,0.f,0.f}, zi[4] = {0.f,0.f,0.f,0.f};
    for (int j1 = 0; j1 < M1; j1 += 4) {
        {   float2 g = Gi[((j1 + 0) << lsh) + m];
            float tr = g.x * e0r - g.y * e0i, ti = g.x * e0i + g.y * e0r;
            zr[0] += tr; zi[0] += ti; zr[1] += tr; zi[1] += ti;
            zr[2] += tr; zi[2] += ti; zr[3] += tr; zi[3] += ti;
            float nr = e0r * sr - e0i * si; e0i = e0r * si + e0i * sr; e0r = nr;
        }
        {   float2 g = Gi[((j1 + 1) << lsh) + m];
            float tr = g.x * e1r - g.y * e1i, ti = g.x * e1i + g.y * e1r;
            zr[0] += tr; zi[0] += ti;
            zr[1] -= ti; zi[1] += tr;
            zr[2] -= tr; zi[2] -= ti;
            zr[3] += ti; zi[3] -= tr;
            float nr = e1r * sr - e1i * si; e1i = e1r * si + e1i * sr; e1r = nr;
        }
        {   float2 g = Gi[((j1 + 2) << lsh) + m];
            float tr = g.x * e0r - g.y * e0i, ti = g.x * e0i + g.y * e0r;
            zr[0] += tr; zi[0] += ti;
            zr[1] -= tr; zi[1] -= ti;
            zr[2] += tr; zi[2] += ti;
            zr[3] -= tr; zi[3] -= ti;
            float nr = e0r * sr - e0i * si; e0i = e0r * si + e0i * sr; e0r = nr;
        }
        {   float2 g = Gi[((j1 + 3) << lsh) + m];
            float tr = g.x * e1r - g.y * e1i, ti = g.x * e1i + g.y * e1r;
            zr[0] += tr; zi[0] += ti;
            zr[1] += ti; zi[1] -= tr;
            zr[2] -= tr; zi[2] -= ti;
            zr[3] -= ti; zi[3] += tr;
            float nr = e1r * sr - e1i * si; e1i = e1r * si + e1i * sr; e1r = nr;
        }
    }
    const int poff = 64 * (band + 1) + 512 * ((1 << band) - 1);
    float* bo = bands + (size_t)sig * BAND_STRIDE + poff;
    if (band == 0) {
        const float dc = C[(size_t)sig * NBINS * 2] * 0.04419417382415922f;
        #pragma unroll
        for (int q = 0; q < 4; ++q) bo[n + q * s4] = zr[q] - dc;
    } else {
        #pragma unroll
        for (int q = 0; q < 4; ++q) {
            float val;
            switch (n & 3) {
                case 0:  val =  zr[q]; break;
                case 1:  val = -zi[q]; break;
                case 2:  val = -zr[q]; break;
                default: val =  zi[q]; break;
            }
            bo[n + q * s4] = val;
        }
    }
}

// ---------------------------------------------------------------------------
// K3: MFMA conv + fused segment-max pooling (proven r8, r16 vector staging)
__global__ __launch_bounds__(256) void k_conv(
    const float* __restrict__ bands,
    const __hip_bfloat16* __restrict__ filters,
    float* __restrict__ segG)
{
    const int tid  = threadIdx.x;
    const int sig  = blockIdx.y;
    const int c    = blockIdx.x;               // 0..126
    const int band = 31 - __clz(c + 1);
    const int cidx = c + 1 - (1 << band);
    const int poff = 64 * (band + 1) + 512 * ((1 << band) - 1);
    const float* bp = bands + (size_t)sig * BAND_STRIDE + poff + cidx * 512;

    __shared__ __align__(16) __hip_bfloat16 xr[8][584];
    __shared__ float segP[64 * 4];

    if (tid < 72) {
        const int j = tid;
        const float* src = bp + 496 - 8 * j;
        float4 f0 = *(const float4*)(src + 12);
        float4 f1 = *(const float4*)(src + 8);
        float4 f2 = *(const float4*)(src + 4);
        float4 f3 = *(const float4*)(src + 0);
        __hip_bfloat16 w[16];
        w[0]  = __float2bfloat16(f0.w); w[1]  = __float2bfloat16(f0.z);
        w[2]  = __float2bfloat16(f0.y); w[3]  = __float2bfloat16(f0.x);
        w[4]  = __float2bfloat16(f1.w); w[5]  = __float2bfloat16(f1.z);
        w[6]  = __float2bfloat16(f1.y); w[7]  = __float2bfloat16(f1.x);
        w[8]  = __float2bfloat16(f2.w); w[9]  = __float2bfloat16(f2.z);
        w[10] = __float2bfloat16(f2.y); w[11] = __float2bfloat16(f2.x);
        w[12] = __float2bfloat16(f3.w); w[13] = __float2bfloat16(f3.z);
        w[14] = __float2bfloat16(f3.y); w[15] = __float2bfloat16(f3.x);
        #pragma unroll
        for (int p = 0; p < 8; ++p) {
            union { bf16x8 v; __hip_bfloat16 h[8]; } o;
            #pragma unroll
            for (int e = 0; e < 8; ++e) o.h[e] = w[p + e];
            *(bf16x8*)(&xr[p][8 * j]) = o.v;
        }
    }
    __syncthreads();

    const int tl   = tid & 15;
    const int quad = (tid >> 4) & 3;
    const int wave = tid >> 6;

    bf16x8 bf0[4], bf1[4];
    #pragma unroll
    for (int ft = 0; ft < 4; ++ft) {
        const __hip_bfloat16* fp = filters + ((ft * 16 + tl) * 64 + quad * 8);
        bf0[ft] = *(const bf16x8*)(fp);
        bf1[ft] = *(const bf16x8*)(fp + 32);
    }

    int s0 = 511 - wave * 128 - tl + 8 * quad;
    const __hip_bfloat16* xp = &xr[0][0] + (s0 & 7) * 584 + (s0 & ~7);

    const int spc = 512 >> (2 + band);
    float* segO = segG + (size_t)(sig * NBANDS + band) * 64 * 128 + cidx * spc;

    const float NEG = -3.4e38f;
    float run0 = NEG, run1 = NEG, run2 = NEG, run3 = NEG;
    const int per = (band >= 2) ? (1 << (band - 2)) : 1;

    for (int it = 0; it < 8; ++it) {
        const int t0 = wave * 128 + it * 16;
        bf16x8 a0 = *(const bf16x8*)(xp);
        bf16x8 a1 = *(const bf16x8*)(xp + 32);
        xp -= 16;
        f32x4 ac0 = {0.f,0.f,0.f,0.f}, ac1 = ac0, ac2 = ac0, ac3 = ac0;
        ac0 = __builtin_amdgcn_mfma_f32_16x16x32_bf16(a0, bf0[0], ac0, 0, 0, 0);
        ac0 = __builtin_amdgcn_mfma_f32_16x16x32_bf16(a1, bf1[0], ac0, 0, 0, 0);
        ac1 = __builtin_amdgcn_mfma_f32_16x16x32_bf16(a0, bf0[1], ac1, 0, 0, 0);
        ac1 = __builtin_amdgcn_mfma_f32_16x16x32_bf16(a1, bf1[1], ac1, 0, 0, 0);
        ac2 = __builtin_amdgcn_mfma_f32_16x16x32_bf16(a0, bf0[2], ac2, 0, 0, 0);
        ac2 = __builtin_amdgcn_mfma_f32_16x16x32_bf16(a1, bf1[2], ac2, 0, 0, 0);
        ac3 = __builtin_amdgcn_mfma_f32_16x16x32_bf16(a0, bf0[3], ac3, 0, 0, 0);
        ac3 = __builtin_amdgcn_mfma_f32_16x16x32_bf16(a1, bf1[3], ac3, 0, 0, 0);
        float m0 = fmaxf(fmaxf(ac0[0], ac0[1]), fmaxf(ac0[2], ac0[3]));
        float m1 = fmaxf(fmaxf(ac1[0], ac1[1]), fmaxf(ac1[2], ac1[3]));
        float m2 = fmaxf(fmaxf(ac2[0], ac2[1]), fmaxf(ac2[2], ac2[3]));
        float m3 = fmaxf(fmaxf(ac3[0], ac3[1]), fmaxf(ac3[2], ac3[3]));
        if (band == 0) {
            int sb = (t0 >> 2) + quad;
            segO[(tl     ) * 128 + sb] = m0;
            segO[(tl + 16) * 128 + sb] = m1;
            segO[(tl + 32) * 128 + sb] = m2;
            segO[(tl + 48) * 128 + sb] = m3;
        } else if (band == 1) {
            m0 = fmaxf(m0, __shfl_xor(m0, 16));
            m1 = fmaxf(m1, __shfl_xor(m1, 16));
            m2 = fmaxf(m2, __shfl_xor(m2, 16));
            m3 = fmaxf(m3, __shfl_xor(m3, 16));
            if ((quad & 1) == 0) {
                int sb = (t0 >> 3) + (quad >> 1);
                segO[(tl     ) * 128 + sb] = m0;
                segO[(tl + 16) * 128 + sb] = m1;
                segO[(tl + 32) * 128 + sb] = m2;
                segO[(tl + 48) * 128 + sb] = m3;
            }
        } else {
            m0 = fmaxf(m0, __shfl_xor(m0, 16)); m0 = fmaxf(m0, __shfl_xor(m0, 32));
            m1 = fmaxf(m1, __shfl_xor(m1, 16)); m1 = fmaxf(m1, __shfl_xor(m1, 32));
            m2 = fmaxf(m2, __shfl_xor(m2, 16)); m2 = fmaxf(m2, __shfl_xor(m2, 32));
            m3 = fmaxf(m3, __shfl_xor(m3, 16)); m3 = fmaxf(m3, __shfl_xor(m3, 32));
            run0 = fmaxf(run0, m0); run1 = fmaxf(run1, m1);
            run2 = fmaxf(run2, m2); run3 = fmaxf(run3, m3);
            if (((it + 1) & (per - 1)) == 0) {
                int sb = t0 >> (2 + band);
                float rv = quad == 0 ? run0 : quad == 1 ? run1
                         : quad == 2 ? run2 : run3;
                segO[(tl + 16 * quad) * 128 + sb] = rv;
                run0 = NEG; run1 = NEG; run2 = NEG; run3 = NEG;
            }
        }
    }
    if (band == 6) {
        float rv = quad == 0 ? run0 : quad == 1 ? run1
                 : quad == 2 ? run2 : run3;
        segP[(tl + 16 * quad) * 4 + wave] = rv;
        __syncthreads();
        if (tid < 128) {
            int f = tid & 63, sg = tid >> 6;
            segO[f * 128 + sg] =
                fmaxf(segP[f * 4 + 2 * sg], segP[f * 4 + 2 * sg + 1]);
        }
    }
}

// ---------------------------------------------------------------------------
// K4 (r20): pool + top-128, 512 threads, wave-scan + hybrid bitonic (r19),
// LOSS fused via 56-counter election (r17). kk-build loads vectorized:
// one coalesced float2 + 2 cross-lane shuffles replaces 4 scattered loads
// (t == lane within the wave since 512 % 64 == 0). Identical fmax chain.
__global__ __launch_bounds__(512) void k_topk(
    const float* __restrict__ segG,
    float* __restrict__ topv, int* __restrict__ topi,
    const __hip_bfloat16* __restrict__ PT, const __hip_bfloat16* __restrict__ PF,
    int* __restrict__ lossCnt, float* __restrict__ accum,
    int* __restrict__ counter, unsigned* __restrict__ out)
{
    const int tid  = threadIdx.x;
    const int lane = tid & 63;
    const int wv4  = tid >> 6;                 // wave id (0..7); scan uses 0..3
    const int band = blockIdx.x, sig = blockIdx.y;
    const float* segB = segG + (size_t)(sig * NBANDS + band) * 64 * 128;

    __shared__ unsigned hist[256];
    __shared__ unsigned wsum[4];
    __shared__ unsigned long long list[512];
    __shared__ int sh_B, sh_nA, sh_cnt, sh_num, sh_w2;
    __shared__ float vT[128], vR[128];
    __shared__ int   iT[128], iR[128];
    __shared__ float red[256];
    __shared__ int amLast;

    unsigned long long kk[8];
    #pragma unroll
    for (int q = 0; q < 8; ++q) {
        int i = q * 512 + tid;
        int f = i >> 6, t = i & 63;            // t == lane (512 % 64 == 0)
        const float2* sg2 = (const float2*)(segB + f * 128);
        float2 p = sg2[t];
        float m = fmaxf(p.x, p.y);
        float py = __shfl_up(p.y, 1);          // sg[2t-1]
        float nx = __shfl_down(p.x, 1);        // sg[2t+2]
        if (t > 0)  m = fmaxf(m, py);
        if (t < 63) m = fmaxf(m, nx);
        kk[q] = ((unsigned long long)encf(m) << 32) | (unsigned)(4095 - i);
    }

    int shift = 56;
    unsigned long long prefix = 0;
    int nA = 0;
    for (int lev = 0; lev < 8; ++lev) {
        if (tid < 256) hist[tid] = 0;
        __syncthreads();
        #pragma unroll
        for (int q = 0; q < 8; ++q) {
            bool inpre = (lev == 0) || ((kk[q] >> (shift + 8)) == prefix);
            if (inpre) atomicAdd(&hist[(unsigned)((kk[q] >> shift) & 255u)], 1u);
        }
        __syncthreads();
        unsigned hcnt = 0, sfx = 0;
        if (tid < 256) {                       // waves 0-3 only (wave-uniform)
            hcnt = hist[tid];
            sfx = hcnt;                        // inclusive suffix scan in-wave
            #pragma unroll
            for (int off = 1; off < 64; off <<= 1) {
                unsigned o = __shfl_down(sfx, off);
                if (lane + off < 64) sfx += o;
            }
            if (lane == 0) wsum[wv4] = sfx;
        }
        __syncthreads();
        if (tid < 256) {
            unsigned addhi = 0;
            #pragma unroll
            for (int w2 = 1; w2 < 4; ++w2) addhi += (w2 > wv4) ? wsum[w2] : 0u;
            unsigned ge = (unsigned)nA + sfx + addhi;   // count >= bucket tid
            unsigned gt = ge - hcnt;                    // count >  bucket tid
            if (ge >= 128u && gt < 128u) {
                sh_B = tid; sh_nA = (int)gt; sh_cnt = (int)hcnt;
            }
        }
        __syncthreads();
        prefix = (prefix << 8) | (unsigned)sh_B;
        nA = sh_nA;
        if (nA + sh_cnt <= 511 || shift == 0) break;
        shift -= 8;
        __syncthreads();
    }

    if (tid < 256) { list[tid] = 0ull; list[tid + 256] = 0ull; }
    if (tid == 0) sh_num = 0;
    __syncthreads();
    #pragma unroll
    for (int q = 0; q < 8; ++q) {
        if ((kk[q] >> shift) >= prefix) {
            int p = atomicAdd(&sh_num, 1);
            if (p < 512) list[p] = kk[q];
        }
    }
    __syncthreads();

    // ---- bitonic sort, hybrid register/LDS ----
    unsigned long long v = list[tid];
    #pragma unroll
    for (int k = 2; k <= 64; k <<= 1) {        // all j < 64: pure shfl
        for (int j = k >> 1; j > 0; j >>= 1) {
            unsigned long long pv = __shfl_xor(v, j);
            bool takeMin = (((tid & j) == 0) == ((tid & k) == 0));
            unsigned long long mn = v < pv ? v : pv;
            unsigned long long mx = v < pv ? pv : v;
            v = takeMin ? mn : mx;
        }
    }
    list[tid] = v;
    __syncthreads();
    for (int k = 128; k <= 512; k <<= 1) {
        for (int j = k >> 1; j >= 64; j >>= 1) {   // cross-wave: LDS
            const int w = tid, l = w ^ j;
            if (l > w) {
                unsigned long long av = list[w], bv = list[l];
                bool up = ((w & k) == 0);
                if ((av > bv) == up) { list[w] = bv; list[l] = av; }
            }
            __syncthreads();
        }
        v = list[tid];
        #pragma unroll
        for (int j = 32; j > 0; j >>= 1) {         // in-wave: shfl
            unsigned long long pv = __shfl_xor(v, j);
            bool takeMin = (((tid & j) == 0) == ((tid & k) == 0));
            unsigned long long mn = v < pv ? v : pv;
            unsigned long long mx = v < pv ? pv : v;
            v = takeMin ? mn : mx;
        }
        list[tid] = v;
        __syncthreads();
    }

    if (tid < K_TOP) {
        unsigned long long key = list[511 - tid];
        const size_t ob = ((size_t)sig * NBANDS + band) * K_TOP + tid;
        topv[ob] = decf((unsigned)(key >> 32));
        topi[ob] = 4095 - (int)(key & 0xFFFFFFFFu);
    }

    // ---- election: second finisher of this (band, sig&7) pair runs loss ----
    __syncthreads();
    if (tid == 0) {
        __threadfence();
        sh_w2 = (atomicAdd(&lossCnt[(sig & 7) * NBANDS + band], 1) == 1);
    }
    __syncthreads();
    if (!sh_w2) return;
    __threadfence();   // acquire: see partner block's topv/topi

    // ---- loss (proven k_loss body; tid < 256 active) ----
    const int b = sig & 7;
    const size_t bt = ((size_t)b * NBANDS + band) * K_TOP;
    const size_t br = ((size_t)(8 + b) * NBANDS + band) * K_TOP;
    if (tid < 128) { vT[tid] = topv[bt + tid]; iT[tid] = topi[bt + tid]; }
    else if (tid < 256) {
        int j = tid - 128; vR[j] = topv[br + j]; iR[j] = topi[br + j];
    }
    __syncthreads();
    float sum = 0.f;
    if (tid < 128) {
        #pragma unroll 4
        for (int k = 0; k < K_TOP; ++k) {
            float a = vT[k] * bf2f(PT[(iT[k] & 63) * 128 + tid]);
            float cc = vR[k] * bf2f(PT[(iR[k] & 63) * 128 + tid]);
            sum += fabsf(a - cc);
        }
    } else if (tid < 256) {
        const int j = tid - 128;
        #pragma unroll 4
        for (int k = 0; k < K_TOP; ++k) {
            float a = bf2f(PF[(iT[k] >> 6) * 128 + j]);
            float cc = bf2f(PF[(iR[k] >> 6) * 128 + j]);
            sum += fabsf(a - cc);
        }
    }
    if (tid < 256) red[tid] = sum;
    __syncthreads();
    for (int ofs = 128; ofs > 0; ofs >>= 1) {
        if (tid < ofs) red[tid] += red[tid + ofs];
        __syncthreads();
    }
    if (tid == 0) {
        atomicAdd(accum, red[0]);
        __threadfence();
        amLast = (atomicAdd(counter, 1) == NBANDS * 8 - 1);
    }
    __syncthreads();
    if (!amLast) return;
    if (tid == 0) {
        __threadfence();
        float L = atomicAdd(accum, 0.f) * (1.0f / 1835008.0f);
        unsigned lu = __float_as_uint(L);
        bool isnanL = ((lu & 0x7F800000u) == 0x7F800000u) && (lu & 0x007FFFFFu);
        float code;
        if      (isnanL)           code = 500.f;
        else if (L == 0.f)         code = 400.f;
        else if (fabsf(L) < 1e-6f) code = 600.f;
        else                       code = L;
        unsigned fb = __float_as_uint(code);
        unsigned hb = (fb + 0x7FFFu + ((fb >> 16) & 1u)) >> 16;
        out[0] = (hb << 16) | hb;    // dual-format store (proven r4)
    }
}

// ---------------------------------------------------------------------------
extern "C" void kernel_launch(void* const* d_in, const int* in_sizes, int n_in,
                              void* d_out, int out_size, void* d_ws, size_t ws_size,
                              hipStream_t stream)
{
    float* C      = (float*)d_ws;                          // 524288 f
    float* bands  = C + (size_t)NSIG * NBINS * 2;          // 1047552 f
    float* segG   = bands + (size_t)NSIG * BAND_STRIDE;    // 917504 f
    float* topv   = segG + (size_t)NSIG * NBANDS * 64 * 128; // 14336 f
    int*   topi   = (int*)(topv + (size_t)NSIG * NBANDS * K_TOP);
    float* accum  = (float*)(topi + (size_t)NSIG * NBANDS * K_TOP);
    int*   counter= (int*)(accum + 1);
    int*   lossCnt= (int*)(accum + 4);                     // 56 ints
    float2* W256  = (float2*)(accum + 64);                 // 256 float2
    float2* Wtab  = (float2*)(accum + 576);                // 8192 float2
    __hip_bfloat16* staged = (__hip_bfloat16*)(accum + 16960); // 16B-aligned
    float* TG = (float*)(staged + SST_TOT);   // T and G alias (T dead before G)
    float* T  = TG;
    float* G  = TG;

    const __hip_bfloat16* fst = staged + SST_F;
    const __hip_bfloat16* pts = staged + SST_PT;
    const __hip_bfloat16* pfs = staged + SST_PF;

    k_fwd1   <<<dim3(17, NSIG),      256, 0, stream>>>(d_in[0], d_in[1],
                 d_in[2], d_in[3], d_in[4], staged, bands, accum, counter,
                 lossCnt, W256, Wtab, T);
    k_fwd2   <<<dim3(128, NSIG),     128, 0, stream>>>(T, C, W256);
    k_synthA <<<dim3(64, NSIG),      256, 0, stream>>>(C, G, Wtab);
    k_synthB <<<dim3(64, NSIG),      256, 0, stream>>>(C, G, bands, Wtab);
    k_conv   <<<dim3(127, NSIG),     256, 0, stream>>>(bands, fst, segG);
    k_topk   <<<dim3(NBANDS, NSIG),  512, 0, stream>>>(segG, topv, topi,
                 pts, pfs, lossCnt, accum, counter, (unsigned*)d_out);
}